// Round 2
// baseline (402.482 us; speedup 1.0000x reference)
//
#include <hip/hip_runtime.h>
#include <math.h>

// GAT predictor: B=64, N=512, ATOM=34, GAT=128, HID=256, 3 layers + out.
// Round-9: fused_attn was latency-bound (MfmaUtil 7%, VALU 27%, HBM 10%) —
// the MFMA loop's 4 global B-loads/iter (L2 hit ~200cy) had only unroll-2 of
// slack at 4 waves/SIMD. Now: (a) B-tile loads for kb=0,1 issued at kernel
// entry so their latency hides under the softmax VALU phase; (b) the 16-iter
// MFMA loop is fully unrolled with a depth-2 register ping-pong prefetch
// (consume pb[kb&1], 8 MFMA, then reload pb[kb&1] for kb+2). VGPR 64->~96,
// still 4 blocks/CU (LDS-limited). Everything else unchanged from round-8.
// ws: whtH 8MB | whtL 8MB | (ex-Pg hosts WoutT) | src/dst | multi 50MB
// d_out head hosts the 2.1MB adj bitmask until the final GEMM overwrites it.

#define ALPHA 0.2f
#define NEG_INF -9e15f

typedef __attribute__((ext_vector_type(8))) short s16x8;   // 8 bf16 (4 VGPRs)
typedef __attribute__((ext_vector_type(4))) float f32x4;

__device__ __forceinline__ ushort bf16_rne(float f) {
  union { float f; unsigned u; } v; v.f = f;
  unsigned r = v.u + 0x7FFFu + ((v.u >> 16) & 1u);
  return (ushort)(r >> 16);
}
__device__ __forceinline__ float bf16_tof(ushort h) {
  union { unsigned u; float f; } v; v.u = ((unsigned)h) << 16;
  return v.f;
}
__device__ __forceinline__ void split_store4(
    ushort* __restrict__ ph, ushort* __restrict__ pl,
    float v0, float v1, float v2, float v3) {
  ushort h0 = bf16_rne(v0), h1 = bf16_rne(v1), h2 = bf16_rne(v2), h3 = bf16_rne(v3);
  *(ushort4*)ph = make_ushort4(h0, h1, h2, h3);
  *(ushort4*)pl = make_ushort4(bf16_rne(v0 - bf16_tof(h0)), bf16_rne(v1 - bf16_tof(h1)),
                               bf16_rne(v2 - bf16_tof(h2)), bf16_rne(v3 - bf16_tof(h3)));
}

// ---- K0: pack adj>0 into bitmask [32768][16] uint. ----
__global__ __launch_bounds__(256) void maskprep(
    const int* __restrict__ adj, unsigned* __restrict__ mask)
{
  const int gid = blockIdx.x * 256 + threadIdx.x;       // 524288 words
  const int4* __restrict__ p = (const int4*)(adj + (long)gid * 32);
  unsigned m = 0;
#pragma unroll
  for (int k = 0; k < 8; k++) {
    const int4 v = p[k];
    m |= (v.x > 0 ? 1u : 0u) << (4 * k);
    m |= (v.y > 0 ? 1u : 0u) << (4 * k + 1);
    m |= (v.z > 0 ? 1u : 0u) << (4 * k + 2);
    m |= (v.w > 0 ? 1u : 0u) << (4 * k + 3);
  }
  mask[gid] = m;
}

// ---- transpose + hi/lo split a weight matrix: W[K,N] fp32 -> TH/TL[N][K]. ----
__global__ __launch_bounds__(256) void wt_prep(
    const float* __restrict__ W, ushort* __restrict__ TH, ushort* __restrict__ TL,
    const int Kd, const int Nd)
{
  const int idx = blockIdx.x * 256 + threadIdx.x;
  if (idx >= Kd * Nd) return;
  const int k = idx / Nd, n = idx % Nd;
  const float v = W[idx];
  const ushort h = bf16_rne(v);
  TH[(long)n * Kd + k] = h;
  TL[(long)n * Kd + k] = bf16_rne(v - bf16_tof(h));
}

// ---- K1: Wh = compound[32768,34]@W[34,128] -> WhT bf16 hi/lo + src/dst. ----
__global__ __launch_bounds__(256) void wh_small(
    const float* __restrict__ A, const float* __restrict__ W,
    const float* __restrict__ avec,
    ushort* __restrict__ whtH, ushort* __restrict__ whtL,
    float* __restrict__ src, float* __restrict__ dst)
{
  __shared__ float AsT[34][36];
  __shared__ float Ws[34][128];
  const int t = threadIdx.x;
  const long row0 = (long)blockIdx.x * 32;
  const int cg = t & 31, rg = t >> 5;
  {
    const int r = t >> 3, l8 = t & 7;
#pragma unroll
    for (int q = 0; q < 5; q++) {
      int k = l8 + q * 8;
      if (k < 34) AsT[k][r] = A[(row0 + r) * 34 + k];
    }
  }
  {
    int idx = t;
#pragma unroll
    for (int i = 0; i < 17; i++, idx += 256)
      Ws[idx >> 7][idx & 127] = W[idx];
  }
  __syncthreads();

  float acc[4][4];
#pragma unroll
  for (int r = 0; r < 4; r++)
#pragma unroll
    for (int c = 0; c < 4; c++) acc[r][c] = 0.f;
#pragma unroll 2
  for (int k = 0; k < 34; k++) {
    const float4 wv = *(const float4*)&Ws[k][cg * 4];
    const float4 av = *(const float4*)&AsT[k][rg * 4];
#define GFMA(r, a) \
    acc[r][0] += (a) * wv.x; acc[r][1] += (a) * wv.y; \
    acc[r][2] += (a) * wv.z; acc[r][3] += (a) * wv.w;
    GFMA(0, av.x) GFMA(1, av.y) GFMA(2, av.z) GFMA(3, av.w)
#undef GFMA
  }

  {
    const long tb = (row0 >> 9) * 65536;
    const int jloc = (int)(row0 & 511) + rg * 4;
#pragma unroll
    for (int cc = 0; cc < 4; cc++) {
      const long o = tb + (long)(cg * 4 + cc) * 512 + jloc;
      split_store4(&whtH[o], &whtL[o], acc[0][cc], acc[1][cc], acc[2][cc], acc[3][cc]);
    }
  }

  const float4 a1 = *(const float4*)&avec[cg * 4];
  const float4 a2 = *(const float4*)&avec[128 + cg * 4];
#pragma unroll
  for (int r = 0; r < 4; r++) {
    float s = acc[r][0]*a1.x + acc[r][1]*a1.y + acc[r][2]*a1.z + acc[r][3]*a1.w;
    float d = acc[r][0]*a2.x + acc[r][1]*a2.y + acc[r][2]*a2.z + acc[r][3]*a2.w;
#pragma unroll
    for (int w = 1; w < 32; w <<= 1) {
      s += __shfl_xor(s, w, 64);
      d += __shfl_xor(d, w, 64);
    }
    if (cg == 0) {
      src[row0 + rg * 4 + r] = s;
      dst[row0 + rg * 4 + r] = d;
    }
  }
}

// ---- K2 (fused): softmax rows directly into LDS As (unnormalized bf16 p),
// then out = elu((P @ WhT^T) * 1/rowsum). B tiles register-prefetched:
// kb=0,1 issued at entry (hide under softmax), depth-2 ping-pong in loop. ----
__global__ __launch_bounds__(256, 4) void fused_attn(
    const unsigned* __restrict__ mask,
    const float* __restrict__ src, const float* __restrict__ dstv,
    const ushort* __restrict__ whtH, const ushort* __restrict__ whtL,
    float* __restrict__ out, const int ostride, const int ocoff)
{
  __shared__ ushort As[32][520];
  __shared__ float dstS[512];
  __shared__ float invS[32];
  const int t = threadIdx.x;
  // XCD swizzle: 1024 blocks = 8 XCDs x 128; give each XCD 8 whole batches so
  // every batch's 256KB wht slice is fetched from HBM once, reused via L2.
  const int flat = blockIdx.y * 16 + blockIdx.x;
  const int swz = (flat & 7) * 128 + (flat >> 3);
  const long base = (long)(swz >> 4) * 512;   // batch * 512
  const int i0 = (swz & 15) * 32;             // row tile within batch

  // -- MFMA-loop geometry + B prefetch (independent of softmax; issue first
  // so the L2/HBM latency hides under the softmax VALU phase).
  const int wv = t >> 6, lane = t & 63;
  const int m16 = lane & 15, q = lane >> 4;
  const int n0 = wv * 32;
  const long bb = base * 128;
  const ushort* __restrict__ bH = whtH + bb + (long)(n0 + m16) * 512 + q * 8;
  const ushort* __restrict__ bL = whtL + bb + (long)(n0 + m16) * 512 + q * 8;
  s16x8 p0H[2], p0L[2], p1H[2], p1L[2];      // depth-2 ping-pong (32 VGPR)
  p0H[0] = *(const s16x8*)&bH[0];
  p0L[0] = *(const s16x8*)&bL[0];
  p1H[0] = *(const s16x8*)&bH[8192];
  p1L[0] = *(const s16x8*)&bL[8192];
  p0H[1] = *(const s16x8*)&bH[32];
  p0L[1] = *(const s16x8*)&bL[32];
  p1H[1] = *(const s16x8*)&bH[8192 + 32];
  p1L[1] = *(const s16x8*)&bL[8192 + 32];

  dstS[t] = dstv[base + t];
  dstS[t + 256] = dstv[base + t + 256];
  __syncthreads();

  // ---- phase 1: masked softmax (unnormalized) -> As bf16, invS = 1/rowsum.
  // 8 threads per row, 64 j each; e recomputed in the exp pass (VALU-cheap).
  {
    const int r = t >> 3, l8 = t & 7;
    const long i = base + i0 + r;
    const float si = src[i];
    const unsigned* __restrict__ mrow = mask + i * 16;
    unsigned mw[16];
#pragma unroll
    for (int jj = 0; jj < 16; jj++) mw[jj] = mrow[jj];
    const int sh = l8 * 4;
    float m = -INFINITY;
#pragma unroll
    for (int jj = 0; jj < 16; jj++) {
      const float4 dv = *(const float4*)&dstS[l8 * 4 + jj * 32];
      float e0 = si + dv.x, e1 = si + dv.y, e2 = si + dv.z, e3 = si + dv.w;
      e0 = fmaxf(e0, ALPHA * e0); e1 = fmaxf(e1, ALPHA * e1);
      e2 = fmaxf(e2, ALPHA * e2); e3 = fmaxf(e3, ALPHA * e3);
      const unsigned w = mw[jj] >> sh;
      e0 = (w & 1u) ? e0 : NEG_INF;
      e1 = (w & 2u) ? e1 : NEG_INF;
      e2 = (w & 4u) ? e2 : NEG_INF;
      e3 = (w & 8u) ? e3 : NEG_INF;
      m = fmaxf(m, fmaxf(fmaxf(e0, e1), fmaxf(e2, e3)));
    }
#pragma unroll
    for (int w = 1; w < 8; w <<= 1) m = fmaxf(m, __shfl_xor(m, w, 64));
    float sum = 0.f;
#pragma unroll
    for (int jj = 0; jj < 16; jj++) {
      const float4 dv = *(const float4*)&dstS[l8 * 4 + jj * 32];
      float e0 = si + dv.x, e1 = si + dv.y, e2 = si + dv.z, e3 = si + dv.w;
      e0 = fmaxf(e0, ALPHA * e0); e1 = fmaxf(e1, ALPHA * e1);
      e2 = fmaxf(e2, ALPHA * e2); e3 = fmaxf(e3, ALPHA * e3);
      const unsigned w = mw[jj] >> sh;
      e0 = (w & 1u) ? e0 : NEG_INF;
      e1 = (w & 2u) ? e1 : NEG_INF;
      e2 = (w & 4u) ? e2 : NEG_INF;
      e3 = (w & 8u) ? e3 : NEG_INF;
      const float p0 = __expf(e0 - m), p1 = __expf(e1 - m);
      const float p2 = __expf(e2 - m), p3 = __expf(e3 - m);
      sum += (p0 + p1) + (p2 + p3);
      *(ushort4*)&As[r][l8 * 4 + jj * 32] =
          make_ushort4(bf16_rne(p0), bf16_rne(p1), bf16_rne(p2), bf16_rne(p3));
    }
#pragma unroll
    for (int w = 1; w < 8; w <<= 1) sum += __shfl_xor(sum, w, 64);
    if (l8 == 0) invS[r] = 1.f / sum;
  }
  __syncthreads();

  // ---- phase 2: MFMA aggregation, fully unrolled with depth-2 prefetch.
  f32x4 acc00 = {0.f,0.f,0.f,0.f}, acc01 = {0.f,0.f,0.f,0.f};
  f32x4 acc10 = {0.f,0.f,0.f,0.f}, acc11 = {0.f,0.f,0.f,0.f};
#pragma unroll
  for (int kb = 0; kb < 16; kb++) {
    const int k0 = kb * 32 + q * 8;
    const s16x8 a0 = *(const s16x8*)&As[m16][k0];
    const s16x8 a1 = *(const s16x8*)&As[16 + m16][k0];
    const int c = kb & 1;
    acc00 = __builtin_amdgcn_mfma_f32_16x16x32_bf16(a0, p0H[c], acc00, 0, 0, 0);
    acc01 = __builtin_amdgcn_mfma_f32_16x16x32_bf16(a0, p1H[c], acc01, 0, 0, 0);
    acc10 = __builtin_amdgcn_mfma_f32_16x16x32_bf16(a1, p0H[c], acc10, 0, 0, 0);
    acc11 = __builtin_amdgcn_mfma_f32_16x16x32_bf16(a1, p1H[c], acc11, 0, 0, 0);
    acc00 = __builtin_amdgcn_mfma_f32_16x16x32_bf16(a0, p0L[c], acc00, 0, 0, 0);
    acc01 = __builtin_amdgcn_mfma_f32_16x16x32_bf16(a0, p1L[c], acc01, 0, 0, 0);
    acc10 = __builtin_amdgcn_mfma_f32_16x16x32_bf16(a1, p0L[c], acc10, 0, 0, 0);
    acc11 = __builtin_amdgcn_mfma_f32_16x16x32_bf16(a1, p1L[c], acc11, 0, 0, 0);
    if (kb + 2 < 16) {
      const int kn = (kb + 2) * 32;
      p0H[c] = *(const s16x8*)&bH[kn];
      p0L[c] = *(const s16x8*)&bL[kn];
      p1H[c] = *(const s16x8*)&bH[8192 + kn];
      p1L[c] = *(const s16x8*)&bL[8192 + kn];
    }
  }
#pragma unroll
  for (int reg = 0; reg < 4; reg++) {
    const int row = q * 4 + reg;
    const float li0 = invS[row], li1 = invS[16 + row];
    float v00 = acc00[reg] * li0, v01 = acc01[reg] * li0;
    float v10 = acc10[reg] * li1, v11 = acc11[reg] * li1;
    v00 = v00 > 0.f ? v00 : expm1f(v00);
    v01 = v01 > 0.f ? v01 : expm1f(v01);
    v10 = v10 > 0.f ? v10 : expm1f(v10);
    v11 = v11 > 0.f ? v11 : expm1f(v11);
    float* o0 = out + (base + i0 + row) * (long)ostride + ocoff + n0 + m16;
    float* o1 = out + (base + i0 + 16 + row) * (long)ostride + ocoff + n0 + m16;
    o0[0] = v00; o0[16] = v01;
    o1[0] = v10; o1[16] = v11;
  }
}

// ---- K3/K4: MFMA GEMM, C = A[32768,K] @ BT^T, 32 rows x 128 cols/block.
// A fp32 -> bf16 hi/lo during LDS staging; B pre-split via wt_prep.
// MODE 0: emit whT hi/lo + src/dst.  MODE 1: +bias +leaky fp32 store. ----
template<int K, int KC, int MODE>
__global__ __launch_bounds__(256) void mfma_gemm(
    const float* __restrict__ A,
    const ushort* __restrict__ BTH, const ushort* __restrict__ BTL,
    const float* __restrict__ bias, float* __restrict__ outF,
    ushort* __restrict__ whtH, ushort* __restrict__ whtL,
    const float* __restrict__ avec, float* __restrict__ src, float* __restrict__ dst,
    const int ostride)
{
  constexpr int KP = KC + 8;
  __shared__ ushort AsH[32][KP];
  __shared__ ushort AsL[32][KP];
  __shared__ float sredS[4][32], sredD[4][32];
  const int t = threadIdx.x;
  const long row0 = (long)blockIdx.x * 32;
  const int ncoff = (MODE == 1) ? blockIdx.y * 128 : 0;

  const int wv = t >> 6, lane = t & 63;
  const int m16 = lane & 15, q = lane >> 4;
  const int n0 = wv * 32;
  const ushort* __restrict__ bh0 = BTH + (long)(ncoff + n0 + m16) * K;
  const ushort* __restrict__ bl0 = BTL + (long)(ncoff + n0 + m16) * K;

  f32x4 acc[2][2];
#pragma unroll
  for (int m = 0; m < 2; m++)
#pragma unroll
    for (int n = 0; n < 2; n++) acc[m][n] = (f32x4){0.f, 0.f, 0.f, 0.f};

  for (int kc = 0; kc < K; kc += KC) {
    constexpr int NIT = (32 * KC / 4) / 256;
#pragma unroll
    for (int it = 0; it < NIT; it++) {
      const int idx = t + it * 256;
      const int r = idx / (KC / 4), k4 = idx % (KC / 4);
      const float4 v = *(const float4*)&A[(row0 + r) * (long)K + kc + k4 * 4];
      split_store4(&AsH[r][k4 * 4], &AsL[r][k4 * 4], v.x, v.y, v.z, v.w);
    }
    __syncthreads();
#pragma unroll
    for (int ks = 0; ks < KC / 32; ks++) {
      const int k0 = ks * 32 + q * 8;
      const s16x8 a0H = *(const s16x8*)&AsH[m16][k0];
      const s16x8 a0L = *(const s16x8*)&AsL[m16][k0];
      const s16x8 a1H = *(const s16x8*)&AsH[16 + m16][k0];
      const s16x8 a1L = *(const s16x8*)&AsL[16 + m16][k0];
      const int kg = kc + k0;
      const s16x8 b0H = *(const s16x8*)&bh0[kg];
      const s16x8 b0L = *(const s16x8*)&bl0[kg];
      const s16x8 b1H = *(const s16x8*)&bh0[16 * K + kg];
      const s16x8 b1L = *(const s16x8*)&bl0[16 * K + kg];
      acc[0][0] = __builtin_amdgcn_mfma_f32_16x16x32_bf16(a0H, b0H, acc[0][0], 0, 0, 0);
      acc[0][1] = __builtin_amdgcn_mfma_f32_16x16x32_bf16(a0H, b1H, acc[0][1], 0, 0, 0);
      acc[1][0] = __builtin_amdgcn_mfma_f32_16x16x32_bf16(a1H, b0H, acc[1][0], 0, 0, 0);
      acc[1][1] = __builtin_amdgcn_mfma_f32_16x16x32_bf16(a1H, b1H, acc[1][1], 0, 0, 0);
      acc[0][0] = __builtin_amdgcn_mfma_f32_16x16x32_bf16(a0L, b0H, acc[0][0], 0, 0, 0);
      acc[0][1] = __builtin_amdgcn_mfma_f32_16x16x32_bf16(a0L, b1H, acc[0][1], 0, 0, 0);
      acc[1][0] = __builtin_amdgcn_mfma_f32_16x16x32_bf16(a1L, b0H, acc[1][0], 0, 0, 0);
      acc[1][1] = __builtin_amdgcn_mfma_f32_16x16x32_bf16(a1L, b1H, acc[1][1], 0, 0, 0);
      acc[0][0] = __builtin_amdgcn_mfma_f32_16x16x32_bf16(a0H, b0L, acc[0][0], 0, 0, 0);
      acc[0][1] = __builtin_amdgcn_mfma_f32_16x16x32_bf16(a0H, b1L, acc[0][1], 0, 0, 0);
      acc[1][0] = __builtin_amdgcn_mfma_f32_16x16x32_bf16(a1H, b0L, acc[1][0], 0, 0, 0);
      acc[1][1] = __builtin_amdgcn_mfma_f32_16x16x32_bf16(a1H, b1L, acc[1][1], 0, 0, 0);
    }
    __syncthreads();
  }

  if (MODE == 0) {
    // whT hi/lo store: whtH[b][c][j]
    const long b = row0 >> 9;
    const int iloc = (int)(row0 & 511);
#pragma unroll
    for (int m = 0; m < 2; m++)
#pragma unroll
      for (int n = 0; n < 2; n++) {
        const int c = n0 + n * 16 + m16;
        const long o = b * 65536 + (long)c * 512 + iloc + m * 16 + q * 4;
        const f32x4 v = acc[m][n];
        split_store4(&whtH[o], &whtL[o], v[0], v[1], v[2], v[3]);
      }
    // fused src/dst: reduce over cols (16 lanes x 2 n-tiles per wave, 4 waves)
    const float a10 = avec[n0 + m16], a11 = avec[n0 + 16 + m16];
    const float a20 = avec[128 + n0 + m16], a21 = avec[128 + n0 + 16 + m16];
#pragma unroll
    for (int m = 0; m < 2; m++) {
#pragma unroll
      for (int reg = 0; reg < 4; reg++) {
        float s = acc[m][0][reg] * a10 + acc[m][1][reg] * a11;
        float d = acc[m][0][reg] * a20 + acc[m][1][reg] * a21;
#pragma unroll
        for (int w = 1; w < 16; w <<= 1) {
          s += __shfl_xor(s, w, 64);
          d += __shfl_xor(d, w, 64);
        }
        if (m16 == 0) {
          const int row = m * 16 + q * 4 + reg;
          sredS[wv][row] = s;
          sredD[wv][row] = d;
        }
      }
    }
    __syncthreads();
    if (t < 32) {
      const float s = sredS[0][t] + sredS[1][t] + sredS[2][t] + sredS[3][t];
      const float d = sredD[0][t] + sredD[1][t] + sredD[2][t] + sredD[3][t];
      src[row0 + t] = s;
      dst[row0 + t] = d;
    }
  } else {
#pragma unroll
    for (int m = 0; m < 2; m++)
#pragma unroll
      for (int n = 0; n < 2; n++) {
        const int c = ncoff + n0 + n * 16 + m16;
        const float bv = bias[c];
#pragma unroll
        for (int reg = 0; reg < 4; reg++) {
          float v = acc[m][n][reg] + bv;
          v = fmaxf(v, ALPHA * v);
          outF[(row0 + m * 16 + q * 4 + reg) * (long)ostride + c] = v;
        }
      }
  }
}

extern "C" void kernel_launch(void* const* d_in, const int* in_sizes, int n_in,
                              void* d_out, int out_size, void* d_ws, size_t ws_size,
                              hipStream_t stream) {
  const float* compound = (const float*)d_in[0];
  const int*   adj      = (const int*)d_in[1];
  const float* W_stack  = (const float*)d_in[2];
  const float* a_stack  = (const float*)d_in[3];
  const float* W_out    = (const float*)d_in[4];
  const float* a_out    = (const float*)d_in[5];
  const float* Wc       = (const float*)d_in[6];
  const float* bc       = (const float*)d_in[7];
  float* out = (float*)d_out;

  ushort* whtH = (ushort*)d_ws;                       // 8 MB
  ushort* whtL = whtH + 4194304;                      // 8 MB
  ushort* Pg   = whtL + 4194304;                      // ex-Pg region, hosts WoutT
  float* f     = (float*)d_ws;
  float* src   = f + 12582912;
  float* dstv  = src + 32768;
  float* multi = dstv + 32768;                        // 12,582,912 floats
  float* x     = multi;                               // aliases multi head
  unsigned* mask = (unsigned*)d_out;                  // 2.1 MB, dead until final GEMM
  ushort* WoT_H = Pg;                                 // parked in ex-Pg region
  ushort* WoT_L = Pg + 49152;
  ushort* WcT_H = (ushort*)(multi + 5000000);         // parked in dead multi tail
  ushort* WcT_L = WcT_H + 32768;

  maskprep<<<2048, 256, 0, stream>>>(adj, mask);
  for (int l = 0; l < 3; l++) {
    wh_small<<<1024, 256, 0, stream>>>(
        compound, W_stack + (long)l * 34 * 128, a_stack + (long)l * 256,
        whtH, whtL, src, dstv);
    fused_attn<<<dim3(16, 64), 256, 0, stream>>>(
        mask, src, dstv, whtH, whtL, multi, 384, l * 128);
  }
  // layer 4: Wh = multi @ W_out  (MFMA, emits whT + src/dst)
  wt_prep<<<192, 256, 0, stream>>>(W_out, WoT_H, WoT_L, 384, 128);
  mfma_gemm<384, 192, 0><<<1024, 256, 0, stream>>>(
      multi, WoT_H, WoT_L, nullptr, nullptr, whtH, whtL, a_out, src, dstv, 0);
  fused_attn<<<dim3(16, 64), 256, 0, stream>>>(
      mask, src, dstv, whtH, whtL, x, 128, 0);
  // final: out = leaky(x @ Wc + bc)  (MFMA)
  wt_prep<<<128, 256, 0, stream>>>(Wc, WcT_H, WcT_L, 128, 256);
  mfma_gemm<128, 128, 1><<<dim3(1024, 2), 256, 0, stream>>>(
      x, WcT_H, WcT_L, bc, out, nullptr, nullptr, nullptr, nullptr, nullptr, 256);
}

// Round 3
// 323.406 us; speedup vs baseline: 1.2445x; 1.2445x over previous
//
#include <hip/hip_runtime.h>
#include <math.h>

// GAT predictor: B=64, N=512, ATOM=34, GAT=128, HID=256, 3 layers + out.
// Round-10: (a) revert round-9's register ping-pong — VGPR cap (launch_bounds
// 256,4 => 128) made it spill to scratch (WRITE 24.5->54MB, FETCH 12.5->27.5MB
// at constant VGPR_Count=64); back to the proven unroll-2 loop. (b) wht layout
// permuted into MFMA-fragment order: per (batch, 16-col n-tile, 32-k kb) 1KB
// chunk, lane l's s16x8 at l*16 bytes. Old layout read B at 16B/lane stride
// 1KB = 16 cache lines per load (4x L2 over-read, ~24TB/s demand, fill-latency
// bound => MfmaUtil 7%). Now each B load is one coalesced 1KB transaction.
// Producers (wh_small, mfma_gemm MODE 0) write the same bijection => numerics
// bit-identical.
// ws: whtH 8MB | whtL 8MB | (ex-Pg hosts WoutT) | src/dst | multi 50MB
// d_out head hosts the 2.1MB adj bitmask until the final GEMM overwrites it.

#define ALPHA 0.2f
#define NEG_INF -9e15f

typedef __attribute__((ext_vector_type(8))) short s16x8;   // 8 bf16 (4 VGPRs)
typedef __attribute__((ext_vector_type(4))) float f32x4;

__device__ __forceinline__ ushort bf16_rne(float f) {
  union { float f; unsigned u; } v; v.f = f;
  unsigned r = v.u + 0x7FFFu + ((v.u >> 16) & 1u);
  return (ushort)(r >> 16);
}
__device__ __forceinline__ float bf16_tof(ushort h) {
  union { unsigned u; float f; } v; v.u = ((unsigned)h) << 16;
  return v.f;
}
__device__ __forceinline__ void split_store4(
    ushort* __restrict__ ph, ushort* __restrict__ pl,
    float v0, float v1, float v2, float v3) {
  ushort h0 = bf16_rne(v0), h1 = bf16_rne(v1), h2 = bf16_rne(v2), h3 = bf16_rne(v3);
  *(ushort4*)ph = make_ushort4(h0, h1, h2, h3);
  *(ushort4*)pl = make_ushort4(bf16_rne(v0 - bf16_tof(h0)), bf16_rne(v1 - bf16_tof(h1)),
                               bf16_rne(v2 - bf16_tof(h2)), bf16_rne(v3 - bf16_tof(h3)));
}

// wht fragment-order offset: batch*65536 + (col/16)*8192 + (j/32)*512
//   + (col%16)*8 + ((j>>3)&3)*128 + (j&7)   [j = node index = GEMM k]
__device__ __forceinline__ long wht_off(long batch, int c, int j) {
  return batch * 65536 + (long)(c >> 4) * 8192 + (j >> 5) * 512 +
         ((c & 15) << 3) + (((j >> 3) & 3) << 7) + (j & 7);
}

// ---- K0: pack adj>0 into bitmask [32768][16] uint. ----
__global__ __launch_bounds__(256) void maskprep(
    const int* __restrict__ adj, unsigned* __restrict__ mask)
{
  const int gid = blockIdx.x * 256 + threadIdx.x;       // 524288 words
  const int4* __restrict__ p = (const int4*)(adj + (long)gid * 32);
  unsigned m = 0;
#pragma unroll
  for (int k = 0; k < 8; k++) {
    const int4 v = p[k];
    m |= (v.x > 0 ? 1u : 0u) << (4 * k);
    m |= (v.y > 0 ? 1u : 0u) << (4 * k + 1);
    m |= (v.z > 0 ? 1u : 0u) << (4 * k + 2);
    m |= (v.w > 0 ? 1u : 0u) << (4 * k + 3);
  }
  mask[gid] = m;
}

// ---- transpose + hi/lo split a weight matrix: W[K,N] fp32 -> TH/TL[N][K]. ----
__global__ __launch_bounds__(256) void wt_prep(
    const float* __restrict__ W, ushort* __restrict__ TH, ushort* __restrict__ TL,
    const int Kd, const int Nd)
{
  const int idx = blockIdx.x * 256 + threadIdx.x;
  if (idx >= Kd * Nd) return;
  const int k = idx / Nd, n = idx % Nd;
  const float v = W[idx];
  const ushort h = bf16_rne(v);
  TH[(long)n * Kd + k] = h;
  TL[(long)n * Kd + k] = bf16_rne(v - bf16_tof(h));
}

// ---- K1: Wh = compound[32768,34]@W[34,128] -> WhT bf16 hi/lo + src/dst. ----
__global__ __launch_bounds__(256) void wh_small(
    const float* __restrict__ A, const float* __restrict__ W,
    const float* __restrict__ avec,
    ushort* __restrict__ whtH, ushort* __restrict__ whtL,
    float* __restrict__ src, float* __restrict__ dst)
{
  __shared__ float AsT[34][36];
  __shared__ float Ws[34][128];
  const int t = threadIdx.x;
  const long row0 = (long)blockIdx.x * 32;
  const int cg = t & 31, rg = t >> 5;
  {
    const int r = t >> 3, l8 = t & 7;
#pragma unroll
    for (int q = 0; q < 5; q++) {
      int k = l8 + q * 8;
      if (k < 34) AsT[k][r] = A[(row0 + r) * 34 + k];
    }
  }
  {
    int idx = t;
#pragma unroll
    for (int i = 0; i < 17; i++, idx += 256)
      Ws[idx >> 7][idx & 127] = W[idx];
  }
  __syncthreads();

  float acc[4][4];
#pragma unroll
  for (int r = 0; r < 4; r++)
#pragma unroll
    for (int c = 0; c < 4; c++) acc[r][c] = 0.f;
#pragma unroll 2
  for (int k = 0; k < 34; k++) {
    const float4 wv = *(const float4*)&Ws[k][cg * 4];
    const float4 av = *(const float4*)&AsT[k][rg * 4];
#define GFMA(r, a) \
    acc[r][0] += (a) * wv.x; acc[r][1] += (a) * wv.y; \
    acc[r][2] += (a) * wv.z; acc[r][3] += (a) * wv.w;
    GFMA(0, av.x) GFMA(1, av.y) GFMA(2, av.z) GFMA(3, av.w)
#undef GFMA
  }

  {
    const long batch = row0 >> 9;
    const int j = (int)(row0 & 511) + rg * 4;       // j%4 == 0 -> contiguous 4
#pragma unroll
    for (int cc = 0; cc < 4; cc++) {
      const long o = wht_off(batch, cg * 4 + cc, j);
      split_store4(&whtH[o], &whtL[o], acc[0][cc], acc[1][cc], acc[2][cc], acc[3][cc]);
    }
  }

  const float4 a1 = *(const float4*)&avec[cg * 4];
  const float4 a2 = *(const float4*)&avec[128 + cg * 4];
#pragma unroll
  for (int r = 0; r < 4; r++) {
    float s = acc[r][0]*a1.x + acc[r][1]*a1.y + acc[r][2]*a1.z + acc[r][3]*a1.w;
    float d = acc[r][0]*a2.x + acc[r][1]*a2.y + acc[r][2]*a2.z + acc[r][3]*a2.w;
#pragma unroll
    for (int w = 1; w < 32; w <<= 1) {
      s += __shfl_xor(s, w, 64);
      d += __shfl_xor(d, w, 64);
    }
    if (cg == 0) {
      src[row0 + rg * 4 + r] = s;
      dst[row0 + rg * 4 + r] = d;
    }
  }
}

// ---- K2 (fused): softmax rows directly into LDS As (unnormalized bf16 p),
// then out = elu((P @ WhT^T) * 1/rowsum). B read in fragment order: one
// coalesced 1KB transaction per wave per tile. ----
__global__ __launch_bounds__(256, 4) void fused_attn(
    const unsigned* __restrict__ mask,
    const float* __restrict__ src, const float* __restrict__ dstv,
    const ushort* __restrict__ whtH, const ushort* __restrict__ whtL,
    float* __restrict__ out, const int ostride, const int ocoff)
{
  __shared__ ushort As[32][520];
  __shared__ float dstS[512];
  __shared__ float invS[32];
  const int t = threadIdx.x;
  // XCD swizzle: 1024 blocks = 8 XCDs x 128; give each XCD 8 whole batches so
  // every batch's 256KB wht slice is fetched from HBM once, reused via L2.
  const int flat = blockIdx.y * 16 + blockIdx.x;
  const int swz = (flat & 7) * 128 + (flat >> 3);
  const long base = (long)(swz >> 4) * 512;   // batch * 512
  const int i0 = (swz & 15) * 32;             // row tile within batch

  dstS[t] = dstv[base + t];
  dstS[t + 256] = dstv[base + t + 256];
  __syncthreads();

  // ---- phase 1: masked softmax (unnormalized) -> As bf16, invS = 1/rowsum.
  // 8 threads per row, 64 j each; e recomputed in the exp pass (VALU-cheap).
  {
    const int r = t >> 3, l8 = t & 7;
    const long i = base + i0 + r;
    const float si = src[i];
    const unsigned* __restrict__ mrow = mask + i * 16;
    unsigned mw[16];
#pragma unroll
    for (int jj = 0; jj < 16; jj++) mw[jj] = mrow[jj];
    const int sh = l8 * 4;
    float m = -INFINITY;
#pragma unroll
    for (int jj = 0; jj < 16; jj++) {
      const float4 dv = *(const float4*)&dstS[l8 * 4 + jj * 32];
      float e0 = si + dv.x, e1 = si + dv.y, e2 = si + dv.z, e3 = si + dv.w;
      e0 = fmaxf(e0, ALPHA * e0); e1 = fmaxf(e1, ALPHA * e1);
      e2 = fmaxf(e2, ALPHA * e2); e3 = fmaxf(e3, ALPHA * e3);
      const unsigned w = mw[jj] >> sh;
      e0 = (w & 1u) ? e0 : NEG_INF;
      e1 = (w & 2u) ? e1 : NEG_INF;
      e2 = (w & 4u) ? e2 : NEG_INF;
      e3 = (w & 8u) ? e3 : NEG_INF;
      m = fmaxf(m, fmaxf(fmaxf(e0, e1), fmaxf(e2, e3)));
    }
#pragma unroll
    for (int w = 1; w < 8; w <<= 1) m = fmaxf(m, __shfl_xor(m, w, 64));
    float sum = 0.f;
#pragma unroll
    for (int jj = 0; jj < 16; jj++) {
      const float4 dv = *(const float4*)&dstS[l8 * 4 + jj * 32];
      float e0 = si + dv.x, e1 = si + dv.y, e2 = si + dv.z, e3 = si + dv.w;
      e0 = fmaxf(e0, ALPHA * e0); e1 = fmaxf(e1, ALPHA * e1);
      e2 = fmaxf(e2, ALPHA * e2); e3 = fmaxf(e3, ALPHA * e3);
      const unsigned w = mw[jj] >> sh;
      e0 = (w & 1u) ? e0 : NEG_INF;
      e1 = (w & 2u) ? e1 : NEG_INF;
      e2 = (w & 4u) ? e2 : NEG_INF;
      e3 = (w & 8u) ? e3 : NEG_INF;
      const float p0 = __expf(e0 - m), p1 = __expf(e1 - m);
      const float p2 = __expf(e2 - m), p3 = __expf(e3 - m);
      sum += (p0 + p1) + (p2 + p3);
      *(ushort4*)&As[r][l8 * 4 + jj * 32] =
          make_ushort4(bf16_rne(p0), bf16_rne(p1), bf16_rne(p2), bf16_rne(p3));
    }
#pragma unroll
    for (int w = 1; w < 8; w <<= 1) sum += __shfl_xor(sum, w, 64);
    if (l8 == 0) invS[r] = 1.f / sum;
  }
  __syncthreads();

  // ---- phase 2: MFMA aggregation (proven unroll-2 loop, coalesced B). ----
  const int wv = t >> 6, lane = t & 63;
  const int m16 = lane & 15, q = lane >> 4;
  const int n0 = wv * 32;
  // fragment-order base: batch*65536 + (2*wv)*8192 + lane*8
  const ushort* __restrict__ bH = whtH + base * 128 + wv * 16384 + lane * 8;
  const ushort* __restrict__ bL = whtL + base * 128 + wv * 16384 + lane * 8;
  f32x4 acc00 = {0.f,0.f,0.f,0.f}, acc01 = {0.f,0.f,0.f,0.f};
  f32x4 acc10 = {0.f,0.f,0.f,0.f}, acc11 = {0.f,0.f,0.f,0.f};
#pragma unroll 2
  for (int kb = 0; kb < 16; kb++) {
    const int k0 = kb * 32 + q * 8;
    const s16x8 a0 = *(const s16x8*)&As[m16][k0];
    const s16x8 a1 = *(const s16x8*)&As[16 + m16][k0];
    const int bo = kb * 512;
    const s16x8 b0H = *(const s16x8*)&bH[bo];
    const s16x8 b0L = *(const s16x8*)&bL[bo];
    const s16x8 b1H = *(const s16x8*)&bH[8192 + bo];
    const s16x8 b1L = *(const s16x8*)&bL[8192 + bo];
    acc00 = __builtin_amdgcn_mfma_f32_16x16x32_bf16(a0, b0H, acc00, 0, 0, 0);
    acc01 = __builtin_amdgcn_mfma_f32_16x16x32_bf16(a0, b1H, acc01, 0, 0, 0);
    acc10 = __builtin_amdgcn_mfma_f32_16x16x32_bf16(a1, b0H, acc10, 0, 0, 0);
    acc11 = __builtin_amdgcn_mfma_f32_16x16x32_bf16(a1, b1H, acc11, 0, 0, 0);
    acc00 = __builtin_amdgcn_mfma_f32_16x16x32_bf16(a0, b0L, acc00, 0, 0, 0);
    acc01 = __builtin_amdgcn_mfma_f32_16x16x32_bf16(a0, b1L, acc01, 0, 0, 0);
    acc10 = __builtin_amdgcn_mfma_f32_16x16x32_bf16(a1, b0L, acc10, 0, 0, 0);
    acc11 = __builtin_amdgcn_mfma_f32_16x16x32_bf16(a1, b1L, acc11, 0, 0, 0);
  }
#pragma unroll
  for (int reg = 0; reg < 4; reg++) {
    const int row = q * 4 + reg;
    const float li0 = invS[row], li1 = invS[16 + row];
    float v00 = acc00[reg] * li0, v01 = acc01[reg] * li0;
    float v10 = acc10[reg] * li1, v11 = acc11[reg] * li1;
    v00 = v00 > 0.f ? v00 : expm1f(v00);
    v01 = v01 > 0.f ? v01 : expm1f(v01);
    v10 = v10 > 0.f ? v10 : expm1f(v10);
    v11 = v11 > 0.f ? v11 : expm1f(v11);
    float* o0 = out + (base + i0 + row) * (long)ostride + ocoff + n0 + m16;
    float* o1 = out + (base + i0 + 16 + row) * (long)ostride + ocoff + n0 + m16;
    o0[0] = v00; o0[16] = v01;
    o1[0] = v10; o1[16] = v11;
  }
}

// ---- K3/K4: MFMA GEMM, C = A[32768,K] @ BT^T, 32 rows x 128 cols/block.
// A fp32 -> bf16 hi/lo during LDS staging; B pre-split via wt_prep.
// MODE 0: emit whT hi/lo (fragment order) + src/dst.
// MODE 1: +bias +leaky fp32 store. ----
template<int K, int KC, int MODE>
__global__ __launch_bounds__(256) void mfma_gemm(
    const float* __restrict__ A,
    const ushort* __restrict__ BTH, const ushort* __restrict__ BTL,
    const float* __restrict__ bias, float* __restrict__ outF,
    ushort* __restrict__ whtH, ushort* __restrict__ whtL,
    const float* __restrict__ avec, float* __restrict__ src, float* __restrict__ dst,
    const int ostride)
{
  constexpr int KP = KC + 8;
  __shared__ ushort AsH[32][KP];
  __shared__ ushort AsL[32][KP];
  __shared__ float sredS[4][32], sredD[4][32];
  const int t = threadIdx.x;
  const long row0 = (long)blockIdx.x * 32;
  const int ncoff = (MODE == 1) ? blockIdx.y * 128 : 0;

  const int wv = t >> 6, lane = t & 63;
  const int m16 = lane & 15, q = lane >> 4;
  const int n0 = wv * 32;
  const ushort* __restrict__ bh0 = BTH + (long)(ncoff + n0 + m16) * K;
  const ushort* __restrict__ bl0 = BTL + (long)(ncoff + n0 + m16) * K;

  f32x4 acc[2][2];
#pragma unroll
  for (int m = 0; m < 2; m++)
#pragma unroll
    for (int n = 0; n < 2; n++) acc[m][n] = (f32x4){0.f, 0.f, 0.f, 0.f};

  for (int kc = 0; kc < K; kc += KC) {
    constexpr int NIT = (32 * KC / 4) / 256;
#pragma unroll
    for (int it = 0; it < NIT; it++) {
      const int idx = t + it * 256;
      const int r = idx / (KC / 4), k4 = idx % (KC / 4);
      const float4 v = *(const float4*)&A[(row0 + r) * (long)K + kc + k4 * 4];
      split_store4(&AsH[r][k4 * 4], &AsL[r][k4 * 4], v.x, v.y, v.z, v.w);
    }
    __syncthreads();
#pragma unroll
    for (int ks = 0; ks < KC / 32; ks++) {
      const int k0 = ks * 32 + q * 8;
      const s16x8 a0H = *(const s16x8*)&AsH[m16][k0];
      const s16x8 a0L = *(const s16x8*)&AsL[m16][k0];
      const s16x8 a1H = *(const s16x8*)&AsH[16 + m16][k0];
      const s16x8 a1L = *(const s16x8*)&AsL[16 + m16][k0];
      const int kg = kc + k0;
      const s16x8 b0H = *(const s16x8*)&bh0[kg];
      const s16x8 b0L = *(const s16x8*)&bl0[kg];
      const s16x8 b1H = *(const s16x8*)&bh0[16 * K + kg];
      const s16x8 b1L = *(const s16x8*)&bl0[16 * K + kg];
      acc[0][0] = __builtin_amdgcn_mfma_f32_16x16x32_bf16(a0H, b0H, acc[0][0], 0, 0, 0);
      acc[0][1] = __builtin_amdgcn_mfma_f32_16x16x32_bf16(a0H, b1H, acc[0][1], 0, 0, 0);
      acc[1][0] = __builtin_amdgcn_mfma_f32_16x16x32_bf16(a1H, b0H, acc[1][0], 0, 0, 0);
      acc[1][1] = __builtin_amdgcn_mfma_f32_16x16x32_bf16(a1H, b1H, acc[1][1], 0, 0, 0);
      acc[0][0] = __builtin_amdgcn_mfma_f32_16x16x32_bf16(a0L, b0H, acc[0][0], 0, 0, 0);
      acc[0][1] = __builtin_amdgcn_mfma_f32_16x16x32_bf16(a0L, b1H, acc[0][1], 0, 0, 0);
      acc[1][0] = __builtin_amdgcn_mfma_f32_16x16x32_bf16(a1L, b0H, acc[1][0], 0, 0, 0);
      acc[1][1] = __builtin_amdgcn_mfma_f32_16x16x32_bf16(a1L, b1H, acc[1][1], 0, 0, 0);
      acc[0][0] = __builtin_amdgcn_mfma_f32_16x16x32_bf16(a0H, b0L, acc[0][0], 0, 0, 0);
      acc[0][1] = __builtin_amdgcn_mfma_f32_16x16x32_bf16(a0H, b1L, acc[0][1], 0, 0, 0);
      acc[1][0] = __builtin_amdgcn_mfma_f32_16x16x32_bf16(a1H, b0L, acc[1][0], 0, 0, 0);
      acc[1][1] = __builtin_amdgcn_mfma_f32_16x16x32_bf16(a1H, b1L, acc[1][1], 0, 0, 0);
    }
    __syncthreads();
  }

  if (MODE == 0) {
    // whT hi/lo store in fragment order
    const long batch = row0 >> 9;
    const int iloc = (int)(row0 & 511);
#pragma unroll
    for (int m = 0; m < 2; m++)
#pragma unroll
      for (int n = 0; n < 2; n++) {
        const int c = n0 + n * 16 + m16;
        const int j = iloc + m * 16 + q * 4;        // j%4 == 0 -> contiguous 4
        const long o = wht_off(batch, c, j);
        const f32x4 v = acc[m][n];
        split_store4(&whtH[o], &whtL[o], v[0], v[1], v[2], v[3]);
      }
    // fused src/dst: reduce over cols (16 lanes x 2 n-tiles per wave, 4 waves)
    const float a10 = avec[n0 + m16], a11 = avec[n0 + 16 + m16];
    const float a20 = avec[128 + n0 + m16], a21 = avec[128 + n0 + 16 + m16];
#pragma unroll
    for (int m = 0; m < 2; m++) {
#pragma unroll
      for (int reg = 0; reg < 4; reg++) {
        float s = acc[m][0][reg] * a10 + acc[m][1][reg] * a11;
        float d = acc[m][0][reg] * a20 + acc[m][1][reg] * a21;
#pragma unroll
        for (int w = 1; w < 16; w <<= 1) {
          s += __shfl_xor(s, w, 64);
          d += __shfl_xor(d, w, 64);
        }
        if (m16 == 0) {
          const int row = m * 16 + q * 4 + reg;
          sredS[wv][row] = s;
          sredD[wv][row] = d;
        }
      }
    }
    __syncthreads();
    if (t < 32) {
      const float s = sredS[0][t] + sredS[1][t] + sredS[2][t] + sredS[3][t];
      const float d = sredD[0][t] + sredD[1][t] + sredD[2][t] + sredD[3][t];
      src[row0 + t] = s;
      dst[row0 + t] = d;
    }
  } else {
#pragma unroll
    for (int m = 0; m < 2; m++)
#pragma unroll
      for (int n = 0; n < 2; n++) {
        const int c = ncoff + n0 + n * 16 + m16;
        const float bv = bias[c];
#pragma unroll
        for (int reg = 0; reg < 4; reg++) {
          float v = acc[m][n][reg] + bv;
          v = fmaxf(v, ALPHA * v);
          outF[(row0 + m * 16 + q * 4 + reg) * (long)ostride + c] = v;
        }
      }
  }
}

extern "C" void kernel_launch(void* const* d_in, const int* in_sizes, int n_in,
                              void* d_out, int out_size, void* d_ws, size_t ws_size,
                              hipStream_t stream) {
  const float* compound = (const float*)d_in[0];
  const int*   adj      = (const int*)d_in[1];
  const float* W_stack  = (const float*)d_in[2];
  const float* a_stack  = (const float*)d_in[3];
  const float* W_out    = (const float*)d_in[4];
  const float* a_out    = (const float*)d_in[5];
  const float* Wc       = (const float*)d_in[6];
  const float* bc       = (const float*)d_in[7];
  float* out = (float*)d_out;

  ushort* whtH = (ushort*)d_ws;                       // 8 MB
  ushort* whtL = whtH + 4194304;                      // 8 MB
  ushort* Pg   = whtL + 4194304;                      // ex-Pg region, hosts WoutT
  float* f     = (float*)d_ws;
  float* src   = f + 12582912;
  float* dstv  = src + 32768;
  float* multi = dstv + 32768;                        // 12,582,912 floats
  float* x     = multi;                               // aliases multi head
  unsigned* mask = (unsigned*)d_out;                  // 2.1 MB, dead until final GEMM
  ushort* WoT_H = Pg;                                 // parked in ex-Pg region
  ushort* WoT_L = Pg + 49152;
  ushort* WcT_H = (ushort*)(multi + 5000000);         // parked in dead multi tail
  ushort* WcT_L = WcT_H + 32768;

  maskprep<<<2048, 256, 0, stream>>>(adj, mask);
  for (int l = 0; l < 3; l++) {
    wh_small<<<1024, 256, 0, stream>>>(
        compound, W_stack + (long)l * 34 * 128, a_stack + (long)l * 256,
        whtH, whtL, src, dstv);
    fused_attn<<<dim3(16, 64), 256, 0, stream>>>(
        mask, src, dstv, whtH, whtL, multi, 384, l * 128);
  }
  // layer 4: Wh = multi @ W_out  (MFMA, emits whT + src/dst)
  wt_prep<<<192, 256, 0, stream>>>(W_out, WoT_H, WoT_L, 384, 128);
  mfma_gemm<384, 192, 0><<<1024, 256, 0, stream>>>(
      multi, WoT_H, WoT_L, nullptr, nullptr, whtH, whtL, a_out, src, dstv, 0);
  fused_attn<<<dim3(16, 64), 256, 0, stream>>>(
      mask, src, dstv, whtH, whtL, x, 128, 0);
  // final: out = leaky(x @ Wc + bc)  (MFMA)
  wt_prep<<<128, 256, 0, stream>>>(Wc, WcT_H, WcT_L, 128, 256);
  mfma_gemm<128, 128, 1><<<dim3(1024, 2), 256, 0, stream>>>(
      x, WcT_H, WcT_L, bc, out, nullptr, nullptr, nullptr, nullptr, nullptr, 256);
}

// Round 4
// 299.335 us; speedup vs baseline: 1.3446x; 1.0804x over previous
//
#include <hip/hip_runtime.h>
#include <math.h>

// GAT predictor: B=64, N=512, ATOM=34, GAT=128, HID=256, 3 layers + out.
// Round-11: the 3 GAT heads are independent -> merge their 6 one-round
// dispatches (wh_small x3, fused_attn x3) into 2 multi-round dispatches.
// fused_attn grid 16x64x3 = 12 blocks/CU = 3 rounds: softmax-phase and
// MFMA-phase blocks now coexist per CU (phase overlap), tail amortized 3x,
// 4 launch gaps removed. wht (fragment-order, round-10) gets 3 slots = 48MB
// exactly filling the ws head; src/dst (4 pairs) + WoutT park in dead d_out
// space behind the adj bitmask (all dead before the final GEMM overwrites).
// ws: wht[3] 48MB | multi 50MB (x aliases head; WcT parked at +5M floats)
// d_out: mask 2.1MB | src[4]/dst[4] 1MB | WoT 0.4MB  (until final GEMM)

#define ALPHA 0.2f
#define NEG_INF -9e15f

typedef __attribute__((ext_vector_type(8))) short s16x8;   // 8 bf16 (4 VGPRs)
typedef __attribute__((ext_vector_type(4))) float f32x4;

__device__ __forceinline__ ushort bf16_rne(float f) {
  union { float f; unsigned u; } v; v.f = f;
  unsigned r = v.u + 0x7FFFu + ((v.u >> 16) & 1u);
  return (ushort)(r >> 16);
}
__device__ __forceinline__ float bf16_tof(ushort h) {
  union { unsigned u; float f; } v; v.u = ((unsigned)h) << 16;
  return v.f;
}
__device__ __forceinline__ void split_store4(
    ushort* __restrict__ ph, ushort* __restrict__ pl,
    float v0, float v1, float v2, float v3) {
  ushort h0 = bf16_rne(v0), h1 = bf16_rne(v1), h2 = bf16_rne(v2), h3 = bf16_rne(v3);
  *(ushort4*)ph = make_ushort4(h0, h1, h2, h3);
  *(ushort4*)pl = make_ushort4(bf16_rne(v0 - bf16_tof(h0)), bf16_rne(v1 - bf16_tof(h1)),
                               bf16_rne(v2 - bf16_tof(h2)), bf16_rne(v3 - bf16_tof(h3)));
}

// wht fragment-order offset: batch*65536 + (col/16)*8192 + (j/32)*512
//   + (col%16)*8 + ((j>>3)&3)*128 + (j&7)   [j = node index = GEMM k]
__device__ __forceinline__ long wht_off(long batch, int c, int j) {
  return batch * 65536 + (long)(c >> 4) * 8192 + (j >> 5) * 512 +
         ((c & 15) << 3) + (((j >> 3) & 3) << 7) + (j & 7);
}

#define WHT_SLOT 8388608L   // ushorts per layer slot (whtH 4M + whtL 4M)

// ---- K0: pack adj>0 into bitmask [32768][16] uint. ----
__global__ __launch_bounds__(256) void maskprep(
    const int* __restrict__ adj, unsigned* __restrict__ mask)
{
  const int gid = blockIdx.x * 256 + threadIdx.x;       // 524288 words
  const int4* __restrict__ p = (const int4*)(adj + (long)gid * 32);
  unsigned m = 0;
#pragma unroll
  for (int k = 0; k < 8; k++) {
    const int4 v = p[k];
    m |= (v.x > 0 ? 1u : 0u) << (4 * k);
    m |= (v.y > 0 ? 1u : 0u) << (4 * k + 1);
    m |= (v.z > 0 ? 1u : 0u) << (4 * k + 2);
    m |= (v.w > 0 ? 1u : 0u) << (4 * k + 3);
  }
  mask[gid] = m;
}

// ---- transpose + hi/lo split a weight matrix: W[K,N] fp32 -> TH/TL[N][K]. ----
__global__ __launch_bounds__(256) void wt_prep(
    const float* __restrict__ W, ushort* __restrict__ TH, ushort* __restrict__ TL,
    const int Kd, const int Nd)
{
  const int idx = blockIdx.x * 256 + threadIdx.x;
  if (idx >= Kd * Nd) return;
  const int k = idx / Nd, n = idx % Nd;
  const float v = W[idx];
  const ushort h = bf16_rne(v);
  TH[(long)n * Kd + k] = h;
  TL[(long)n * Kd + k] = bf16_rne(v - bf16_tof(h));
}

// ---- K1 (3 layers merged): Wh_l = compound @ W_l -> whT_l + src_l/dst_l.
// blockIdx.y = layer. ----
__global__ __launch_bounds__(256) void wh_small(
    const float* __restrict__ A, const float* __restrict__ Wst,
    const float* __restrict__ ast,
    ushort* __restrict__ whtBase, float* __restrict__ srcB, float* __restrict__ dstB)
{
  __shared__ float AsT[34][36];
  __shared__ float Ws[34][128];
  const int t = threadIdx.x;
  const int l = blockIdx.y;
  const float* __restrict__ W = Wst + (long)l * 34 * 128;
  const float* __restrict__ avec = ast + (long)l * 256;
  ushort* __restrict__ whtH = whtBase + (long)l * WHT_SLOT;
  ushort* __restrict__ whtL = whtH + 4194304;
  float* __restrict__ src = srcB + (long)l * 32768;
  float* __restrict__ dst = dstB + (long)l * 32768;
  const long row0 = (long)blockIdx.x * 32;
  const int cg = t & 31, rg = t >> 5;
  {
    const int r = t >> 3, l8 = t & 7;
#pragma unroll
    for (int q = 0; q < 5; q++) {
      int k = l8 + q * 8;
      if (k < 34) AsT[k][r] = A[(row0 + r) * 34 + k];
    }
  }
  {
    int idx = t;
#pragma unroll
    for (int i = 0; i < 17; i++, idx += 256)
      Ws[idx >> 7][idx & 127] = W[idx];
  }
  __syncthreads();

  float acc[4][4];
#pragma unroll
  for (int r = 0; r < 4; r++)
#pragma unroll
    for (int c = 0; c < 4; c++) acc[r][c] = 0.f;
#pragma unroll 2
  for (int k = 0; k < 34; k++) {
    const float4 wv = *(const float4*)&Ws[k][cg * 4];
    const float4 av = *(const float4*)&AsT[k][rg * 4];
#define GFMA(r, a) \
    acc[r][0] += (a) * wv.x; acc[r][1] += (a) * wv.y; \
    acc[r][2] += (a) * wv.z; acc[r][3] += (a) * wv.w;
    GFMA(0, av.x) GFMA(1, av.y) GFMA(2, av.z) GFMA(3, av.w)
#undef GFMA
  }

  {
    const long batch = row0 >> 9;
    const int j = (int)(row0 & 511) + rg * 4;       // j%4 == 0 -> contiguous 4
#pragma unroll
    for (int cc = 0; cc < 4; cc++) {
      const long o = wht_off(batch, cg * 4 + cc, j);
      split_store4(&whtH[o], &whtL[o], acc[0][cc], acc[1][cc], acc[2][cc], acc[3][cc]);
    }
  }

  const float4 a1 = *(const float4*)&avec[cg * 4];
  const float4 a2 = *(const float4*)&avec[128 + cg * 4];
#pragma unroll
  for (int r = 0; r < 4; r++) {
    float s = acc[r][0]*a1.x + acc[r][1]*a1.y + acc[r][2]*a1.z + acc[r][3]*a1.w;
    float d = acc[r][0]*a2.x + acc[r][1]*a2.y + acc[r][2]*a2.z + acc[r][3]*a2.w;
#pragma unroll
    for (int w = 1; w < 32; w <<= 1) {
      s += __shfl_xor(s, w, 64);
      d += __shfl_xor(d, w, 64);
    }
    if (cg == 0) {
      src[row0 + rg * 4 + r] = s;
      dst[row0 + rg * 4 + r] = d;
    }
  }
}

// ---- K2 (fused, multi-layer): softmax rows -> LDS As (unnormalized bf16 p),
// then out = elu((P @ WhT^T) * 1/rowsum). blockIdx.z = layer. ----
__global__ __launch_bounds__(256, 4) void fused_attn(
    const unsigned* __restrict__ mask,
    const float* __restrict__ srcB, const float* __restrict__ dstB,
    const ushort* __restrict__ whtBase,
    float* __restrict__ out, const int ostride)
{
  __shared__ ushort As[32][520];
  __shared__ float dstS[512];
  __shared__ float invS[32];
  const int t = threadIdx.x;
  const int l = blockIdx.z;
  const float* __restrict__ src = srcB + (long)l * 32768;
  const float* __restrict__ dstv = dstB + (long)l * 32768;
  const ushort* __restrict__ whtH = whtBase + (long)l * WHT_SLOT;
  const ushort* __restrict__ whtL = whtH + 4194304;
  const int ocoff = l * 128;
  // XCD swizzle: per layer 1024 blocks = 8 XCDs x 128; each XCD gets 8 whole
  // batches so a batch's 512KB wht slice is HBM-fetched once, reused via L2.
  const int flat = blockIdx.y * 16 + blockIdx.x;
  const int swz = (flat & 7) * 128 + (flat >> 3);
  const long base = (long)(swz >> 4) * 512;   // batch * 512
  const int i0 = (swz & 15) * 32;             // row tile within batch

  dstS[t] = dstv[base + t];
  dstS[t + 256] = dstv[base + t + 256];
  __syncthreads();

  // ---- phase 1: masked softmax (unnormalized) -> As bf16, invS = 1/rowsum.
  // 8 threads per row, 64 j each; e recomputed in the exp pass (VALU-cheap).
  {
    const int r = t >> 3, l8 = t & 7;
    const long i = base + i0 + r;
    const float si = src[i];
    const unsigned* __restrict__ mrow = mask + i * 16;
    unsigned mw[16];
#pragma unroll
    for (int jj = 0; jj < 16; jj++) mw[jj] = mrow[jj];
    const int sh = l8 * 4;
    float m = -INFINITY;
#pragma unroll
    for (int jj = 0; jj < 16; jj++) {
      const float4 dv = *(const float4*)&dstS[l8 * 4 + jj * 32];
      float e0 = si + dv.x, e1 = si + dv.y, e2 = si + dv.z, e3 = si + dv.w;
      e0 = fmaxf(e0, ALPHA * e0); e1 = fmaxf(e1, ALPHA * e1);
      e2 = fmaxf(e2, ALPHA * e2); e3 = fmaxf(e3, ALPHA * e3);
      const unsigned w = mw[jj] >> sh;
      e0 = (w & 1u) ? e0 : NEG_INF;
      e1 = (w & 2u) ? e1 : NEG_INF;
      e2 = (w & 4u) ? e2 : NEG_INF;
      e3 = (w & 8u) ? e3 : NEG_INF;
      m = fmaxf(m, fmaxf(fmaxf(e0, e1), fmaxf(e2, e3)));
    }
#pragma unroll
    for (int w = 1; w < 8; w <<= 1) m = fmaxf(m, __shfl_xor(m, w, 64));
    float sum = 0.f;
#pragma unroll
    for (int jj = 0; jj < 16; jj++) {
      const float4 dv = *(const float4*)&dstS[l8 * 4 + jj * 32];
      float e0 = si + dv.x, e1 = si + dv.y, e2 = si + dv.z, e3 = si + dv.w;
      e0 = fmaxf(e0, ALPHA * e0); e1 = fmaxf(e1, ALPHA * e1);
      e2 = fmaxf(e2, ALPHA * e2); e3 = fmaxf(e3, ALPHA * e3);
      const unsigned w = mw[jj] >> sh;
      e0 = (w & 1u) ? e0 : NEG_INF;
      e1 = (w & 2u) ? e1 : NEG_INF;
      e2 = (w & 4u) ? e2 : NEG_INF;
      e3 = (w & 8u) ? e3 : NEG_INF;
      const float p0 = __expf(e0 - m), p1 = __expf(e1 - m);
      const float p2 = __expf(e2 - m), p3 = __expf(e3 - m);
      sum += (p0 + p1) + (p2 + p3);
      *(ushort4*)&As[r][l8 * 4 + jj * 32] =
          make_ushort4(bf16_rne(p0), bf16_rne(p1), bf16_rne(p2), bf16_rne(p3));
    }
#pragma unroll
    for (int w = 1; w < 8; w <<= 1) sum += __shfl_xor(sum, w, 64);
    if (l8 == 0) invS[r] = 1.f / sum;
  }
  __syncthreads();

  // ---- phase 2: MFMA aggregation (unroll-2 loop, coalesced fragment B). ----
  const int wv = t >> 6, lane = t & 63;
  const int m16 = lane & 15, q = lane >> 4;
  const int n0 = wv * 32;
  // fragment-order base: batch*65536 + (2*wv)*8192 + lane*8
  const ushort* __restrict__ bH = whtH + base * 128 + wv * 16384 + lane * 8;
  const ushort* __restrict__ bL = whtL + base * 128 + wv * 16384 + lane * 8;
  f32x4 acc00 = {0.f,0.f,0.f,0.f}, acc01 = {0.f,0.f,0.f,0.f};
  f32x4 acc10 = {0.f,0.f,0.f,0.f}, acc11 = {0.f,0.f,0.f,0.f};
#pragma unroll 2
  for (int kb = 0; kb < 16; kb++) {
    const int k0 = kb * 32 + q * 8;
    const s16x8 a0 = *(const s16x8*)&As[m16][k0];
    const s16x8 a1 = *(const s16x8*)&As[16 + m16][k0];
    const int bo = kb * 512;
    const s16x8 b0H = *(const s16x8*)&bH[bo];
    const s16x8 b0L = *(const s16x8*)&bL[bo];
    const s16x8 b1H = *(const s16x8*)&bH[8192 + bo];
    const s16x8 b1L = *(const s16x8*)&bL[8192 + bo];
    acc00 = __builtin_amdgcn_mfma_f32_16x16x32_bf16(a0, b0H, acc00, 0, 0, 0);
    acc01 = __builtin_amdgcn_mfma_f32_16x16x32_bf16(a0, b1H, acc01, 0, 0, 0);
    acc10 = __builtin_amdgcn_mfma_f32_16x16x32_bf16(a1, b0H, acc10, 0, 0, 0);
    acc11 = __builtin_amdgcn_mfma_f32_16x16x32_bf16(a1, b1H, acc11, 0, 0, 0);
    acc00 = __builtin_amdgcn_mfma_f32_16x16x32_bf16(a0, b0L, acc00, 0, 0, 0);
    acc01 = __builtin_amdgcn_mfma_f32_16x16x32_bf16(a0, b1L, acc01, 0, 0, 0);
    acc10 = __builtin_amdgcn_mfma_f32_16x16x32_bf16(a1, b0L, acc10, 0, 0, 0);
    acc11 = __builtin_amdgcn_mfma_f32_16x16x32_bf16(a1, b1L, acc11, 0, 0, 0);
  }
#pragma unroll
  for (int reg = 0; reg < 4; reg++) {
    const int row = q * 4 + reg;
    const float li0 = invS[row], li1 = invS[16 + row];
    float v00 = acc00[reg] * li0, v01 = acc01[reg] * li0;
    float v10 = acc10[reg] * li1, v11 = acc11[reg] * li1;
    v00 = v00 > 0.f ? v00 : expm1f(v00);
    v01 = v01 > 0.f ? v01 : expm1f(v01);
    v10 = v10 > 0.f ? v10 : expm1f(v10);
    v11 = v11 > 0.f ? v11 : expm1f(v11);
    float* o0 = out + (base + i0 + row) * (long)ostride + ocoff + n0 + m16;
    float* o1 = out + (base + i0 + 16 + row) * (long)ostride + ocoff + n0 + m16;
    o0[0] = v00; o0[16] = v01;
    o1[0] = v10; o1[16] = v11;
  }
}

// ---- K3/K4: MFMA GEMM, C = A[32768,K] @ BT^T, 32 rows x 128 cols/block.
// A fp32 -> bf16 hi/lo during LDS staging; B pre-split via wt_prep.
// MODE 0: emit whT hi/lo (fragment order) + src/dst.
// MODE 1: +bias +leaky fp32 store. ----
template<int K, int KC, int MODE>
__global__ __launch_bounds__(256) void mfma_gemm(
    const float* __restrict__ A,
    const ushort* __restrict__ BTH, const ushort* __restrict__ BTL,
    const float* __restrict__ bias, float* __restrict__ outF,
    ushort* __restrict__ whtH, ushort* __restrict__ whtL,
    const float* __restrict__ avec, float* __restrict__ src, float* __restrict__ dst,
    const int ostride)
{
  constexpr int KP = KC + 8;
  __shared__ ushort AsH[32][KP];
  __shared__ ushort AsL[32][KP];
  __shared__ float sredS[4][32], sredD[4][32];
  const int t = threadIdx.x;
  const long row0 = (long)blockIdx.x * 32;
  const int ncoff = (MODE == 1) ? blockIdx.y * 128 : 0;

  const int wv = t >> 6, lane = t & 63;
  const int m16 = lane & 15, q = lane >> 4;
  const int n0 = wv * 32;
  const ushort* __restrict__ bh0 = BTH + (long)(ncoff + n0 + m16) * K;
  const ushort* __restrict__ bl0 = BTL + (long)(ncoff + n0 + m16) * K;

  f32x4 acc[2][2];
#pragma unroll
  for (int m = 0; m < 2; m++)
#pragma unroll
    for (int n = 0; n < 2; n++) acc[m][n] = (f32x4){0.f, 0.f, 0.f, 0.f};

  for (int kc = 0; kc < K; kc += KC) {
    constexpr int NIT = (32 * KC / 4) / 256;
#pragma unroll
    for (int it = 0; it < NIT; it++) {
      const int idx = t + it * 256;
      const int r = idx / (KC / 4), k4 = idx % (KC / 4);
      const float4 v = *(const float4*)&A[(row0 + r) * (long)K + kc + k4 * 4];
      split_store4(&AsH[r][k4 * 4], &AsL[r][k4 * 4], v.x, v.y, v.z, v.w);
    }
    __syncthreads();
#pragma unroll
    for (int ks = 0; ks < KC / 32; ks++) {
      const int k0 = ks * 32 + q * 8;
      const s16x8 a0H = *(const s16x8*)&AsH[m16][k0];
      const s16x8 a0L = *(const s16x8*)&AsL[m16][k0];
      const s16x8 a1H = *(const s16x8*)&AsH[16 + m16][k0];
      const s16x8 a1L = *(const s16x8*)&AsL[16 + m16][k0];
      const int kg = kc + k0;
      const s16x8 b0H = *(const s16x8*)&bh0[kg];
      const s16x8 b0L = *(const s16x8*)&bl0[kg];
      const s16x8 b1H = *(const s16x8*)&bh0[16 * K + kg];
      const s16x8 b1L = *(const s16x8*)&bl0[16 * K + kg];
      acc[0][0] = __builtin_amdgcn_mfma_f32_16x16x32_bf16(a0H, b0H, acc[0][0], 0, 0, 0);
      acc[0][1] = __builtin_amdgcn_mfma_f32_16x16x32_bf16(a0H, b1H, acc[0][1], 0, 0, 0);
      acc[1][0] = __builtin_amdgcn_mfma_f32_16x16x32_bf16(a1H, b0H, acc[1][0], 0, 0, 0);
      acc[1][1] = __builtin_amdgcn_mfma_f32_16x16x32_bf16(a1H, b1H, acc[1][1], 0, 0, 0);
      acc[0][0] = __builtin_amdgcn_mfma_f32_16x16x32_bf16(a0L, b0H, acc[0][0], 0, 0, 0);
      acc[0][1] = __builtin_amdgcn_mfma_f32_16x16x32_bf16(a0L, b1H, acc[0][1], 0, 0, 0);
      acc[1][0] = __builtin_amdgcn_mfma_f32_16x16x32_bf16(a1L, b0H, acc[1][0], 0, 0, 0);
      acc[1][1] = __builtin_amdgcn_mfma_f32_16x16x32_bf16(a1L, b1H, acc[1][1], 0, 0, 0);
      acc[0][0] = __builtin_amdgcn_mfma_f32_16x16x32_bf16(a0H, b0L, acc[0][0], 0, 0, 0);
      acc[0][1] = __builtin_amdgcn_mfma_f32_16x16x32_bf16(a0H, b1L, acc[0][1], 0, 0, 0);
      acc[1][0] = __builtin_amdgcn_mfma_f32_16x16x32_bf16(a1H, b0L, acc[1][0], 0, 0, 0);
      acc[1][1] = __builtin_amdgcn_mfma_f32_16x16x32_bf16(a1H, b1L, acc[1][1], 0, 0, 0);
    }
    __syncthreads();
  }

  if (MODE == 0) {
    // whT hi/lo store in fragment order
    const long batch = row0 >> 9;
    const int iloc = (int)(row0 & 511);
#pragma unroll
    for (int m = 0; m < 2; m++)
#pragma unroll
      for (int n = 0; n < 2; n++) {
        const int c = n0 + n * 16 + m16;
        const int j = iloc + m * 16 + q * 4;        // j%4 == 0 -> contiguous 4
        const long o = wht_off(batch, c, j);
        const f32x4 v = acc[m][n];
        split_store4(&whtH[o], &whtL[o], v[0], v[1], v[2], v[3]);
      }
    // fused src/dst: reduce over cols (16 lanes x 2 n-tiles per wave, 4 waves)
    const float a10 = avec[n0 + m16], a11 = avec[n0 + 16 + m16];
    const float a20 = avec[128 + n0 + m16], a21 = avec[128 + n0 + 16 + m16];
#pragma unroll
    for (int m = 0; m < 2; m++) {
#pragma unroll
      for (int reg = 0; reg < 4; reg++) {
        float s = acc[m][0][reg] * a10 + acc[m][1][reg] * a11;
        float d = acc[m][0][reg] * a20 + acc[m][1][reg] * a21;
#pragma unroll
        for (int w = 1; w < 16; w <<= 1) {
          s += __shfl_xor(s, w, 64);
          d += __shfl_xor(d, w, 64);
        }
        if (m16 == 0) {
          const int row = m * 16 + q * 4 + reg;
          sredS[wv][row] = s;
          sredD[wv][row] = d;
        }
      }
    }
    __syncthreads();
    if (t < 32) {
      const float s = sredS[0][t] + sredS[1][t] + sredS[2][t] + sredS[3][t];
      const float d = sredD[0][t] + sredD[1][t] + sredD[2][t] + sredD[3][t];
      src[row0 + t] = s;
      dst[row0 + t] = d;
    }
  } else {
#pragma unroll
    for (int m = 0; m < 2; m++)
#pragma unroll
      for (int n = 0; n < 2; n++) {
        const int c = ncoff + n0 + n * 16 + m16;
        const float bv = bias[c];
#pragma unroll
        for (int reg = 0; reg < 4; reg++) {
          float v = acc[m][n][reg] + bv;
          v = fmaxf(v, ALPHA * v);
          outF[(row0 + m * 16 + q * 4 + reg) * (long)ostride + c] = v;
        }
      }
  }
}

extern "C" void kernel_launch(void* const* d_in, const int* in_sizes, int n_in,
                              void* d_out, int out_size, void* d_ws, size_t ws_size,
                              hipStream_t stream) {
  const float* compound = (const float*)d_in[0];
  const int*   adj      = (const int*)d_in[1];
  const float* W_stack  = (const float*)d_in[2];
  const float* a_stack  = (const float*)d_in[3];
  const float* W_out    = (const float*)d_in[4];
  const float* a_out    = (const float*)d_in[5];
  const float* Wc       = (const float*)d_in[6];
  const float* bc       = (const float*)d_in[7];
  float* out = (float*)d_out;

  // workspace: wht slots for 3 layers (48MB, exactly fills old head region),
  // then multi (50MB). x aliases multi head; WcT parked in dead multi tail.
  ushort* wht_all = (ushort*)d_ws;                    // 3 x 16MB slots
  float* f     = (float*)d_ws;
  float* multi = f + 12582912;                        // 12,582,912 floats
  float* x     = multi;                               // aliases multi head
  ushort* WcT_H = (ushort*)(multi + 5000000);         // beyond x's 4.19M floats
  ushort* WcT_L = WcT_H + 32768;

  // d_out parking (dead until final GEMM overwrites):
  // mask 524288 uints | src[4] | dst[4] | WoT_H/L
  unsigned* mask = (unsigned*)d_out;
  float* doutF = (float*)d_out;
  float* srcB = doutF + 524288;                       // 4 x 32768
  float* dstB = srcB + 4 * 32768;                     // 4 x 32768
  ushort* WoT_H = (ushort*)(dstB + 4 * 32768);        // 98304 ushorts
  ushort* WoT_L = WoT_H + 98304;
  float* src3 = srcB + 3 * 32768;
  float* dst3 = dstB + 3 * 32768;

  maskprep<<<2048, 256, 0, stream>>>(adj, mask);
  // 3 GAT heads in two merged dispatches
  wh_small<<<dim3(1024, 3), 256, 0, stream>>>(
      compound, W_stack, a_stack, wht_all, srcB, dstB);
  fused_attn<<<dim3(16, 64, 3), 256, 0, stream>>>(
      mask, srcB, dstB, wht_all, multi, 384);
  // layer 4: Wh = multi @ W_out  (MFMA, emits whT slot-0 + src/dst slot-3)
  wt_prep<<<192, 256, 0, stream>>>(W_out, WoT_H, WoT_L, 384, 128);
  mfma_gemm<384, 192, 0><<<1024, 256, 0, stream>>>(
      multi, WoT_H, WoT_L, nullptr, nullptr, wht_all, wht_all + 4194304,
      a_out, src3, dst3, 0);
  fused_attn<<<dim3(16, 64, 1), 256, 0, stream>>>(
      mask, src3, dst3, wht_all, x, 128);
  // final: out = leaky(x @ Wc + bc)  (MFMA)
  wt_prep<<<128, 256, 0, stream>>>(Wc, WcT_H, WcT_L, 128, 256);
  mfma_gemm<128, 128, 1><<<dim3(1024, 2), 256, 0, stream>>>(
      x, WcT_H, WcT_L, bc, out, nullptr, nullptr, nullptr, nullptr, nullptr, 256);
}

// Round 5
// 281.815 us; speedup vs baseline: 1.4282x; 1.0622x over previous
//
#include <hip/hip_runtime.h>
#include <hip/hip_bf16.h>
#include <math.h>

// GAT predictor: B=64, N=512, ATOM=34, GAT=128, HID=256, 3 layers + out.
// Round-12: fused_attn is VALU-bound in softmax (VALUBusy 54%, MfmaUtil 14%).
// Cuts: (1) pass-1 masked max via monotonicity: max_j leaky(si+dv_j) ==
// leaky(si + max_j dv_j) (bit-exact; 7 ops/elem -> 2); (2) logits pre-scaled
// by log2e at staging so p = v_exp_f32(e-m) directly (leaky commutes with
// positive scale); (3) p->bf16 via __float22bfloat162_rn (compiler emits
// v_cvt_pk_bf16_f32) instead of 4-op manual rne; (4) elu epilogue expm1f ->
// __expf-1. MFMA loop / layouts / launches unchanged from round-11.
// ws: wht[3] 48MB | multi 50MB (x aliases head; WcT parked at +5M floats)
// d_out: mask 2.1MB | src[4]/dst[4] 1MB | WoT 0.4MB  (until final GEMM)

#define ALPHA 0.2f
#define NEG_INF -9e15f
#define LOG2E 1.44269504088896f

#if __has_builtin(__builtin_amdgcn_exp2f)
#define EXP2F(x) __builtin_amdgcn_exp2f(x)
#else
extern "C" __device__ float __ocml_exp2_f32(float);
#define EXP2F(x) __ocml_exp2_f32(x)
#endif

typedef __attribute__((ext_vector_type(8))) short s16x8;   // 8 bf16 (4 VGPRs)
typedef __attribute__((ext_vector_type(4))) float f32x4;

__device__ __forceinline__ ushort bf16_rne(float f) {
  union { float f; unsigned u; } v; v.f = f;
  unsigned r = v.u + 0x7FFFu + ((v.u >> 16) & 1u);
  return (ushort)(r >> 16);
}
__device__ __forceinline__ float bf16_tof(ushort h) {
  union { unsigned u; float f; } v; v.u = ((unsigned)h) << 16;
  return v.f;
}
__device__ __forceinline__ void split_store4(
    ushort* __restrict__ ph, ushort* __restrict__ pl,
    float v0, float v1, float v2, float v3) {
  ushort h0 = bf16_rne(v0), h1 = bf16_rne(v1), h2 = bf16_rne(v2), h3 = bf16_rne(v3);
  *(ushort4*)ph = make_ushort4(h0, h1, h2, h3);
  *(ushort4*)pl = make_ushort4(bf16_rne(v0 - bf16_tof(h0)), bf16_rne(v1 - bf16_tof(h1)),
                               bf16_rne(v2 - bf16_tof(h2)), bf16_rne(v3 - bf16_tof(h3)));
}

// wht fragment-order offset: batch*65536 + (col/16)*8192 + (j/32)*512
//   + (col%16)*8 + ((j>>3)&3)*128 + (j&7)   [j = node index = GEMM k]
__device__ __forceinline__ long wht_off(long batch, int c, int j) {
  return batch * 65536 + (long)(c >> 4) * 8192 + (j >> 5) * 512 +
         ((c & 15) << 3) + (((j >> 3) & 3) << 7) + (j & 7);
}

#define WHT_SLOT 8388608L   // ushorts per layer slot (whtH 4M + whtL 4M)

// ---- K0: pack adj>0 into bitmask [32768][16] uint. ----
__global__ __launch_bounds__(256) void maskprep(
    const int* __restrict__ adj, unsigned* __restrict__ mask)
{
  const int gid = blockIdx.x * 256 + threadIdx.x;       // 524288 words
  const int4* __restrict__ p = (const int4*)(adj + (long)gid * 32);
  unsigned m = 0;
#pragma unroll
  for (int k = 0; k < 8; k++) {
    const int4 v = p[k];
    m |= (v.x > 0 ? 1u : 0u) << (4 * k);
    m |= (v.y > 0 ? 1u : 0u) << (4 * k + 1);
    m |= (v.z > 0 ? 1u : 0u) << (4 * k + 2);
    m |= (v.w > 0 ? 1u : 0u) << (4 * k + 3);
  }
  mask[gid] = m;
}

// ---- transpose + hi/lo split a weight matrix: W[K,N] fp32 -> TH/TL[N][K]. ----
__global__ __launch_bounds__(256) void wt_prep(
    const float* __restrict__ W, ushort* __restrict__ TH, ushort* __restrict__ TL,
    const int Kd, const int Nd)
{
  const int idx = blockIdx.x * 256 + threadIdx.x;
  if (idx >= Kd * Nd) return;
  const int k = idx / Nd, n = idx % Nd;
  const float v = W[idx];
  const ushort h = bf16_rne(v);
  TH[(long)n * Kd + k] = h;
  TL[(long)n * Kd + k] = bf16_rne(v - bf16_tof(h));
}

// ---- K1 (3 layers merged): Wh_l = compound @ W_l -> whT_l + src_l/dst_l.
// blockIdx.y = layer. ----
__global__ __launch_bounds__(256) void wh_small(
    const float* __restrict__ A, const float* __restrict__ Wst,
    const float* __restrict__ ast,
    ushort* __restrict__ whtBase, float* __restrict__ srcB, float* __restrict__ dstB)
{
  __shared__ float AsT[34][36];
  __shared__ float Ws[34][128];
  const int t = threadIdx.x;
  const int l = blockIdx.y;
  const float* __restrict__ W = Wst + (long)l * 34 * 128;
  const float* __restrict__ avec = ast + (long)l * 256;
  ushort* __restrict__ whtH = whtBase + (long)l * WHT_SLOT;
  ushort* __restrict__ whtL = whtH + 4194304;
  float* __restrict__ src = srcB + (long)l * 32768;
  float* __restrict__ dst = dstB + (long)l * 32768;
  const long row0 = (long)blockIdx.x * 32;
  const int cg = t & 31, rg = t >> 5;
  {
    const int r = t >> 3, l8 = t & 7;
#pragma unroll
    for (int q = 0; q < 5; q++) {
      int k = l8 + q * 8;
      if (k < 34) AsT[k][r] = A[(row0 + r) * 34 + k];
    }
  }
  {
    int idx = t;
#pragma unroll
    for (int i = 0; i < 17; i++, idx += 256)
      Ws[idx >> 7][idx & 127] = W[idx];
  }
  __syncthreads();

  float acc[4][4];
#pragma unroll
  for (int r = 0; r < 4; r++)
#pragma unroll
    for (int c = 0; c < 4; c++) acc[r][c] = 0.f;
#pragma unroll 2
  for (int k = 0; k < 34; k++) {
    const float4 wv = *(const float4*)&Ws[k][cg * 4];
    const float4 av = *(const float4*)&AsT[k][rg * 4];
#define GFMA(r, a) \
    acc[r][0] += (a) * wv.x; acc[r][1] += (a) * wv.y; \
    acc[r][2] += (a) * wv.z; acc[r][3] += (a) * wv.w;
    GFMA(0, av.x) GFMA(1, av.y) GFMA(2, av.z) GFMA(3, av.w)
#undef GFMA
  }

  {
    const long batch = row0 >> 9;
    const int j = (int)(row0 & 511) + rg * 4;       // j%4 == 0 -> contiguous 4
#pragma unroll
    for (int cc = 0; cc < 4; cc++) {
      const long o = wht_off(batch, cg * 4 + cc, j);
      split_store4(&whtH[o], &whtL[o], acc[0][cc], acc[1][cc], acc[2][cc], acc[3][cc]);
    }
  }

  const float4 a1 = *(const float4*)&avec[cg * 4];
  const float4 a2 = *(const float4*)&avec[128 + cg * 4];
#pragma unroll
  for (int r = 0; r < 4; r++) {
    float s = acc[r][0]*a1.x + acc[r][1]*a1.y + acc[r][2]*a1.z + acc[r][3]*a1.w;
    float d = acc[r][0]*a2.x + acc[r][1]*a2.y + acc[r][2]*a2.z + acc[r][3]*a2.w;
#pragma unroll
    for (int w = 1; w < 32; w <<= 1) {
      s += __shfl_xor(s, w, 64);
      d += __shfl_xor(d, w, 64);
    }
    if (cg == 0) {
      src[row0 + rg * 4 + r] = s;
      dst[row0 + rg * 4 + r] = d;
    }
  }
}

// ---- K2 (fused, multi-layer): softmax rows -> LDS As (unnormalized bf16 p),
// then out = elu((P @ WhT^T) * 1/rowsum). blockIdx.z = layer.
// Logits pre-scaled by log2e; p = exp2(e-m). ----
__global__ __launch_bounds__(256, 4) void fused_attn(
    const unsigned* __restrict__ mask,
    const float* __restrict__ srcB, const float* __restrict__ dstB,
    const ushort* __restrict__ whtBase,
    float* __restrict__ out, const int ostride)
{
  __shared__ ushort As[32][520];
  __shared__ float dstS[512];
  __shared__ float invS[32];
  const int t = threadIdx.x;
  const int l = blockIdx.z;
  const float* __restrict__ src = srcB + (long)l * 32768;
  const float* __restrict__ dstv = dstB + (long)l * 32768;
  const ushort* __restrict__ whtH = whtBase + (long)l * WHT_SLOT;
  const ushort* __restrict__ whtL = whtH + 4194304;
  const int ocoff = l * 128;
  // XCD swizzle: per layer 1024 blocks = 8 XCDs x 128; each XCD gets 8 whole
  // batches so a batch's 512KB wht slice is HBM-fetched once, reused via L2.
  const int flat = blockIdx.y * 16 + blockIdx.x;
  const int swz = (flat & 7) * 128 + (flat >> 3);
  const long base = (long)(swz >> 4) * 512;   // batch * 512
  const int i0 = (swz & 15) * 32;             // row tile within batch

  dstS[t] = dstv[base + t] * LOG2E;
  dstS[t + 256] = dstv[base + t + 256] * LOG2E;
  __syncthreads();

  // ---- phase 1: masked softmax (unnormalized, log2-domain) -> As bf16.
  // 8 threads per row, 64 j each.
  {
    const int r = t >> 3, l8 = t & 7;
    const long i = base + i0 + r;
    const float si = src[i] * LOG2E;
    const unsigned* __restrict__ mrow = mask + i * 16;
    unsigned mw[16];
#pragma unroll
    for (int jj = 0; jj < 16; jj++) mw[jj] = mrow[jj];
    const int sh = l8 * 4;
    // pass 1: masked max of dv only (leaky/add factored out by monotonicity)
    float md = -INFINITY;
#pragma unroll
    for (int jj = 0; jj < 16; jj++) {
      const float4 dv = *(const float4*)&dstS[l8 * 4 + jj * 32];
      const unsigned w = mw[jj] >> sh;
      md = fmaxf(md, (w & 1u) ? dv.x : -INFINITY);
      md = fmaxf(md, (w & 2u) ? dv.y : -INFINITY);
      md = fmaxf(md, (w & 4u) ? dv.z : -INFINITY);
      md = fmaxf(md, (w & 8u) ? dv.w : -INFINITY);
    }
#pragma unroll
    for (int w = 1; w < 8; w <<= 1) md = fmaxf(md, __shfl_xor(md, w, 64));
    const float em = si + md;
    const float m = fmaxf(em, ALPHA * em);   // == max_masked leaky(si+dv)
    float sum = 0.f;
#pragma unroll
    for (int jj = 0; jj < 16; jj++) {
      const float4 dv = *(const float4*)&dstS[l8 * 4 + jj * 32];
      const unsigned w = mw[jj] >> sh;
      float e0 = si + dv.x, e1 = si + dv.y, e2 = si + dv.z, e3 = si + dv.w;
      e0 = fmaxf(e0, ALPHA * e0); e1 = fmaxf(e1, ALPHA * e1);
      e2 = fmaxf(e2, ALPHA * e2); e3 = fmaxf(e3, ALPHA * e3);
      e0 = (w & 1u) ? e0 : NEG_INF;
      e1 = (w & 2u) ? e1 : NEG_INF;
      e2 = (w & 4u) ? e2 : NEG_INF;
      e3 = (w & 8u) ? e3 : NEG_INF;
      const float p0 = EXP2F(e0 - m), p1 = EXP2F(e1 - m);
      const float p2 = EXP2F(e2 - m), p3 = EXP2F(e3 - m);
      sum += (p0 + p1) + (p2 + p3);
      union { __hip_bfloat162 b; unsigned u; } u01, u23;
      u01.b = __float22bfloat162_rn(make_float2(p0, p1));
      u23.b = __float22bfloat162_rn(make_float2(p2, p3));
      *(uint2*)&As[r][l8 * 4 + jj * 32] = make_uint2(u01.u, u23.u);
    }
#pragma unroll
    for (int w = 1; w < 8; w <<= 1) sum += __shfl_xor(sum, w, 64);
    if (l8 == 0) invS[r] = 1.f / sum;
  }
  __syncthreads();

  // ---- phase 2: MFMA aggregation (unroll-2 loop, coalesced fragment B). ----
  const int wv = t >> 6, lane = t & 63;
  const int m16 = lane & 15, q = lane >> 4;
  const int n0 = wv * 32;
  // fragment-order base: batch*65536 + (2*wv)*8192 + lane*8
  const ushort* __restrict__ bH = whtH + base * 128 + wv * 16384 + lane * 8;
  const ushort* __restrict__ bL = whtL + base * 128 + wv * 16384 + lane * 8;
  f32x4 acc00 = {0.f,0.f,0.f,0.f}, acc01 = {0.f,0.f,0.f,0.f};
  f32x4 acc10 = {0.f,0.f,0.f,0.f}, acc11 = {0.f,0.f,0.f,0.f};
#pragma unroll 2
  for (int kb = 0; kb < 16; kb++) {
    const int k0 = kb * 32 + q * 8;
    const s16x8 a0 = *(const s16x8*)&As[m16][k0];
    const s16x8 a1 = *(const s16x8*)&As[16 + m16][k0];
    const int bo = kb * 512;
    const s16x8 b0H = *(const s16x8*)&bH[bo];
    const s16x8 b0L = *(const s16x8*)&bL[bo];
    const s16x8 b1H = *(const s16x8*)&bH[8192 + bo];
    const s16x8 b1L = *(const s16x8*)&bL[8192 + bo];
    acc00 = __builtin_amdgcn_mfma_f32_16x16x32_bf16(a0, b0H, acc00, 0, 0, 0);
    acc01 = __builtin_amdgcn_mfma_f32_16x16x32_bf16(a0, b1H, acc01, 0, 0, 0);
    acc10 = __builtin_amdgcn_mfma_f32_16x16x32_bf16(a1, b0H, acc10, 0, 0, 0);
    acc11 = __builtin_amdgcn_mfma_f32_16x16x32_bf16(a1, b1H, acc11, 0, 0, 0);
    acc00 = __builtin_amdgcn_mfma_f32_16x16x32_bf16(a0, b0L, acc00, 0, 0, 0);
    acc01 = __builtin_amdgcn_mfma_f32_16x16x32_bf16(a0, b1L, acc01, 0, 0, 0);
    acc10 = __builtin_amdgcn_mfma_f32_16x16x32_bf16(a1, b0L, acc10, 0, 0, 0);
    acc11 = __builtin_amdgcn_mfma_f32_16x16x32_bf16(a1, b1L, acc11, 0, 0, 0);
  }
#pragma unroll
  for (int reg = 0; reg < 4; reg++) {
    const int row = q * 4 + reg;
    const float li0 = invS[row], li1 = invS[16 + row];
    float v00 = acc00[reg] * li0, v01 = acc01[reg] * li0;
    float v10 = acc10[reg] * li1, v11 = acc11[reg] * li1;
    v00 = v00 > 0.f ? v00 : __expf(v00) - 1.f;
    v01 = v01 > 0.f ? v01 : __expf(v01) - 1.f;
    v10 = v10 > 0.f ? v10 : __expf(v10) - 1.f;
    v11 = v11 > 0.f ? v11 : __expf(v11) - 1.f;
    float* o0 = out + (base + i0 + row) * (long)ostride + ocoff + n0 + m16;
    float* o1 = out + (base + i0 + 16 + row) * (long)ostride + ocoff + n0 + m16;
    o0[0] = v00; o0[16] = v01;
    o1[0] = v10; o1[16] = v11;
  }
}

// ---- K3/K4: MFMA GEMM, C = A[32768,K] @ BT^T, 32 rows x 128 cols/block.
// A fp32 -> bf16 hi/lo during LDS staging; B pre-split via wt_prep.
// MODE 0: emit whT hi/lo (fragment order) + src/dst.
// MODE 1: +bias +leaky fp32 store. ----
template<int K, int KC, int MODE>
__global__ __launch_bounds__(256) void mfma_gemm(
    const float* __restrict__ A,
    const ushort* __restrict__ BTH, const ushort* __restrict__ BTL,
    const float* __restrict__ bias, float* __restrict__ outF,
    ushort* __restrict__ whtH, ushort* __restrict__ whtL,
    const float* __restrict__ avec, float* __restrict__ src, float* __restrict__ dst,
    const int ostride)
{
  constexpr int KP = KC + 8;
  __shared__ ushort AsH[32][KP];
  __shared__ ushort AsL[32][KP];
  __shared__ float sredS[4][32], sredD[4][32];
  const int t = threadIdx.x;
  const long row0 = (long)blockIdx.x * 32;
  const int ncoff = (MODE == 1) ? blockIdx.y * 128 : 0;

  const int wv = t >> 6, lane = t & 63;
  const int m16 = lane & 15, q = lane >> 4;
  const int n0 = wv * 32;
  const ushort* __restrict__ bh0 = BTH + (long)(ncoff + n0 + m16) * K;
  const ushort* __restrict__ bl0 = BTL + (long)(ncoff + n0 + m16) * K;

  f32x4 acc[2][2];
#pragma unroll
  for (int m = 0; m < 2; m++)
#pragma unroll
    for (int n = 0; n < 2; n++) acc[m][n] = (f32x4){0.f, 0.f, 0.f, 0.f};

  for (int kc = 0; kc < K; kc += KC) {
    constexpr int NIT = (32 * KC / 4) / 256;
#pragma unroll
    for (int it = 0; it < NIT; it++) {
      const int idx = t + it * 256;
      const int r = idx / (KC / 4), k4 = idx % (KC / 4);
      const float4 v = *(const float4*)&A[(row0 + r) * (long)K + kc + k4 * 4];
      split_store4(&AsH[r][k4 * 4], &AsL[r][k4 * 4], v.x, v.y, v.z, v.w);
    }
    __syncthreads();
#pragma unroll
    for (int ks = 0; ks < KC / 32; ks++) {
      const int k0 = ks * 32 + q * 8;
      const s16x8 a0H = *(const s16x8*)&AsH[m16][k0];
      const s16x8 a0L = *(const s16x8*)&AsL[m16][k0];
      const s16x8 a1H = *(const s16x8*)&AsH[16 + m16][k0];
      const s16x8 a1L = *(const s16x8*)&AsL[16 + m16][k0];
      const int kg = kc + k0;
      const s16x8 b0H = *(const s16x8*)&bh0[kg];
      const s16x8 b0L = *(const s16x8*)&bl0[kg];
      const s16x8 b1H = *(const s16x8*)&bh0[16 * K + kg];
      const s16x8 b1L = *(const s16x8*)&bl0[16 * K + kg];
      acc[0][0] = __builtin_amdgcn_mfma_f32_16x16x32_bf16(a0H, b0H, acc[0][0], 0, 0, 0);
      acc[0][1] = __builtin_amdgcn_mfma_f32_16x16x32_bf16(a0H, b1H, acc[0][1], 0, 0, 0);
      acc[1][0] = __builtin_amdgcn_mfma_f32_16x16x32_bf16(a1H, b0H, acc[1][0], 0, 0, 0);
      acc[1][1] = __builtin_amdgcn_mfma_f32_16x16x32_bf16(a1H, b1H, acc[1][1], 0, 0, 0);
      acc[0][0] = __builtin_amdgcn_mfma_f32_16x16x32_bf16(a0L, b0H, acc[0][0], 0, 0, 0);
      acc[0][1] = __builtin_amdgcn_mfma_f32_16x16x32_bf16(a0L, b1H, acc[0][1], 0, 0, 0);
      acc[1][0] = __builtin_amdgcn_mfma_f32_16x16x32_bf16(a1L, b0H, acc[1][0], 0, 0, 0);
      acc[1][1] = __builtin_amdgcn_mfma_f32_16x16x32_bf16(a1L, b1H, acc[1][1], 0, 0, 0);
      acc[0][0] = __builtin_amdgcn_mfma_f32_16x16x32_bf16(a0H, b0L, acc[0][0], 0, 0, 0);
      acc[0][1] = __builtin_amdgcn_mfma_f32_16x16x32_bf16(a0H, b1L, acc[0][1], 0, 0, 0);
      acc[1][0] = __builtin_amdgcn_mfma_f32_16x16x32_bf16(a1H, b0L, acc[1][0], 0, 0, 0);
      acc[1][1] = __builtin_amdgcn_mfma_f32_16x16x32_bf16(a1H, b1L, acc[1][1], 0, 0, 0);
    }
    __syncthreads();
  }

  if (MODE == 0) {
    // whT hi/lo store in fragment order
    const long batch = row0 >> 9;
    const int iloc = (int)(row0 & 511);
#pragma unroll
    for (int m = 0; m < 2; m++)
#pragma unroll
      for (int n = 0; n < 2; n++) {
        const int c = n0 + n * 16 + m16;
        const int j = iloc + m * 16 + q * 4;        // j%4 == 0 -> contiguous 4
        const long o = wht_off(batch, c, j);
        const f32x4 v = acc[m][n];
        split_store4(&whtH[o], &whtL[o], v[0], v[1], v[2], v[3]);
      }
    // fused src/dst: reduce over cols (16 lanes x 2 n-tiles per wave, 4 waves)
    const float a10 = avec[n0 + m16], a11 = avec[n0 + 16 + m16];
    const float a20 = avec[128 + n0 + m16], a21 = avec[128 + n0 + 16 + m16];
#pragma unroll
    for (int m = 0; m < 2; m++) {
#pragma unroll
      for (int reg = 0; reg < 4; reg++) {
        float s = acc[m][0][reg] * a10 + acc[m][1][reg] * a11;
        float d = acc[m][0][reg] * a20 + acc[m][1][reg] * a21;
#pragma unroll
        for (int w = 1; w < 16; w <<= 1) {
          s += __shfl_xor(s, w, 64);
          d += __shfl_xor(d, w, 64);
        }
        if (m16 == 0) {
          const int row = m * 16 + q * 4 + reg;
          sredS[wv][row] = s;
          sredD[wv][row] = d;
        }
      }
    }
    __syncthreads();
    if (t < 32) {
      const float s = sredS[0][t] + sredS[1][t] + sredS[2][t] + sredS[3][t];
      const float d = sredD[0][t] + sredD[1][t] + sredD[2][t] + sredD[3][t];
      src[row0 + t] = s;
      dst[row0 + t] = d;
    }
  } else {
#pragma unroll
    for (int m = 0; m < 2; m++)
#pragma unroll
      for (int n = 0; n < 2; n++) {
        const int c = ncoff + n0 + n * 16 + m16;
        const float bv = bias[c];
#pragma unroll
        for (int reg = 0; reg < 4; reg++) {
          float v = acc[m][n][reg] + bv;
          v = fmaxf(v, ALPHA * v);
          outF[(row0 + m * 16 + q * 4 + reg) * (long)ostride + c] = v;
        }
      }
  }
}

extern "C" void kernel_launch(void* const* d_in, const int* in_sizes, int n_in,
                              void* d_out, int out_size, void* d_ws, size_t ws_size,
                              hipStream_t stream) {
  const float* compound = (const float*)d_in[0];
  const int*   adj      = (const int*)d_in[1];
  const float* W_stack  = (const float*)d_in[2];
  const float* a_stack  = (const float*)d_in[3];
  const float* W_out    = (const float*)d_in[4];
  const float* a_out    = (const float*)d_in[5];
  const float* Wc       = (const float*)d_in[6];
  const float* bc       = (const float*)d_in[7];
  float* out = (float*)d_out;

  // workspace: wht slots for 3 layers (48MB), then multi (50MB).
  // x aliases multi head; WcT parked in dead multi tail.
  ushort* wht_all = (ushort*)d_ws;                    // 3 x 16MB slots
  float* f     = (float*)d_ws;
  float* multi = f + 12582912;                        // 12,582,912 floats
  float* x     = multi;                               // aliases multi head
  ushort* WcT_H = (ushort*)(multi + 5000000);         // beyond x's 4.19M floats
  ushort* WcT_L = WcT_H + 32768;

  // d_out parking (dead until final GEMM overwrites):
  // mask 524288 uints | src[4] | dst[4] | WoT_H/L
  unsigned* mask = (unsigned*)d_out;
  float* doutF = (float*)d_out;
  float* srcB = doutF + 524288;                       // 4 x 32768
  float* dstB = srcB + 4 * 32768;                     // 4 x 32768
  ushort* WoT_H = (ushort*)(dstB + 4 * 32768);        // 98304 ushorts
  ushort* WoT_L = WoT_H + 98304;
  float* src3 = srcB + 3 * 32768;
  float* dst3 = dstB + 3 * 32768;

  maskprep<<<2048, 256, 0, stream>>>(adj, mask);
  // 3 GAT heads in two merged dispatches
  wh_small<<<dim3(1024, 3), 256, 0, stream>>>(
      compound, W_stack, a_stack, wht_all, srcB, dstB);
  fused_attn<<<dim3(16, 64, 3), 256, 0, stream>>>(
      mask, srcB, dstB, wht_all, multi, 384);
  // layer 4: Wh = multi @ W_out  (MFMA, emits whT slot-0 + src/dst slot-3)
  wt_prep<<<192, 256, 0, stream>>>(W_out, WoT_H, WoT_L, 384, 128);
  mfma_gemm<384, 192, 0><<<1024, 256, 0, stream>>>(
      multi, WoT_H, WoT_L, nullptr, nullptr, wht_all, wht_all + 4194304,
      a_out, src3, dst3, 0);
  fused_attn<<<dim3(16, 64, 1), 256, 0, stream>>>(
      mask, src3, dst3, wht_all, x, 128);
  // final: out = leaky(x @ Wc + bc)  (MFMA)
  wt_prep<<<128, 256, 0, stream>>>(Wc, WcT_H, WcT_L, 128, 256);
  mfma_gemm<128, 128, 1><<<dim3(1024, 2), 256, 0, stream>>>(
      x, WcT_H, WcT_L, bc, out, nullptr, nullptr, nullptr, nullptr, nullptr, 256);
}

// Round 6
// 281.394 us; speedup vs baseline: 1.4303x; 1.0015x over previous
//
#include <hip/hip_runtime.h>
#include <hip/hip_bf16.h>
#include <math.h>

// GAT predictor: B=64, N=512, ATOM=34, GAT=128, HID=256, 3 layers + out.
// Round-13: softmax max-pass eliminated. The per-row max only guards range,
// so use the UNMASKED bound m_r = leaky(si + max_j dv_j): max_j dv_j ("md")
// is row-independent -> computed once per block during dstS staging (wave
// shfl reduce + 4-word LDS exchange on the existing barrier). p = exp2(e-m)
// <= 1 always; masked entries zeroed by one cndmask on p; underflowing tail
// terms contribute ~0 exactly as before. Softmax: 2 passes @ ~11 ops/elem ->
// 1 pass @ ~7. Normalization divides the per-row constant out; bf16 relative
// precision is scale-invariant -> absmax unchanged. Everything else identical
// to round-12 (fragment-order wht, log2-domain logits, merged layers).
// ws: wht[3] 48MB | multi 50MB (x aliases head; WcT parked at +5M floats)
// d_out: mask 2.1MB | src[4]/dst[4] 1MB | WoT 0.4MB  (until final GEMM)

#define ALPHA 0.2f
#define NEG_INF -9e15f
#define LOG2E 1.44269504088896f

#if __has_builtin(__builtin_amdgcn_exp2f)
#define EXP2F(x) __builtin_amdgcn_exp2f(x)
#else
extern "C" __device__ float __ocml_exp2_f32(float);
#define EXP2F(x) __ocml_exp2_f32(x)
#endif

typedef __attribute__((ext_vector_type(8))) short s16x8;   // 8 bf16 (4 VGPRs)
typedef __attribute__((ext_vector_type(4))) float f32x4;

__device__ __forceinline__ ushort bf16_rne(float f) {
  union { float f; unsigned u; } v; v.f = f;
  unsigned r = v.u + 0x7FFFu + ((v.u >> 16) & 1u);
  return (ushort)(r >> 16);
}
__device__ __forceinline__ float bf16_tof(ushort h) {
  union { unsigned u; float f; } v; v.u = ((unsigned)h) << 16;
  return v.f;
}
__device__ __forceinline__ void split_store4(
    ushort* __restrict__ ph, ushort* __restrict__ pl,
    float v0, float v1, float v2, float v3) {
  ushort h0 = bf16_rne(v0), h1 = bf16_rne(v1), h2 = bf16_rne(v2), h3 = bf16_rne(v3);
  *(ushort4*)ph = make_ushort4(h0, h1, h2, h3);
  *(ushort4*)pl = make_ushort4(bf16_rne(v0 - bf16_tof(h0)), bf16_rne(v1 - bf16_tof(h1)),
                               bf16_rne(v2 - bf16_tof(h2)), bf16_rne(v3 - bf16_tof(h3)));
}

// wht fragment-order offset: batch*65536 + (col/16)*8192 + (j/32)*512
//   + (col%16)*8 + ((j>>3)&3)*128 + (j&7)   [j = node index = GEMM k]
__device__ __forceinline__ long wht_off(long batch, int c, int j) {
  return batch * 65536 + (long)(c >> 4) * 8192 + (j >> 5) * 512 +
         ((c & 15) << 3) + (((j >> 3) & 3) << 7) + (j & 7);
}

#define WHT_SLOT 8388608L   // ushorts per layer slot (whtH 4M + whtL 4M)

// ---- K0: pack adj>0 into bitmask [32768][16] uint. ----
__global__ __launch_bounds__(256) void maskprep(
    const int* __restrict__ adj, unsigned* __restrict__ mask)
{
  const int gid = blockIdx.x * 256 + threadIdx.x;       // 524288 words
  const int4* __restrict__ p = (const int4*)(adj + (long)gid * 32);
  unsigned m = 0;
#pragma unroll
  for (int k = 0; k < 8; k++) {
    const int4 v = p[k];
    m |= (v.x > 0 ? 1u : 0u) << (4 * k);
    m |= (v.y > 0 ? 1u : 0u) << (4 * k + 1);
    m |= (v.z > 0 ? 1u : 0u) << (4 * k + 2);
    m |= (v.w > 0 ? 1u : 0u) << (4 * k + 3);
  }
  mask[gid] = m;
}

// ---- transpose + hi/lo split a weight matrix: W[K,N] fp32 -> TH/TL[N][K]. ----
__global__ __launch_bounds__(256) void wt_prep(
    const float* __restrict__ W, ushort* __restrict__ TH, ushort* __restrict__ TL,
    const int Kd, const int Nd)
{
  const int idx = blockIdx.x * 256 + threadIdx.x;
  if (idx >= Kd * Nd) return;
  const int k = idx / Nd, n = idx % Nd;
  const float v = W[idx];
  const ushort h = bf16_rne(v);
  TH[(long)n * Kd + k] = h;
  TL[(long)n * Kd + k] = bf16_rne(v - bf16_tof(h));
}

// ---- K1 (3 layers merged): Wh_l = compound @ W_l -> whT_l + src_l/dst_l.
// blockIdx.y = layer. ----
__global__ __launch_bounds__(256) void wh_small(
    const float* __restrict__ A, const float* __restrict__ Wst,
    const float* __restrict__ ast,
    ushort* __restrict__ whtBase, float* __restrict__ srcB, float* __restrict__ dstB)
{
  __shared__ float AsT[34][36];
  __shared__ float Ws[34][128];
  const int t = threadIdx.x;
  const int l = blockIdx.y;
  const float* __restrict__ W = Wst + (long)l * 34 * 128;
  const float* __restrict__ avec = ast + (long)l * 256;
  ushort* __restrict__ whtH = whtBase + (long)l * WHT_SLOT;
  ushort* __restrict__ whtL = whtH + 4194304;
  float* __restrict__ src = srcB + (long)l * 32768;
  float* __restrict__ dst = dstB + (long)l * 32768;
  const long row0 = (long)blockIdx.x * 32;
  const int cg = t & 31, rg = t >> 5;
  {
    const int r = t >> 3, l8 = t & 7;
#pragma unroll
    for (int q = 0; q < 5; q++) {
      int k = l8 + q * 8;
      if (k < 34) AsT[k][r] = A[(row0 + r) * 34 + k];
    }
  }
  {
    int idx = t;
#pragma unroll
    for (int i = 0; i < 17; i++, idx += 256)
      Ws[idx >> 7][idx & 127] = W[idx];
  }
  __syncthreads();

  float acc[4][4];
#pragma unroll
  for (int r = 0; r < 4; r++)
#pragma unroll
    for (int c = 0; c < 4; c++) acc[r][c] = 0.f;
#pragma unroll 2
  for (int k = 0; k < 34; k++) {
    const float4 wv = *(const float4*)&Ws[k][cg * 4];
    const float4 av = *(const float4*)&AsT[k][rg * 4];
#define GFMA(r, a) \
    acc[r][0] += (a) * wv.x; acc[r][1] += (a) * wv.y; \
    acc[r][2] += (a) * wv.z; acc[r][3] += (a) * wv.w;
    GFMA(0, av.x) GFMA(1, av.y) GFMA(2, av.z) GFMA(3, av.w)
#undef GFMA
  }

  {
    const long batch = row0 >> 9;
    const int j = (int)(row0 & 511) + rg * 4;       // j%4 == 0 -> contiguous 4
#pragma unroll
    for (int cc = 0; cc < 4; cc++) {
      const long o = wht_off(batch, cg * 4 + cc, j);
      split_store4(&whtH[o], &whtL[o], acc[0][cc], acc[1][cc], acc[2][cc], acc[3][cc]);
    }
  }

  const float4 a1 = *(const float4*)&avec[cg * 4];
  const float4 a2 = *(const float4*)&avec[128 + cg * 4];
#pragma unroll
  for (int r = 0; r < 4; r++) {
    float s = acc[r][0]*a1.x + acc[r][1]*a1.y + acc[r][2]*a1.z + acc[r][3]*a1.w;
    float d = acc[r][0]*a2.x + acc[r][1]*a2.y + acc[r][2]*a2.z + acc[r][3]*a2.w;
#pragma unroll
    for (int w = 1; w < 32; w <<= 1) {
      s += __shfl_xor(s, w, 64);
      d += __shfl_xor(d, w, 64);
    }
    if (cg == 0) {
      src[row0 + rg * 4 + r] = s;
      dst[row0 + rg * 4 + r] = d;
    }
  }
}

// ---- K2 (fused, multi-layer): single-pass masked softmax -> LDS As
// (unnormalized bf16 p), then out = elu((P @ WhT^T) * 1/rowsum).
// blockIdx.z = layer. Logits in log2 domain; per-row bound m = leaky(si+md)
// with md = block-wide unmasked max of dstS. ----
__global__ __launch_bounds__(256, 4) void fused_attn(
    const unsigned* __restrict__ mask,
    const float* __restrict__ srcB, const float* __restrict__ dstB,
    const ushort* __restrict__ whtBase,
    float* __restrict__ out, const int ostride)
{
  __shared__ ushort As[32][520];
  __shared__ float dstS[512];
  __shared__ float invS[32];
  __shared__ float wredM[4];
  const int t = threadIdx.x;
  const int l = blockIdx.z;
  const float* __restrict__ src = srcB + (long)l * 32768;
  const float* __restrict__ dstv = dstB + (long)l * 32768;
  const ushort* __restrict__ whtH = whtBase + (long)l * WHT_SLOT;
  const ushort* __restrict__ whtL = whtH + 4194304;
  const int ocoff = l * 128;
  // XCD swizzle: per layer 1024 blocks = 8 XCDs x 128; each XCD gets 8 whole
  // batches so a batch's 512KB wht slice is HBM-fetched once, reused via L2.
  const int flat = blockIdx.y * 16 + blockIdx.x;
  const int swz = (flat & 7) * 128 + (flat >> 3);
  const long base = (long)(swz >> 4) * 512;   // batch * 512
  const int i0 = (swz & 15) * 32;             // row tile within batch

  // stage dstS (log2 domain) + block-wide max md (piggyback on the barrier)
  {
    const float d0 = dstv[base + t] * LOG2E;
    const float d1 = dstv[base + t + 256] * LOG2E;
    dstS[t] = d0;
    dstS[t + 256] = d1;
    float mx = fmaxf(d0, d1);
#pragma unroll
    for (int w = 1; w < 64; w <<= 1) mx = fmaxf(mx, __shfl_xor(mx, w, 64));
    if ((t & 63) == 0) wredM[t >> 6] = mx;
  }
  __syncthreads();
  const float md = fmaxf(fmaxf(wredM[0], wredM[1]), fmaxf(wredM[2], wredM[3]));

  // ---- phase 1: single-pass masked softmax -> As bf16, invS = 1/rowsum.
  // 8 threads per row, 64 j each.
  {
    const int r = t >> 3, l8 = t & 7;
    const long i = base + i0 + r;
    const float si = src[i] * LOG2E;
    const unsigned* __restrict__ mrow = mask + i * 16;
    unsigned mw[16];
#pragma unroll
    for (int jj = 0; jj < 16; jj++) mw[jj] = mrow[jj];
    const int sh = l8 * 4;
    const float em = si + md;
    const float m = fmaxf(em, ALPHA * em);   // >= masked max of leaky(si+dv)
    float sum = 0.f;
#pragma unroll
    for (int jj = 0; jj < 16; jj++) {
      const float4 dv = *(const float4*)&dstS[l8 * 4 + jj * 32];
      const unsigned w = mw[jj] >> sh;
      float e0 = si + dv.x, e1 = si + dv.y, e2 = si + dv.z, e3 = si + dv.w;
      e0 = fmaxf(e0, ALPHA * e0) - m; e1 = fmaxf(e1, ALPHA * e1) - m;
      e2 = fmaxf(e2, ALPHA * e2) - m; e3 = fmaxf(e3, ALPHA * e3) - m;
      float p0 = EXP2F(e0), p1 = EXP2F(e1), p2 = EXP2F(e2), p3 = EXP2F(e3);
      p0 = (w & 1u) ? p0 : 0.f;
      p1 = (w & 2u) ? p1 : 0.f;
      p2 = (w & 4u) ? p2 : 0.f;
      p3 = (w & 8u) ? p3 : 0.f;
      sum += (p0 + p1) + (p2 + p3);
      union { __hip_bfloat162 b; unsigned u; } u01, u23;
      u01.b = __float22bfloat162_rn(make_float2(p0, p1));
      u23.b = __float22bfloat162_rn(make_float2(p2, p3));
      *(uint2*)&As[r][l8 * 4 + jj * 32] = make_uint2(u01.u, u23.u);
    }
#pragma unroll
    for (int w = 1; w < 8; w <<= 1) sum += __shfl_xor(sum, w, 64);
    if (l8 == 0) invS[r] = 1.f / sum;
  }
  __syncthreads();

  // ---- phase 2: MFMA aggregation (unroll-2 loop, coalesced fragment B). ----
  const int wv = t >> 6, lane = t & 63;
  const int m16 = lane & 15, q = lane >> 4;
  const int n0 = wv * 32;
  // fragment-order base: batch*65536 + (2*wv)*8192 + lane*8
  const ushort* __restrict__ bH = whtH + base * 128 + wv * 16384 + lane * 8;
  const ushort* __restrict__ bL = whtL + base * 128 + wv * 16384 + lane * 8;
  f32x4 acc00 = {0.f,0.f,0.f,0.f}, acc01 = {0.f,0.f,0.f,0.f};
  f32x4 acc10 = {0.f,0.f,0.f,0.f}, acc11 = {0.f,0.f,0.f,0.f};
#pragma unroll 2
  for (int kb = 0; kb < 16; kb++) {
    const int k0 = kb * 32 + q * 8;
    const s16x8 a0 = *(const s16x8*)&As[m16][k0];
    const s16x8 a1 = *(const s16x8*)&As[16 + m16][k0];
    const int bo = kb * 512;
    const s16x8 b0H = *(const s16x8*)&bH[bo];
    const s16x8 b0L = *(const s16x8*)&bL[bo];
    const s16x8 b1H = *(const s16x8*)&bH[8192 + bo];
    const s16x8 b1L = *(const s16x8*)&bL[8192 + bo];
    acc00 = __builtin_amdgcn_mfma_f32_16x16x32_bf16(a0, b0H, acc00, 0, 0, 0);
    acc01 = __builtin_amdgcn_mfma_f32_16x16x32_bf16(a0, b1H, acc01, 0, 0, 0);
    acc10 = __builtin_amdgcn_mfma_f32_16x16x32_bf16(a1, b0H, acc10, 0, 0, 0);
    acc11 = __builtin_amdgcn_mfma_f32_16x16x32_bf16(a1, b1H, acc11, 0, 0, 0);
    acc00 = __builtin_amdgcn_mfma_f32_16x16x32_bf16(a0, b0L, acc00, 0, 0, 0);
    acc01 = __builtin_amdgcn_mfma_f32_16x16x32_bf16(a0, b1L, acc01, 0, 0, 0);
    acc10 = __builtin_amdgcn_mfma_f32_16x16x32_bf16(a1, b0L, acc10, 0, 0, 0);
    acc11 = __builtin_amdgcn_mfma_f32_16x16x32_bf16(a1, b1L, acc11, 0, 0, 0);
  }
#pragma unroll
  for (int reg = 0; reg < 4; reg++) {
    const int row = q * 4 + reg;
    const float li0 = invS[row], li1 = invS[16 + row];
    float v00 = acc00[reg] * li0, v01 = acc01[reg] * li0;
    float v10 = acc10[reg] * li1, v11 = acc11[reg] * li1;
    v00 = v00 > 0.f ? v00 : __expf(v00) - 1.f;
    v01 = v01 > 0.f ? v01 : __expf(v01) - 1.f;
    v10 = v10 > 0.f ? v10 : __expf(v10) - 1.f;
    v11 = v11 > 0.f ? v11 : __expf(v11) - 1.f;
    float* o0 = out + (base + i0 + row) * (long)ostride + ocoff + n0 + m16;
    float* o1 = out + (base + i0 + 16 + row) * (long)ostride + ocoff + n0 + m16;
    o0[0] = v00; o0[16] = v01;
    o1[0] = v10; o1[16] = v11;
  }
}

// ---- K3/K4: MFMA GEMM, C = A[32768,K] @ BT^T, 32 rows x 128 cols/block.
// A fp32 -> bf16 hi/lo during LDS staging; B pre-split via wt_prep.
// MODE 0: emit whT hi/lo (fragment order) + src/dst.
// MODE 1: +bias +leaky fp32 store. ----
template<int K, int KC, int MODE>
__global__ __launch_bounds__(256) void mfma_gemm(
    const float* __restrict__ A,
    const ushort* __restrict__ BTH, const ushort* __restrict__ BTL,
    const float* __restrict__ bias, float* __restrict__ outF,
    ushort* __restrict__ whtH, ushort* __restrict__ whtL,
    const float* __restrict__ avec, float* __restrict__ src, float* __restrict__ dst,
    const int ostride)
{
  constexpr int KP = KC + 8;
  __shared__ ushort AsH[32][KP];
  __shared__ ushort AsL[32][KP];
  __shared__ float sredS[4][32], sredD[4][32];
  const int t = threadIdx.x;
  const long row0 = (long)blockIdx.x * 32;
  const int ncoff = (MODE == 1) ? blockIdx.y * 128 : 0;

  const int wv = t >> 6, lane = t & 63;
  const int m16 = lane & 15, q = lane >> 4;
  const int n0 = wv * 32;
  const ushort* __restrict__ bh0 = BTH + (long)(ncoff + n0 + m16) * K;
  const ushort* __restrict__ bl0 = BTL + (long)(ncoff + n0 + m16) * K;

  f32x4 acc[2][2];
#pragma unroll
  for (int m = 0; m < 2; m++)
#pragma unroll
    for (int n = 0; n < 2; n++) acc[m][n] = (f32x4){0.f, 0.f, 0.f, 0.f};

  for (int kc = 0; kc < K; kc += KC) {
    constexpr int NIT = (32 * KC / 4) / 256;
#pragma unroll
    for (int it = 0; it < NIT; it++) {
      const int idx = t + it * 256;
      const int r = idx / (KC / 4), k4 = idx % (KC / 4);
      const float4 v = *(const float4*)&A[(row0 + r) * (long)K + kc + k4 * 4];
      split_store4(&AsH[r][k4 * 4], &AsL[r][k4 * 4], v.x, v.y, v.z, v.w);
    }
    __syncthreads();
#pragma unroll
    for (int ks = 0; ks < KC / 32; ks++) {
      const int k0 = ks * 32 + q * 8;
      const s16x8 a0H = *(const s16x8*)&AsH[m16][k0];
      const s16x8 a0L = *(const s16x8*)&AsL[m16][k0];
      const s16x8 a1H = *(const s16x8*)&AsH[16 + m16][k0];
      const s16x8 a1L = *(const s16x8*)&AsL[16 + m16][k0];
      const int kg = kc + k0;
      const s16x8 b0H = *(const s16x8*)&bh0[kg];
      const s16x8 b0L = *(const s16x8*)&bl0[kg];
      const s16x8 b1H = *(const s16x8*)&bh0[16 * K + kg];
      const s16x8 b1L = *(const s16x8*)&bl0[16 * K + kg];
      acc[0][0] = __builtin_amdgcn_mfma_f32_16x16x32_bf16(a0H, b0H, acc[0][0], 0, 0, 0);
      acc[0][1] = __builtin_amdgcn_mfma_f32_16x16x32_bf16(a0H, b1H, acc[0][1], 0, 0, 0);
      acc[1][0] = __builtin_amdgcn_mfma_f32_16x16x32_bf16(a1H, b0H, acc[1][0], 0, 0, 0);
      acc[1][1] = __builtin_amdgcn_mfma_f32_16x16x32_bf16(a1H, b1H, acc[1][1], 0, 0, 0);
      acc[0][0] = __builtin_amdgcn_mfma_f32_16x16x32_bf16(a0L, b0H, acc[0][0], 0, 0, 0);
      acc[0][1] = __builtin_amdgcn_mfma_f32_16x16x32_bf16(a0L, b1H, acc[0][1], 0, 0, 0);
      acc[1][0] = __builtin_amdgcn_mfma_f32_16x16x32_bf16(a1L, b0H, acc[1][0], 0, 0, 0);
      acc[1][1] = __builtin_amdgcn_mfma_f32_16x16x32_bf16(a1L, b1H, acc[1][1], 0, 0, 0);
      acc[0][0] = __builtin_amdgcn_mfma_f32_16x16x32_bf16(a0H, b0L, acc[0][0], 0, 0, 0);
      acc[0][1] = __builtin_amdgcn_mfma_f32_16x16x32_bf16(a0H, b1L, acc[0][1], 0, 0, 0);
      acc[1][0] = __builtin_amdgcn_mfma_f32_16x16x32_bf16(a1H, b0L, acc[1][0], 0, 0, 0);
      acc[1][1] = __builtin_amdgcn_mfma_f32_16x16x32_bf16(a1H, b1L, acc[1][1], 0, 0, 0);
    }
    __syncthreads();
  }

  if (MODE == 0) {
    // whT hi/lo store in fragment order
    const long batch = row0 >> 9;
    const int iloc = (int)(row0 & 511);
#pragma unroll
    for (int m = 0; m < 2; m++)
#pragma unroll
      for (int n = 0; n < 2; n++) {
        const int c = n0 + n * 16 + m16;
        const int j = iloc + m * 16 + q * 4;        // j%4 == 0 -> contiguous 4
        const long o = wht_off(batch, c, j);
        const f32x4 v = acc[m][n];
        split_store4(&whtH[o], &whtL[o], v[0], v[1], v[2], v[3]);
      }
    // fused src/dst: reduce over cols (16 lanes x 2 n-tiles per wave, 4 waves)
    const float a10 = avec[n0 + m16], a11 = avec[n0 + 16 + m16];
    const float a20 = avec[128 + n0 + m16], a21 = avec[128 + n0 + 16 + m16];
#pragma unroll
    for (int m = 0; m < 2; m++) {
#pragma unroll
      for (int reg = 0; reg < 4; reg++) {
        float s = acc[m][0][reg] * a10 + acc[m][1][reg] * a11;
        float d = acc[m][0][reg] * a20 + acc[m][1][reg] * a21;
#pragma unroll
        for (int w = 1; w < 16; w <<= 1) {
          s += __shfl_xor(s, w, 64);
          d += __shfl_xor(d, w, 64);
        }
        if (m16 == 0) {
          const int row = m * 16 + q * 4 + reg;
          sredS[wv][row] = s;
          sredD[wv][row] = d;
        }
      }
    }
    __syncthreads();
    if (t < 32) {
      const float s = sredS[0][t] + sredS[1][t] + sredS[2][t] + sredS[3][t];
      const float d = sredD[0][t] + sredD[1][t] + sredD[2][t] + sredD[3][t];
      src[row0 + t] = s;
      dst[row0 + t] = d;
    }
  } else {
#pragma unroll
    for (int m = 0; m < 2; m++)
#pragma unroll
      for (int n = 0; n < 2; n++) {
        const int c = ncoff + n0 + n * 16 + m16;
        const float bv = bias[c];
#pragma unroll
        for (int reg = 0; reg < 4; reg++) {
          float v = acc[m][n][reg] + bv;
          v = fmaxf(v, ALPHA * v);
          outF[(row0 + m * 16 + q * 4 + reg) * (long)ostride + c] = v;
        }
      }
  }
}

extern "C" void kernel_launch(void* const* d_in, const int* in_sizes, int n_in,
                              void* d_out, int out_size, void* d_ws, size_t ws_size,
                              hipStream_t stream) {
  const float* compound = (const float*)d_in[0];
  const int*   adj      = (const int*)d_in[1];
  const float* W_stack  = (const float*)d_in[2];
  const float* a_stack  = (const float*)d_in[3];
  const float* W_out    = (const float*)d_in[4];
  const float* a_out    = (const float*)d_in[5];
  const float* Wc       = (const float*)d_in[6];
  const float* bc       = (const float*)d_in[7];
  float* out = (float*)d_out;

  // workspace: wht slots for 3 layers (48MB), then multi (50MB).
  // x aliases multi head; WcT parked in dead multi tail.
  ushort* wht_all = (ushort*)d_ws;                    // 3 x 16MB slots
  float* f     = (float*)d_ws;
  float* multi = f + 12582912;                        // 12,582,912 floats
  float* x     = multi;                               // aliases multi head
  ushort* WcT_H = (ushort*)(multi + 5000000);         // beyond x's 4.19M floats
  ushort* WcT_L = WcT_H + 32768;

  // d_out parking (dead until final GEMM overwrites):
  // mask 524288 uints | src[4] | dst[4] | WoT_H/L
  unsigned* mask = (unsigned*)d_out;
  float* doutF = (float*)d_out;
  float* srcB = doutF + 524288;                       // 4 x 32768
  float* dstB = srcB + 4 * 32768;                     // 4 x 32768
  ushort* WoT_H = (ushort*)(dstB + 4 * 32768);        // 98304 ushorts
  ushort* WoT_L = WoT_H + 98304;
  float* src3 = srcB + 3 * 32768;
  float* dst3 = dstB + 3 * 32768;

  maskprep<<<2048, 256, 0, stream>>>(adj, mask);
  // 3 GAT heads in two merged dispatches
  wh_small<<<dim3(1024, 3), 256, 0, stream>>>(
      compound, W_stack, a_stack, wht_all, srcB, dstB);
  fused_attn<<<dim3(16, 64, 3), 256, 0, stream>>>(
      mask, srcB, dstB, wht_all, multi, 384);
  // layer 4: Wh = multi @ W_out  (MFMA, emits whT slot-0 + src/dst slot-3)
  wt_prep<<<192, 256, 0, stream>>>(W_out, WoT_H, WoT_L, 384, 128);
  mfma_gemm<384, 192, 0><<<1024, 256, 0, stream>>>(
      multi, WoT_H, WoT_L, nullptr, nullptr, wht_all, wht_all + 4194304,
      a_out, src3, dst3, 0);
  fused_attn<<<dim3(16, 64, 1), 256, 0, stream>>>(
      mask, src3, dst3, wht_all, x, 128);
  // final: out = leaky(x @ Wc + bc)  (MFMA)
  wt_prep<<<128, 256, 0, stream>>>(Wc, WcT_H, WcT_L, 128, 256);
  mfma_gemm<128, 128, 1><<<dim3(1024, 2), 256, 0, stream>>>(
      x, WcT_H, WcT_L, bc, out, nullptr, nullptr, nullptr, nullptr, nullptr, 256);
}

// Round 9
// 273.518 us; speedup vs baseline: 1.4715x; 1.0288x over previous
//
#include <hip/hip_runtime.h>
#include <hip/hip_bf16.h>
#include <math.h>

// GAT predictor: B=64, N=512, ATOM=34, GAT=128, HID=256, 3 layers + out.
// Round-16: fix round-14/15's NaN — wt_prep(Wc) in the front union wrote WcT
// at multi+5M floats, which the 3-layer fused_attn then clobbered (multi
// spans 12.58M floats). Wc prep is restored to its round-13-proven slot:
// after the single fused_attn, when only x (4.19M floats) is live in multi.
// front_union keeps the safe pieces: [0,3072) wh_small x3, [3072,5120)
// maskprep (134MB HBM read overlaps wh compute), [5120,5312) wt_prep(W_out)
// (WoT parks in d_out, no writer touches it before gemm384 reads it).
// LOG2E pre-scale stays folded into src/dst producers. 6 dispatches.
// ws: wht[3] 48MB | multi 50MB (x aliases head; WcT parked at +5M floats,
//     written only after multi is dead)
// d_out: mask 2.1MB | src[4]/dst[4] 1MB | WoT 0.4MB  (until final GEMM)

#define ALPHA 0.2f
#define LOG2E 1.44269504088896f

#if __has_builtin(__builtin_amdgcn_exp2f)
#define EXP2F(x) __builtin_amdgcn_exp2f(x)
#else
extern "C" __device__ float __ocml_exp2_f32(float);
#define EXP2F(x) __ocml_exp2_f32(x)
#endif

typedef __attribute__((ext_vector_type(8))) short s16x8;   // 8 bf16 (4 VGPRs)
typedef __attribute__((ext_vector_type(4))) float f32x4;

__device__ __forceinline__ ushort bf16_rne(float f) {
  union { float f; unsigned u; } v; v.f = f;
  unsigned r = v.u + 0x7FFFu + ((v.u >> 16) & 1u);
  return (ushort)(r >> 16);
}
__device__ __forceinline__ float bf16_tof(ushort h) {
  union { unsigned u; float f; } v; v.u = ((unsigned)h) << 16;
  return v.f;
}
__device__ __forceinline__ void split_store4(
    ushort* __restrict__ ph, ushort* __restrict__ pl,
    float v0, float v1, float v2, float v3) {
  ushort h0 = bf16_rne(v0), h1 = bf16_rne(v1), h2 = bf16_rne(v2), h3 = bf16_rne(v3);
  *(ushort4*)ph = make_ushort4(h0, h1, h2, h3);
  *(ushort4*)pl = make_ushort4(bf16_rne(v0 - bf16_tof(h0)), bf16_rne(v1 - bf16_tof(h1)),
                               bf16_rne(v2 - bf16_tof(h2)), bf16_rne(v3 - bf16_tof(h3)));
}

// wht fragment-order offset: batch*65536 + (col/16)*8192 + (j/32)*512
//   + (col%16)*8 + ((j>>3)&3)*128 + (j&7)   [j = node index = GEMM k]
__device__ __forceinline__ long wht_off(long batch, int c, int j) {
  return batch * 65536 + (long)(c >> 4) * 8192 + (j >> 5) * 512 +
         ((c & 15) << 3) + (((j >> 3) & 3) << 7) + (j & 7);
}

#define WHT_SLOT 8388608L   // ushorts per layer slot (whtH 4M + whtL 4M)

// ---- standalone wt_prep: W[K,N] fp32 -> TH/TL[N][K] bf16 hi/lo ----
__global__ __launch_bounds__(256) void wt_prep(
    const float* __restrict__ W, ushort* __restrict__ TH, ushort* __restrict__ TL,
    const int Kd, const int Nd)
{
  const int idx = blockIdx.x * 256 + threadIdx.x;
  if (idx >= Kd * Nd) return;
  const int k = idx / Nd, n = idx % Nd;
  const float v = W[idx];
  const ushort h = bf16_rne(v);
  TH[(long)n * Kd + k] = h;
  TL[(long)n * Kd + k] = bf16_rne(v - bf16_tof(h));
}

// ---- K0 (front union): wh_small x3 | maskprep | wt_prep(W_out)
// branch on blockIdx.x. Overlaps the 134MB adj read with the wh compute. ----
__global__ __launch_bounds__(256) void front_union(
    const float* __restrict__ A, const float* __restrict__ Wst,
    const float* __restrict__ ast,
    ushort* __restrict__ whtBase, float* __restrict__ srcB, float* __restrict__ dstB,
    const int* __restrict__ adj, unsigned* __restrict__ mask,
    const float* __restrict__ W_out, ushort* __restrict__ WoT_H, ushort* __restrict__ WoT_L)
{
  __shared__ float AsT[34][36];
  __shared__ float Ws[34][128];
  const int bid = blockIdx.x;
  const int t = threadIdx.x;

  if (bid >= 3072) {
    if (bid < 5120) {
      // ---- maskprep: pack adj>0 into bitmask [32768][16] uint ----
      const int gid = (bid - 3072) * 256 + t;
      const int4* __restrict__ p = (const int4*)(adj + (long)gid * 32);
      unsigned m = 0;
#pragma unroll
      for (int k = 0; k < 8; k++) {
        const int4 v = p[k];
        m |= (v.x > 0 ? 1u : 0u) << (4 * k);
        m |= (v.y > 0 ? 1u : 0u) << (4 * k + 1);
        m |= (v.z > 0 ? 1u : 0u) << (4 * k + 2);
        m |= (v.w > 0 ? 1u : 0u) << (4 * k + 3);
      }
      mask[gid] = m;
    } else {
      // ---- wt_prep(W_out): [384,128] fp32 -> WoT[128][384] bf16 hi/lo ----
      const int idx = (bid - 5120) * 256 + t;   // 192 blocks = 49152 exact
      const int k = idx / 128, n = idx % 128;
      const float v = W_out[idx];
      const ushort h = bf16_rne(v);
      WoT_H[(long)n * 384 + k] = h;
      WoT_L[(long)n * 384 + k] = bf16_rne(v - bf16_tof(h));
    }
    return;
  }

  // ---- wh_small: Wh_l = compound @ W_l -> whT_l (fragment order) + src/dst
  const int l = bid >> 10;
  const float* __restrict__ W = Wst + (long)l * 34 * 128;
  const float* __restrict__ avec = ast + (long)l * 256;
  ushort* __restrict__ whtH = whtBase + (long)l * WHT_SLOT;
  ushort* __restrict__ whtL = whtH + 4194304;
  float* __restrict__ src = srcB + (long)l * 32768;
  float* __restrict__ dst = dstB + (long)l * 32768;
  const long row0 = (long)(bid & 1023) * 32;
  const int cg = t & 31, rg = t >> 5;
  {
    const int r = t >> 3, l8 = t & 7;
#pragma unroll
    for (int q = 0; q < 5; q++) {
      int k = l8 + q * 8;
      if (k < 34) AsT[k][r] = A[(row0 + r) * 34 + k];
    }
  }
  {
    int idx = t;
#pragma unroll
    for (int i = 0; i < 17; i++, idx += 256)
      Ws[idx >> 7][idx & 127] = W[idx];
  }
  __syncthreads();

  float acc[4][4];
#pragma unroll
  for (int r = 0; r < 4; r++)
#pragma unroll
    for (int c = 0; c < 4; c++) acc[r][c] = 0.f;
#pragma unroll 2
  for (int k = 0; k < 34; k++) {
    const float4 wv = *(const float4*)&Ws[k][cg * 4];
    const float4 av = *(const float4*)&AsT[k][rg * 4];
#define GFMA(r, a) \
    acc[r][0] += (a) * wv.x; acc[r][1] += (a) * wv.y; \
    acc[r][2] += (a) * wv.z; acc[r][3] += (a) * wv.w;
    GFMA(0, av.x) GFMA(1, av.y) GFMA(2, av.z) GFMA(3, av.w)
#undef GFMA
  }

  {
    const long batch = row0 >> 9;
    const int j = (int)(row0 & 511) + rg * 4;       // j%4 == 0 -> contiguous 4
#pragma unroll
    for (int cc = 0; cc < 4; cc++) {
      const long o = wht_off(batch, cg * 4 + cc, j);
      split_store4(&whtH[o], &whtL[o], acc[0][cc], acc[1][cc], acc[2][cc], acc[3][cc]);
    }
  }

  const float4 a1 = *(const float4*)&avec[cg * 4];
  const float4 a2 = *(const float4*)&avec[128 + cg * 4];
#pragma unroll
  for (int r = 0; r < 4; r++) {
    float s = acc[r][0]*a1.x + acc[r][1]*a1.y + acc[r][2]*a1.z + acc[r][3]*a1.w;
    float d = acc[r][0]*a2.x + acc[r][1]*a2.y + acc[r][2]*a2.z + acc[r][3]*a2.w;
#pragma unroll
    for (int w = 1; w < 32; w <<= 1) {
      s += __shfl_xor(s, w, 64);
      d += __shfl_xor(d, w, 64);
    }
    if (cg == 0) {
      src[row0 + rg * 4 + r] = s * LOG2E;   // log2-domain at producer
      dst[row0 + rg * 4 + r] = d * LOG2E;
    }
  }
}

// ---- K2 (fused, multi-layer): single-pass masked softmax -> LDS As
// (unnormalized bf16 p), then out = elu((P @ WhT^T) * 1/rowsum).
// blockIdx.z = layer. Logits already log2-domain; per-row bound
// m = leaky(si+md), md = block-wide unmasked max of dstS. ----
__global__ __launch_bounds__(256, 4) void fused_attn(
    const unsigned* __restrict__ mask,
    const float* __restrict__ srcB, const float* __restrict__ dstB,
    const ushort* __restrict__ whtBase,
    float* __restrict__ out, const int ostride)
{
  __shared__ ushort As[32][520];
  __shared__ float dstS[512];
  __shared__ float invS[32];
  __shared__ float wredM[4];
  const int t = threadIdx.x;
  const int l = blockIdx.z;
  const float* __restrict__ src = srcB + (long)l * 32768;
  const float* __restrict__ dstv = dstB + (long)l * 32768;
  const ushort* __restrict__ whtH = whtBase + (long)l * WHT_SLOT;
  const ushort* __restrict__ whtL = whtH + 4194304;
  const int ocoff = l * 128;
  // XCD swizzle: per layer 1024 blocks = 8 XCDs x 128; each XCD gets 8 whole
  // batches so a batch's 512KB wht slice is HBM-fetched once, reused via L2.
  const int flat = blockIdx.y * 16 + blockIdx.x;
  const int swz = (flat & 7) * 128 + (flat >> 3);
  const long base = (long)(swz >> 4) * 512;   // batch * 512
  const int i0 = (swz & 15) * 32;             // row tile within batch

  // stage dstS (already log2 domain) + block-wide max md
  {
    const float d0 = dstv[base + t];
    const float d1 = dstv[base + t + 256];
    dstS[t] = d0;
    dstS[t + 256] = d1;
    float mx = fmaxf(d0, d1);
#pragma unroll
    for (int w = 1; w < 64; w <<= 1) mx = fmaxf(mx, __shfl_xor(mx, w, 64));
    if ((t & 63) == 0) wredM[t >> 6] = mx;
  }
  __syncthreads();
  const float md = fmaxf(fmaxf(wredM[0], wredM[1]), fmaxf(wredM[2], wredM[3]));

  // ---- phase 1: single-pass masked softmax -> As bf16, invS = 1/rowsum.
  // 8 threads per row, 64 j each.
  {
    const int r = t >> 3, l8 = t & 7;
    const long i = base + i0 + r;
    const float si = src[i];
    const unsigned* __restrict__ mrow = mask + i * 16;
    unsigned mw[16];
#pragma unroll
    for (int jj = 0; jj < 16; jj++) mw[jj] = mrow[jj];
    const int sh = l8 * 4;
    const float em = si + md;
    const float m = fmaxf(em, ALPHA * em);   // >= masked max of leaky(si+dv)
    float sum = 0.f;
#pragma unroll
    for (int jj = 0; jj < 16; jj++) {
      const float4 dv = *(const float4*)&dstS[l8 * 4 + jj * 32];
      const unsigned w = mw[jj] >> sh;
      float e0 = si + dv.x, e1 = si + dv.y, e2 = si + dv.z, e3 = si + dv.w;
      e0 = fmaxf(e0, ALPHA * e0) - m; e1 = fmaxf(e1, ALPHA * e1) - m;
      e2 = fmaxf(e2, ALPHA * e2) - m; e3 = fmaxf(e3, ALPHA * e3) - m;
      float p0 = EXP2F(e0), p1 = EXP2F(e1), p2 = EXP2F(e2), p3 = EXP2F(e3);
      p0 = (w & 1u) ? p0 : 0.f;
      p1 = (w & 2u) ? p1 : 0.f;
      p2 = (w & 4u) ? p2 : 0.f;
      p3 = (w & 8u) ? p3 : 0.f;
      sum += (p0 + p1) + (p2 + p3);
      union { __hip_bfloat162 b; unsigned u; } u01, u23;
      u01.b = __float22bfloat162_rn(make_float2(p0, p1));
      u23.b = __float22bfloat162_rn(make_float2(p2, p3));
      *(uint2*)&As[r][l8 * 4 + jj * 32] = make_uint2(u01.u, u23.u);
    }
#pragma unroll
    for (int w = 1; w < 8; w <<= 1) sum += __shfl_xor(sum, w, 64);
    if (l8 == 0) invS[r] = 1.f / sum;
  }
  __syncthreads();

  // ---- phase 2: MFMA aggregation (unroll-2 loop, coalesced fragment B). ----
  const int wv = t >> 6, lane = t & 63;
  const int m16 = lane & 15, q = lane >> 4;
  const int n0 = wv * 32;
  // fragment-order base: batch*65536 + (2*wv)*8192 + lane*8
  const ushort* __restrict__ bH = whtH + base * 128 + wv * 16384 + lane * 8;
  const ushort* __restrict__ bL = whtL + base * 128 + wv * 16384 + lane * 8;
  f32x4 acc00 = {0.f,0.f,0.f,0.f}, acc01 = {0.f,0.f,0.f,0.f};
  f32x4 acc10 = {0.f,0.f,0.f,0.f}, acc11 = {0.f,0.f,0.f,0.f};
#pragma unroll 2
  for (int kb = 0; kb < 16; kb++) {
    const int k0 = kb * 32 + q * 8;
    const s16x8 a0 = *(const s16x8*)&As[m16][k0];
    const s16x8 a1 = *(const s16x8*)&As[16 + m16][k0];
    const int bo = kb * 512;
    const s16x8 b0H = *(const s16x8*)&bH[bo];
    const s16x8 b0L = *(const s16x8*)&bL[bo];
    const s16x8 b1H = *(const s16x8*)&bH[8192 + bo];
    const s16x8 b1L = *(const s16x8*)&bL[8192 + bo];
    acc00 = __builtin_amdgcn_mfma_f32_16x16x32_bf16(a0, b0H, acc00, 0, 0, 0);
    acc01 = __builtin_amdgcn_mfma_f32_16x16x32_bf16(a0, b1H, acc01, 0, 0, 0);
    acc10 = __builtin_amdgcn_mfma_f32_16x16x32_bf16(a1, b0H, acc10, 0, 0, 0);
    acc11 = __builtin_amdgcn_mfma_f32_16x16x32_bf16(a1, b1H, acc11, 0, 0, 0);
    acc00 = __builtin_amdgcn_mfma_f32_16x16x32_bf16(a0, b0L, acc00, 0, 0, 0);
    acc01 = __builtin_amdgcn_mfma_f32_16x16x32_bf16(a0, b1L, acc01, 0, 0, 0);
    acc10 = __builtin_amdgcn_mfma_f32_16x16x32_bf16(a1, b0L, acc10, 0, 0, 0);
    acc11 = __builtin_amdgcn_mfma_f32_16x16x32_bf16(a1, b1L, acc11, 0, 0, 0);
  }
#pragma unroll
  for (int reg = 0; reg < 4; reg++) {
    const int row = q * 4 + reg;
    const float li0 = invS[row], li1 = invS[16 + row];
    float v00 = acc00[reg] * li0, v01 = acc01[reg] * li0;
    float v10 = acc10[reg] * li1, v11 = acc11[reg] * li1;
    v00 = v00 > 0.f ? v00 : __expf(v00) - 1.f;
    v01 = v01 > 0.f ? v01 : __expf(v01) - 1.f;
    v10 = v10 > 0.f ? v10 : __expf(v10) - 1.f;
    v11 = v11 > 0.f ? v11 : __expf(v11) - 1.f;
    float* o0 = out + (base + i0 + row) * (long)ostride + ocoff + n0 + m16;
    float* o1 = out + (base + i0 + 16 + row) * (long)ostride + ocoff + n0 + m16;
    o0[0] = v00; o0[16] = v01;
    o1[0] = v10; o1[16] = v11;
  }
}

// ---- K3/K4: MFMA GEMM, C = A[32768,K] @ BT^T, 32 rows x 128 cols/block.
// A fp32 -> bf16 hi/lo during LDS staging; B pre-split via wt_prep.
// MODE 0: emit whT hi/lo (fragment order) + src/dst (log2-scaled).
// MODE 1: +bias +leaky fp32 store. ----
template<int K, int KC, int MODE>
__global__ __launch_bounds__(256) void mfma_gemm(
    const float* __restrict__ A,
    const ushort* __restrict__ BTH, const ushort* __restrict__ BTL,
    const float* __restrict__ bias, float* __restrict__ outF,
    ushort* __restrict__ whtH, ushort* __restrict__ whtL,
    const float* __restrict__ avec, float* __restrict__ src, float* __restrict__ dst,
    const int ostride)
{
  constexpr int KP = KC + 8;
  __shared__ ushort AsH[32][KP];
  __shared__ ushort AsL[32][KP];
  __shared__ float sredS[4][32], sredD[4][32];
  const int t = threadIdx.x;
  const long row0 = (long)blockIdx.x * 32;
  const int ncoff = (MODE == 1) ? blockIdx.y * 128 : 0;

  const int wv = t >> 6, lane = t & 63;
  const int m16 = lane & 15, q = lane >> 4;
  const int n0 = wv * 32;
  const ushort* __restrict__ bh0 = BTH + (long)(ncoff + n0 + m16) * K;
  const ushort* __restrict__ bl0 = BTL + (long)(ncoff + n0 + m16) * K;

  f32x4 acc[2][2];
#pragma unroll
  for (int m = 0; m < 2; m++)
#pragma unroll
    for (int n = 0; n < 2; n++) acc[m][n] = (f32x4){0.f, 0.f, 0.f, 0.f};

  for (int kc = 0; kc < K; kc += KC) {
    constexpr int NIT = (32 * KC / 4) / 256;
#pragma unroll
    for (int it = 0; it < NIT; it++) {
      const int idx = t + it * 256;
      const int r = idx / (KC / 4), k4 = idx % (KC / 4);
      const float4 v = *(const float4*)&A[(row0 + r) * (long)K + kc + k4 * 4];
      split_store4(&AsH[r][k4 * 4], &AsL[r][k4 * 4], v.x, v.y, v.z, v.w);
    }
    __syncthreads();
#pragma unroll
    for (int ks = 0; ks < KC / 32; ks++) {
      const int k0 = ks * 32 + q * 8;
      const s16x8 a0H = *(const s16x8*)&AsH[m16][k0];
      const s16x8 a0L = *(const s16x8*)&AsL[m16][k0];
      const s16x8 a1H = *(const s16x8*)&AsH[16 + m16][k0];
      const s16x8 a1L = *(const s16x8*)&AsL[16 + m16][k0];
      const int kg = kc + k0;
      const s16x8 b0H = *(const s16x8*)&bh0[kg];
      const s16x8 b0L = *(const s16x8*)&bl0[kg];
      const s16x8 b1H = *(const s16x8*)&bh0[16 * K + kg];
      const s16x8 b1L = *(const s16x8*)&bl0[16 * K + kg];
      acc[0][0] = __builtin_amdgcn_mfma_f32_16x16x32_bf16(a0H, b0H, acc[0][0], 0, 0, 0);
      acc[0][1] = __builtin_amdgcn_mfma_f32_16x16x32_bf16(a0H, b1H, acc[0][1], 0, 0, 0);
      acc[1][0] = __builtin_amdgcn_mfma_f32_16x16x32_bf16(a1H, b0H, acc[1][0], 0, 0, 0);
      acc[1][1] = __builtin_amdgcn_mfma_f32_16x16x32_bf16(a1H, b1H, acc[1][1], 0, 0, 0);
      acc[0][0] = __builtin_amdgcn_mfma_f32_16x16x32_bf16(a0L, b0H, acc[0][0], 0, 0, 0);
      acc[0][1] = __builtin_amdgcn_mfma_f32_16x16x32_bf16(a0L, b1H, acc[0][1], 0, 0, 0);
      acc[1][0] = __builtin_amdgcn_mfma_f32_16x16x32_bf16(a1L, b0H, acc[1][0], 0, 0, 0);
      acc[1][1] = __builtin_amdgcn_mfma_f32_16x16x32_bf16(a1L, b1H, acc[1][1], 0, 0, 0);
      acc[0][0] = __builtin_amdgcn_mfma_f32_16x16x32_bf16(a0H, b0L, acc[0][0], 0, 0, 0);
      acc[0][1] = __builtin_amdgcn_mfma_f32_16x16x32_bf16(a0H, b1L, acc[0][1], 0, 0, 0);
      acc[1][0] = __builtin_amdgcn_mfma_f32_16x16x32_bf16(a1H, b0L, acc[1][0], 0, 0, 0);
      acc[1][1] = __builtin_amdgcn_mfma_f32_16x16x32_bf16(a1H, b1L, acc[1][1], 0, 0, 0);
    }
    __syncthreads();
  }

  if (MODE == 0) {
    // whT hi/lo store in fragment order
    const long batch = row0 >> 9;
    const int iloc = (int)(row0 & 511);
#pragma unroll
    for (int m = 0; m < 2; m++)
#pragma unroll
      for (int n = 0; n < 2; n++) {
        const int c = n0 + n * 16 + m16;
        const int j = iloc + m * 16 + q * 4;        // j%4 == 0 -> contiguous 4
        const long o = wht_off(batch, c, j);
        const f32x4 v = acc[m][n];
        split_store4(&whtH[o], &whtL[o], v[0], v[1], v[2], v[3]);
      }
    // fused src/dst: reduce over cols (16 lanes x 2 n-tiles per wave, 4 waves)
    const float a10 = avec[n0 + m16], a11 = avec[n0 + 16 + m16];
    const float a20 = avec[128 + n0 + m16], a21 = avec[128 + n0 + 16 + m16];
#pragma unroll
    for (int m = 0; m < 2; m++) {
#pragma unroll
      for (int reg = 0; reg < 4; reg++) {
        float s = acc[m][0][reg] * a10 + acc[m][1][reg] * a11;
        float d = acc[m][0][reg] * a20 + acc[m][1][reg] * a21;
#pragma unroll
        for (int w = 1; w < 16; w <<= 1) {
          s += __shfl_xor(s, w, 64);
          d += __shfl_xor(d, w, 64);
        }
        if (m16 == 0) {
          const int row = m * 16 + q * 4 + reg;
          sredS[wv][row] = s;
          sredD[wv][row] = d;
        }
      }
    }
    __syncthreads();
    if (t < 32) {
      const float s = sredS[0][t] + sredS[1][t] + sredS[2][t] + sredS[3][t];
      const float d = sredD[0][t] + sredD[1][t] + sredD[2][t] + sredD[3][t];
      src[row0 + t] = s * LOG2E;   // log2-domain at producer
      dst[row0 + t] = d * LOG2E;
    }
  } else {
#pragma unroll
    for (int m = 0; m < 2; m++)
#pragma unroll
      for (int n = 0; n < 2; n++) {
        const int c = ncoff + n0 + n * 16 + m16;
        const float bv = bias[c];
#pragma unroll
        for (int reg = 0; reg < 4; reg++) {
          float v = acc[m][n][reg] + bv;
          v = fmaxf(v, ALPHA * v);
          outF[(row0 + m * 16 + q * 4 + reg) * (long)ostride + c] = v;
        }
      }
  }
}

extern "C" void kernel_launch(void* const* d_in, const int* in_sizes, int n_in,
                              void* d_out, int out_size, void* d_ws, size_t ws_size,
                              hipStream_t stream) {
  const float* compound = (const float*)d_in[0];
  const int*   adj      = (const int*)d_in[1];
  const float* W_stack  = (const float*)d_in[2];
  const float* a_stack  = (const float*)d_in[3];
  const float* W_out    = (const float*)d_in[4];
  const float* a_out    = (const float*)d_in[5];
  const float* Wc       = (const float*)d_in[6];
  const float* bc       = (const float*)d_in[7];
  float* out = (float*)d_out;

  // workspace: wht slots for 3 layers (48MB), then multi (50MB).
  // x aliases multi head; WcT parked in dead multi tail (written only after
  // multi's last reader, gemm384, has run).
  ushort* wht_all = (ushort*)d_ws;                    // 3 x 16MB slots
  float* f     = (float*)d_ws;
  float* multi = f + 12582912;                        // 12,582,912 floats
  float* x     = multi;                               // aliases multi head
  ushort* WcT_H = (ushort*)(multi + 5000000);         // beyond x's 4.19M floats
  ushort* WcT_L = WcT_H + 32768;

  // d_out parking (dead until final GEMM overwrites):
  // mask 524288 uints | src[4] | dst[4] | WoT_H/L
  unsigned* mask = (unsigned*)d_out;
  float* doutF = (float*)d_out;
  float* srcB = doutF + 524288;                       // 4 x 32768
  float* dstB = srcB + 4 * 32768;                     // 4 x 32768
  ushort* WoT_H = (ushort*)(dstB + 4 * 32768);        // 98304 ushorts
  ushort* WoT_L = WoT_H + 98304;
  float* src3 = srcB + 3 * 32768;
  float* dst3 = dstB + 3 * 32768;

  // front: wh_small x3 + maskprep + wt_prep(W_out) in ONE dispatch
  front_union<<<5312, 256, 0, stream>>>(
      compound, W_stack, a_stack, wht_all, srcB, dstB,
      adj, mask, W_out, WoT_H, WoT_L);
  // 3 GAT heads
  fused_attn<<<dim3(16, 64, 3), 256, 0, stream>>>(
      mask, srcB, dstB, wht_all, multi, 384);
  // layer 4: Wh = multi @ W_out  (MFMA, emits whT slot-0 + src/dst slot-3)
  mfma_gemm<384, 192, 0><<<1024, 256, 0, stream>>>(
      multi, WoT_H, WoT_L, nullptr, nullptr, wht_all, wht_all + 4194304,
      a_out, src3, dst3, 0);
  fused_attn<<<dim3(16, 64, 1), 256, 0, stream>>>(
      mask, src3, dst3, wht_all, x, 128);
  // Wc prep AFTER multi is dead (only x's 4.19M floats live) — round-13 slot
  wt_prep<<<128, 256, 0, stream>>>(Wc, WcT_H, WcT_L, 128, 256);
  // final: out = leaky(x @ Wc + bc)  (MFMA)
  mfma_gemm<128, 128, 1><<<dim3(1024, 2), 256, 0, stream>>>(
      x, WcT_H, WcT_L, bc, out, nullptr, nullptr, nullptr, nullptr, nullptr, 256);
}

// Round 10
// 257.454 us; speedup vs baseline: 1.5633x; 1.0624x over previous
//
#include <hip/hip_runtime.h>
#include <hip/hip_bf16.h>
#include <math.h>

// GAT predictor: B=64, N=512, ATOM=34, GAT=128, HID=256, 3 layers + out.
// Round-17: redo round-9's B prefetch correctly. Round-9 spilled because the
// ping-pong lived in arrays indexed [kb&1] (rule #20: runtime-indexed
// ext_vector arrays -> scratch at IR-gen; WRITE_SIZE 24->54MB proved it).
// Now: 8 NAMED s16x8 registers (pa0H..pb1L, 32 VGPR), even/odd explicitly
// unrolled loop, first two k-blocks issued at kernel entry (latency hides
// under softmax). VGPR 52 -> ~90 < 128 cap, no spill expected (verify:
// WRITE_SIZE must stay 49152). Everything else identical to round-16
// (front_union, single-pass softmax, fragment-order wht, log2 producers).
// ws: wht[3] 48MB | multi 50MB (x aliases head; WcT parked at +5M floats,
//     written only after multi is dead)
// d_out: mask 2.1MB | src[4]/dst[4] 1MB | WoT 0.4MB  (until final GEMM)

#define ALPHA 0.2f
#define LOG2E 1.44269504088896f

#if __has_builtin(__builtin_amdgcn_exp2f)
#define EXP2F(x) __builtin_amdgcn_exp2f(x)
#else
extern "C" __device__ float __ocml_exp2_f32(float);
#define EXP2F(x) __ocml_exp2_f32(x)
#endif

typedef __attribute__((ext_vector_type(8))) short s16x8;   // 8 bf16 (4 VGPRs)
typedef __attribute__((ext_vector_type(4))) float f32x4;

__device__ __forceinline__ ushort bf16_rne(float f) {
  union { float f; unsigned u; } v; v.f = f;
  unsigned r = v.u + 0x7FFFu + ((v.u >> 16) & 1u);
  return (ushort)(r >> 16);
}
__device__ __forceinline__ float bf16_tof(ushort h) {
  union { unsigned u; float f; } v; v.u = ((unsigned)h) << 16;
  return v.f;
}
__device__ __forceinline__ void split_store4(
    ushort* __restrict__ ph, ushort* __restrict__ pl,
    float v0, float v1, float v2, float v3) {
  ushort h0 = bf16_rne(v0), h1 = bf16_rne(v1), h2 = bf16_rne(v2), h3 = bf16_rne(v3);
  *(ushort4*)ph = make_ushort4(h0, h1, h2, h3);
  *(ushort4*)pl = make_ushort4(bf16_rne(v0 - bf16_tof(h0)), bf16_rne(v1 - bf16_tof(h1)),
                               bf16_rne(v2 - bf16_tof(h2)), bf16_rne(v3 - bf16_tof(h3)));
}

// wht fragment-order offset: batch*65536 + (col/16)*8192 + (j/32)*512
//   + (col%16)*8 + ((j>>3)&3)*128 + (j&7)   [j = node index = GEMM k]
__device__ __forceinline__ long wht_off(long batch, int c, int j) {
  return batch * 65536 + (long)(c >> 4) * 8192 + (j >> 5) * 512 +
         ((c & 15) << 3) + (((j >> 3) & 3) << 7) + (j & 7);
}

#define WHT_SLOT 8388608L   // ushorts per layer slot (whtH 4M + whtL 4M)

// ---- standalone wt_prep: W[K,N] fp32 -> TH/TL[N][K] bf16 hi/lo ----
__global__ __launch_bounds__(256) void wt_prep(
    const float* __restrict__ W, ushort* __restrict__ TH, ushort* __restrict__ TL,
    const int Kd, const int Nd)
{
  const int idx = blockIdx.x * 256 + threadIdx.x;
  if (idx >= Kd * Nd) return;
  const int k = idx / Nd, n = idx % Nd;
  const float v = W[idx];
  const ushort h = bf16_rne(v);
  TH[(long)n * Kd + k] = h;
  TL[(long)n * Kd + k] = bf16_rne(v - bf16_tof(h));
}

// ---- K0 (front union): wh_small x3 | maskprep | wt_prep(W_out)
// branch on blockIdx.x. Overlaps the 134MB adj read with the wh compute. ----
__global__ __launch_bounds__(256) void front_union(
    const float* __restrict__ A, const float* __restrict__ Wst,
    const float* __restrict__ ast,
    ushort* __restrict__ whtBase, float* __restrict__ srcB, float* __restrict__ dstB,
    const int* __restrict__ adj, unsigned* __restrict__ mask,
    const float* __restrict__ W_out, ushort* __restrict__ WoT_H, ushort* __restrict__ WoT_L)
{
  __shared__ float AsT[34][36];
  __shared__ float Ws[34][128];
  const int bid = blockIdx.x;
  const int t = threadIdx.x;

  if (bid >= 3072) {
    if (bid < 5120) {
      // ---- maskprep: pack adj>0 into bitmask [32768][16] uint ----
      const int gid = (bid - 3072) * 256 + t;
      const int4* __restrict__ p = (const int4*)(adj + (long)gid * 32);
      unsigned m = 0;
#pragma unroll
      for (int k = 0; k < 8; k++) {
        const int4 v = p[k];
        m |= (v.x > 0 ? 1u : 0u) << (4 * k);
        m |= (v.y > 0 ? 1u : 0u) << (4 * k + 1);
        m |= (v.z > 0 ? 1u : 0u) << (4 * k + 2);
        m |= (v.w > 0 ? 1u : 0u) << (4 * k + 3);
      }
      mask[gid] = m;
    } else {
      // ---- wt_prep(W_out): [384,128] fp32 -> WoT[128][384] bf16 hi/lo ----
      const int idx = (bid - 5120) * 256 + t;   // 192 blocks = 49152 exact
      const int k = idx / 128, n = idx % 128;
      const float v = W_out[idx];
      const ushort h = bf16_rne(v);
      WoT_H[(long)n * 384 + k] = h;
      WoT_L[(long)n * 384 + k] = bf16_rne(v - bf16_tof(h));
    }
    return;
  }

  // ---- wh_small: Wh_l = compound @ W_l -> whT_l (fragment order) + src/dst
  const int l = bid >> 10;
  const float* __restrict__ W = Wst + (long)l * 34 * 128;
  const float* __restrict__ avec = ast + (long)l * 256;
  ushort* __restrict__ whtH = whtBase + (long)l * WHT_SLOT;
  ushort* __restrict__ whtL = whtH + 4194304;
  float* __restrict__ src = srcB + (long)l * 32768;
  float* __restrict__ dst = dstB + (long)l * 32768;
  const long row0 = (long)(bid & 1023) * 32;
  const int cg = t & 31, rg = t >> 5;
  {
    const int r = t >> 3, l8 = t & 7;
#pragma unroll
    for (int q = 0; q < 5; q++) {
      int k = l8 + q * 8;
      if (k < 34) AsT[k][r] = A[(row0 + r) * 34 + k];
    }
  }
  {
    int idx = t;
#pragma unroll
    for (int i = 0; i < 17; i++, idx += 256)
      Ws[idx >> 7][idx & 127] = W[idx];
  }
  __syncthreads();

  float acc[4][4];
#pragma unroll
  for (int r = 0; r < 4; r++)
#pragma unroll
    for (int c = 0; c < 4; c++) acc[r][c] = 0.f;
#pragma unroll 2
  for (int k = 0; k < 34; k++) {
    const float4 wv = *(const float4*)&Ws[k][cg * 4];
    const float4 av = *(const float4*)&AsT[k][rg * 4];
#define GFMA(r, a) \
    acc[r][0] += (a) * wv.x; acc[r][1] += (a) * wv.y; \
    acc[r][2] += (a) * wv.z; acc[r][3] += (a) * wv.w;
    GFMA(0, av.x) GFMA(1, av.y) GFMA(2, av.z) GFMA(3, av.w)
#undef GFMA
  }

  {
    const long batch = row0 >> 9;
    const int j = (int)(row0 & 511) + rg * 4;       // j%4 == 0 -> contiguous 4
#pragma unroll
    for (int cc = 0; cc < 4; cc++) {
      const long o = wht_off(batch, cg * 4 + cc, j);
      split_store4(&whtH[o], &whtL[o], acc[0][cc], acc[1][cc], acc[2][cc], acc[3][cc]);
    }
  }

  const float4 a1 = *(const float4*)&avec[cg * 4];
  const float4 a2 = *(const float4*)&avec[128 + cg * 4];
#pragma unroll
  for (int r = 0; r < 4; r++) {
    float s = acc[r][0]*a1.x + acc[r][1]*a1.y + acc[r][2]*a1.z + acc[r][3]*a1.w;
    float d = acc[r][0]*a2.x + acc[r][1]*a2.y + acc[r][2]*a2.z + acc[r][3]*a2.w;
#pragma unroll
    for (int w = 1; w < 32; w <<= 1) {
      s += __shfl_xor(s, w, 64);
      d += __shfl_xor(d, w, 64);
    }
    if (cg == 0) {
      src[row0 + rg * 4 + r] = s * LOG2E;   // log2-domain at producer
      dst[row0 + rg * 4 + r] = d * LOG2E;
    }
  }
}

// ---- K2 (fused, multi-layer): single-pass masked softmax -> LDS As
// (unnormalized bf16 p), then out = elu((P @ WhT^T) * 1/rowsum).
// blockIdx.z = layer. B tiles prefetched in NAMED registers, depth-2
// ping-pong; first two k-blocks issued at entry (hide under softmax). ----
__global__ __launch_bounds__(256, 4) void fused_attn(
    const unsigned* __restrict__ mask,
    const float* __restrict__ srcB, const float* __restrict__ dstB,
    const ushort* __restrict__ whtBase,
    float* __restrict__ out, const int ostride)
{
  __shared__ ushort As[32][520];
  __shared__ float dstS[512];
  __shared__ float invS[32];
  __shared__ float wredM[4];
  const int t = threadIdx.x;
  const int l = blockIdx.z;
  const float* __restrict__ src = srcB + (long)l * 32768;
  const float* __restrict__ dstv = dstB + (long)l * 32768;
  const ushort* __restrict__ whtH = whtBase + (long)l * WHT_SLOT;
  const ushort* __restrict__ whtL = whtH + 4194304;
  const int ocoff = l * 128;
  // XCD swizzle: per layer 1024 blocks = 8 XCDs x 128; each XCD gets 8 whole
  // batches so a batch's 512KB wht slice is HBM-fetched once, reused via L2.
  const int flat = blockIdx.y * 16 + blockIdx.x;
  const int swz = (flat & 7) * 128 + (flat >> 3);
  const long base = (long)(swz >> 4) * 512;   // batch * 512
  const int i0 = (swz & 15) * 32;             // row tile within batch

  // MFMA geometry + entry prefetch of k-blocks 0 and 1 (independent of
  // softmax; L2 latency hides under the VALU phase). Named registers only.
  const int wv = t >> 6, lane = t & 63;
  const int m16 = lane & 15, q = lane >> 4;
  const int n0 = wv * 32;
  const ushort* __restrict__ bH = whtH + base * 128 + wv * 16384 + lane * 8;
  const ushort* __restrict__ bL = whtL + base * 128 + wv * 16384 + lane * 8;
  s16x8 pa0H = *(const s16x8*)&bH[0];
  s16x8 pa0L = *(const s16x8*)&bL[0];
  s16x8 pa1H = *(const s16x8*)&bH[8192];
  s16x8 pa1L = *(const s16x8*)&bL[8192];
  s16x8 pb0H = *(const s16x8*)&bH[512];
  s16x8 pb0L = *(const s16x8*)&bL[512];
  s16x8 pb1H = *(const s16x8*)&bH[8192 + 512];
  s16x8 pb1L = *(const s16x8*)&bL[8192 + 512];

  // stage dstS (already log2 domain) + block-wide max md
  {
    const float d0 = dstv[base + t];
    const float d1 = dstv[base + t + 256];
    dstS[t] = d0;
    dstS[t + 256] = d1;
    float mx = fmaxf(d0, d1);
#pragma unroll
    for (int w = 1; w < 64; w <<= 1) mx = fmaxf(mx, __shfl_xor(mx, w, 64));
    if ((t & 63) == 0) wredM[t >> 6] = mx;
  }
  __syncthreads();
  const float md = fmaxf(fmaxf(wredM[0], wredM[1]), fmaxf(wredM[2], wredM[3]));

  // ---- phase 1: single-pass masked softmax -> As bf16, invS = 1/rowsum.
  // 8 threads per row, 64 j each.
  {
    const int r = t >> 3, l8 = t & 7;
    const long i = base + i0 + r;
    const float si = src[i];
    const unsigned* __restrict__ mrow = mask + i * 16;
    unsigned mw[16];
#pragma unroll
    for (int jj = 0; jj < 16; jj++) mw[jj] = mrow[jj];
    const int sh = l8 * 4;
    const float em = si + md;
    const float m = fmaxf(em, ALPHA * em);   // >= masked max of leaky(si+dv)
    float sum = 0.f;
#pragma unroll
    for (int jj = 0; jj < 16; jj++) {
      const float4 dv = *(const float4*)&dstS[l8 * 4 + jj * 32];
      const unsigned w = mw[jj] >> sh;
      float e0 = si + dv.x, e1 = si + dv.y, e2 = si + dv.z, e3 = si + dv.w;
      e0 = fmaxf(e0, ALPHA * e0) - m; e1 = fmaxf(e1, ALPHA * e1) - m;
      e2 = fmaxf(e2, ALPHA * e2) - m; e3 = fmaxf(e3, ALPHA * e3) - m;
      float p0 = EXP2F(e0), p1 = EXP2F(e1), p2 = EXP2F(e2), p3 = EXP2F(e3);
      p0 = (w & 1u) ? p0 : 0.f;
      p1 = (w & 2u) ? p1 : 0.f;
      p2 = (w & 4u) ? p2 : 0.f;
      p3 = (w & 8u) ? p3 : 0.f;
      sum += (p0 + p1) + (p2 + p3);
      union { __hip_bfloat162 b; unsigned u; } u01, u23;
      u01.b = __float22bfloat162_rn(make_float2(p0, p1));
      u23.b = __float22bfloat162_rn(make_float2(p2, p3));
      *(uint2*)&As[r][l8 * 4 + jj * 32] = make_uint2(u01.u, u23.u);
    }
#pragma unroll
    for (int w = 1; w < 8; w <<= 1) sum += __shfl_xor(sum, w, 64);
    if (l8 == 0) invS[r] = 1.f / sum;
  }
  __syncthreads();

  // ---- phase 2: MFMA aggregation, explicit even/odd depth-2 ping-pong. ----
  f32x4 acc00 = {0.f,0.f,0.f,0.f}, acc01 = {0.f,0.f,0.f,0.f};
  f32x4 acc10 = {0.f,0.f,0.f,0.f}, acc11 = {0.f,0.f,0.f,0.f};
#pragma unroll
  for (int kp = 0; kp < 8; kp++) {
    {   // even kb = 2*kp  (set A)
      const int k0 = (2 * kp) * 32 + q * 8;
      const s16x8 a0 = *(const s16x8*)&As[m16][k0];
      const s16x8 a1 = *(const s16x8*)&As[16 + m16][k0];
      acc00 = __builtin_amdgcn_mfma_f32_16x16x32_bf16(a0, pa0H, acc00, 0, 0, 0);
      acc01 = __builtin_amdgcn_mfma_f32_16x16x32_bf16(a0, pa1H, acc01, 0, 0, 0);
      acc10 = __builtin_amdgcn_mfma_f32_16x16x32_bf16(a1, pa0H, acc10, 0, 0, 0);
      acc11 = __builtin_amdgcn_mfma_f32_16x16x32_bf16(a1, pa1H, acc11, 0, 0, 0);
      acc00 = __builtin_amdgcn_mfma_f32_16x16x32_bf16(a0, pa0L, acc00, 0, 0, 0);
      acc01 = __builtin_amdgcn_mfma_f32_16x16x32_bf16(a0, pa1L, acc01, 0, 0, 0);
      acc10 = __builtin_amdgcn_mfma_f32_16x16x32_bf16(a1, pa0L, acc10, 0, 0, 0);
      acc11 = __builtin_amdgcn_mfma_f32_16x16x32_bf16(a1, pa1L, acc11, 0, 0, 0);
      if (kp < 7) {
        const int bo = (2 * kp + 2) * 512;
        pa0H = *(const s16x8*)&bH[bo];
        pa0L = *(const s16x8*)&bL[bo];
        pa1H = *(const s16x8*)&bH[8192 + bo];
        pa1L = *(const s16x8*)&bL[8192 + bo];
      }
    }
    {   // odd kb = 2*kp+1  (set B)
      const int k0 = (2 * kp + 1) * 32 + q * 8;
      const s16x8 a0 = *(const s16x8*)&As[m16][k0];
      const s16x8 a1 = *(const s16x8*)&As[16 + m16][k0];
      acc00 = __builtin_amdgcn_mfma_f32_16x16x32_bf16(a0, pb0H, acc00, 0, 0, 0);
      acc01 = __builtin_amdgcn_mfma_f32_16x16x32_bf16(a0, pb1H, acc01, 0, 0, 0);
      acc10 = __builtin_amdgcn_mfma_f32_16x16x32_bf16(a1, pb0H, acc10, 0, 0, 0);
      acc11 = __builtin_amdgcn_mfma_f32_16x16x32_bf16(a1, pb1H, acc11, 0, 0, 0);
      acc00 = __builtin_amdgcn_mfma_f32_16x16x32_bf16(a0, pb0L, acc00, 0, 0, 0);
      acc01 = __builtin_amdgcn_mfma_f32_16x16x32_bf16(a0, pb1L, acc01, 0, 0, 0);
      acc10 = __builtin_amdgcn_mfma_f32_16x16x32_bf16(a1, pb0L, acc10, 0, 0, 0);
      acc11 = __builtin_amdgcn_mfma_f32_16x16x32_bf16(a1, pb1L, acc11, 0, 0, 0);
      if (kp < 7) {
        const int bo = (2 * kp + 3) * 512;
        pb0H = *(const s16x8*)&bH[bo];
        pb0L = *(const s16x8*)&bL[bo];
        pb1H = *(const s16x8*)&bH[8192 + bo];
        pb1L = *(const s16x8*)&bL[8192 + bo];
      }
    }
  }
#pragma unroll
  for (int reg = 0; reg < 4; reg++) {
    const int row = q * 4 + reg;
    const float li0 = invS[row], li1 = invS[16 + row];
    float v00 = acc00[reg] * li0, v01 = acc01[reg] * li0;
    float v10 = acc10[reg] * li1, v11 = acc11[reg] * li1;
    v00 = v00 > 0.f ? v00 : __expf(v00) - 1.f;
    v01 = v01 > 0.f ? v01 : __expf(v01) - 1.f;
    v10 = v10 > 0.f ? v10 : __expf(v10) - 1.f;
    v11 = v11 > 0.f ? v11 : __expf(v11) - 1.f;
    float* o0 = out + (base + i0 + row) * (long)ostride + ocoff + n0 + m16;
    float* o1 = out + (base + i0 + 16 + row) * (long)ostride + ocoff + n0 + m16;
    o0[0] = v00; o0[16] = v01;
    o1[0] = v10; o1[16] = v11;
  }
}

// ---- K3/K4: MFMA GEMM, C = A[32768,K] @ BT^T, 32 rows x 128 cols/block.
// A fp32 -> bf16 hi/lo during LDS staging; B pre-split via wt_prep.
// MODE 0: emit whT hi/lo (fragment order) + src/dst (log2-scaled).
// MODE 1: +bias +leaky fp32 store. ----
template<int K, int KC, int MODE>
__global__ __launch_bounds__(256) void mfma_gemm(
    const float* __restrict__ A,
    const ushort* __restrict__ BTH, const ushort* __restrict__ BTL,
    const float* __restrict__ bias, float* __restrict__ outF,
    ushort* __restrict__ whtH, ushort* __restrict__ whtL,
    const float* __restrict__ avec, float* __restrict__ src, float* __restrict__ dst,
    const int ostride)
{
  constexpr int KP = KC + 8;
  __shared__ ushort AsH[32][KP];
  __shared__ ushort AsL[32][KP];
  __shared__ float sredS[4][32], sredD[4][32];
  const int t = threadIdx.x;
  const long row0 = (long)blockIdx.x * 32;
  const int ncoff = (MODE == 1) ? blockIdx.y * 128 : 0;

  const int wv = t >> 6, lane = t & 63;
  const int m16 = lane & 15, q = lane >> 4;
  const int n0 = wv * 32;
  const ushort* __restrict__ bh0 = BTH + (long)(ncoff + n0 + m16) * K;
  const ushort* __restrict__ bl0 = BTL + (long)(ncoff + n0 + m16) * K;

  f32x4 acc[2][2];
#pragma unroll
  for (int m = 0; m < 2; m++)
#pragma unroll
    for (int n = 0; n < 2; n++) acc[m][n] = (f32x4){0.f, 0.f, 0.f, 0.f};

  for (int kc = 0; kc < K; kc += KC) {
    constexpr int NIT = (32 * KC / 4) / 256;
#pragma unroll
    for (int it = 0; it < NIT; it++) {
      const int idx = t + it * 256;
      const int r = idx / (KC / 4), k4 = idx % (KC / 4);
      const float4 v = *(const float4*)&A[(row0 + r) * (long)K + kc + k4 * 4];
      split_store4(&AsH[r][k4 * 4], &AsL[r][k4 * 4], v.x, v.y, v.z, v.w);
    }
    __syncthreads();
#pragma unroll
    for (int ks = 0; ks < KC / 32; ks++) {
      const int k0 = ks * 32 + q * 8;
      const s16x8 a0H = *(const s16x8*)&AsH[m16][k0];
      const s16x8 a0L = *(const s16x8*)&AsL[m16][k0];
      const s16x8 a1H = *(const s16x8*)&AsH[16 + m16][k0];
      const s16x8 a1L = *(const s16x8*)&AsL[16 + m16][k0];
      const int kg = kc + k0;
      const s16x8 b0H = *(const s16x8*)&bh0[kg];
      const s16x8 b0L = *(const s16x8*)&bl0[kg];
      const s16x8 b1H = *(const s16x8*)&bh0[16 * K + kg];
      const s16x8 b1L = *(const s16x8*)&bl0[16 * K + kg];
      acc[0][0] = __builtin_amdgcn_mfma_f32_16x16x32_bf16(a0H, b0H, acc[0][0], 0, 0, 0);
      acc[0][1] = __builtin_amdgcn_mfma_f32_16x16x32_bf16(a0H, b1H, acc[0][1], 0, 0, 0);
      acc[1][0] = __builtin_amdgcn_mfma_f32_16x16x32_bf16(a1H, b0H, acc[1][0], 0, 0, 0);
      acc[1][1] = __builtin_amdgcn_mfma_f32_16x16x32_bf16(a1H, b1H, acc[1][1], 0, 0, 0);
      acc[0][0] = __builtin_amdgcn_mfma_f32_16x16x32_bf16(a0L, b0H, acc[0][0], 0, 0, 0);
      acc[0][1] = __builtin_amdgcn_mfma_f32_16x16x32_bf16(a0L, b1H, acc[0][1], 0, 0, 0);
      acc[1][0] = __builtin_amdgcn_mfma_f32_16x16x32_bf16(a1L, b0H, acc[1][0], 0, 0, 0);
      acc[1][1] = __builtin_amdgcn_mfma_f32_16x16x32_bf16(a1L, b1H, acc[1][1], 0, 0, 0);
      acc[0][0] = __builtin_amdgcn_mfma_f32_16x16x32_bf16(a0H, b0L, acc[0][0], 0, 0, 0);
      acc[0][1] = __builtin_amdgcn_mfma_f32_16x16x32_bf16(a0H, b1L, acc[0][1], 0, 0, 0);
      acc[1][0] = __builtin_amdgcn_mfma_f32_16x16x32_bf16(a1H, b0L, acc[1][0], 0, 0, 0);
      acc[1][1] = __builtin_amdgcn_mfma_f32_16x16x32_bf16(a1H, b1L, acc[1][1], 0, 0, 0);
    }
    __syncthreads();
  }

  if (MODE == 0) {
    // whT hi/lo store in fragment order
    const long batch = row0 >> 9;
    const int iloc = (int)(row0 & 511);
#pragma unroll
    for (int m = 0; m < 2; m++)
#pragma unroll
      for (int n = 0; n < 2; n++) {
        const int c = n0 + n * 16 + m16;
        const int j = iloc + m * 16 + q * 4;        // j%4 == 0 -> contiguous 4
        const long o = wht_off(batch, c, j);
        const f32x4 v = acc[m][n];
        split_store4(&whtH[o], &whtL[o], v[0], v[1], v[2], v[3]);
      }
    // fused src/dst: reduce over cols (16 lanes x 2 n-tiles per wave, 4 waves)
    const float a10 = avec[n0 + m16], a11 = avec[n0 + 16 + m16];
    const float a20 = avec[128 + n0 + m16], a21 = avec[128 + n0 + 16 + m16];
#pragma unroll
    for (int m = 0; m < 2; m++) {
#pragma unroll
      for (int reg = 0; reg < 4; reg++) {
        float s = acc[m][0][reg] * a10 + acc[m][1][reg] * a11;
        float d = acc[m][0][reg] * a20 + acc[m][1][reg] * a21;
#pragma unroll
        for (int w = 1; w < 16; w <<= 1) {
          s += __shfl_xor(s, w, 64);
          d += __shfl_xor(d, w, 64);
        }
        if (m16 == 0) {
          const int row = m * 16 + q * 4 + reg;
          sredS[wv][row] = s;
          sredD[wv][row] = d;
        }
      }
    }
    __syncthreads();
    if (t < 32) {
      const float s = sredS[0][t] + sredS[1][t] + sredS[2][t] + sredS[3][t];
      const float d = sredD[0][t] + sredD[1][t] + sredD[2][t] + sredD[3][t];
      src[row0 + t] = s * LOG2E;   // log2-domain at producer
      dst[row0 + t] = d * LOG2E;
    }
  } else {
#pragma unroll
    for (int m = 0; m < 2; m++)
#pragma unroll
      for (int n = 0; n < 2; n++) {
        const int c = ncoff + n0 + n * 16 + m16;
        const float bv = bias[c];
#pragma unroll
        for (int reg = 0; reg < 4; reg++) {
          float v = acc[m][n][reg] + bv;
          v = fmaxf(v, ALPHA * v);
          outF[(row0 + m * 16 + q * 4 + reg) * (long)ostride + c] = v;
        }
      }
  }
}

extern "C" void kernel_launch(void* const* d_in, const int* in_sizes, int n_in,
                              void* d_out, int out_size, void* d_ws, size_t ws_size,
                              hipStream_t stream) {
  const float* compound = (const float*)d_in[0];
  const int*   adj      = (const int*)d_in[1];
  const float* W_stack  = (const float*)d_in[2];
  const float* a_stack  = (const float*)d_in[3];
  const float* W_out    = (const float*)d_in[4];
  const float* a_out    = (const float*)d_in[5];
  const float* Wc       = (const float*)d_in[6];
  const float* bc       = (const float*)d_in[7];
  float* out = (float*)d_out;

  // workspace: wht slots for 3 layers (48MB), then multi (50MB).
  // x aliases multi head; WcT parked in dead multi tail (written only after
  // multi's last reader, gemm384, has run).
  ushort* wht_all = (ushort*)d_ws;                    // 3 x 16MB slots
  float* f     = (float*)d_ws;
  float* multi = f + 12582912;                        // 12,582,912 floats
  float* x     = multi;                               // aliases multi head
  ushort* WcT_H = (ushort*)(multi + 5000000);         // beyond x's 4.19M floats
  ushort* WcT_L = WcT_H + 32768;

  // d_out parking (dead until final GEMM overwrites):
  // mask 524288 uints | src[4] | dst[4] | WoT_H/L
  unsigned* mask = (unsigned*)d_out;
  float* doutF = (float*)d_out;
  float* srcB = doutF + 524288;                       // 4 x 32768
  float* dstB = srcB + 4 * 32768;                     // 4 x 32768
  ushort* WoT_H = (ushort*)(dstB + 4 * 32768);        // 98304 ushorts
  ushort* WoT_L = WoT_H + 98304;
  float* src3 = srcB + 3 * 32768;
  float* dst3 = dstB + 3 * 32768;

  // front: wh_small x3 + maskprep + wt_prep(W_out) in ONE dispatch
  front_union<<<5312, 256, 0, stream>>>(
      compound, W_stack, a_stack, wht_all, srcB, dstB,
      adj, mask, W_out, WoT_H, WoT_L);
  // 3 GAT heads
  fused_attn<<<dim3(16, 64, 3), 256, 0, stream>>>(
      mask, srcB, dstB, wht_all, multi, 384);
  // layer 4: Wh = multi @ W_out  (MFMA, emits whT slot-0 + src/dst slot-3)
  mfma_gemm<384, 192, 0><<<1024, 256, 0, stream>>>(
      multi, WoT_H, WoT_L, nullptr, nullptr, wht_all, wht_all + 4194304,
      a_out, src3, dst3, 0);
  fused_attn<<<dim3(16, 64, 1), 256, 0, stream>>>(
      mask, src3, dst3, wht_all, x, 128);
  // Wc prep AFTER multi is dead (only x's 4.19M floats live) — round-13 slot
  wt_prep<<<128, 256, 0, stream>>>(Wc, WcT_H, WcT_L, 128, 256);
  // final: out = leaky(x @ Wc + bc)  (MFMA)
  mfma_gemm<128, 128, 1><<<dim3(1024, 2), 256, 0, stream>>>(
      x, WcT_H, WcT_L, bc, out, nullptr, nullptr, nullptr, nullptr, nullptr, 256);
}

// Round 11
// 241.510 us; speedup vs baseline: 1.6665x; 1.0660x over previous
//
#include <hip/hip_runtime.h>
#include <hip/hip_bf16.h>
#include <math.h>

// GAT predictor: B=64, N=512, ATOM=34, GAT=128, HID=256, 3 layers + out.
// Round-18: (a) fused_attn mask over-read fixed — each softmax thread now
// owns a CONTIGUOUS 64-j window so it loads 2 mask words (uint2) instead of
// 16 (8x redundancy gone: 16MB->2MB per merged dispatch). dstS padded +4/64
// (stride-256B float4 reads would be 8-way conflicted) and As columns
// XOR-swizzled by (j>>6)<<3 (8-ushort granularity keeps s16x8 reads
// contiguous; phase-2 applies the same compile-time XOR ((kb>>1)&7)<<3).
// (b) WoT/WcT emitted in wht-style fragment order; mfma_gemm B loads become
// single 1KB coalesced transactions (was 16B/lane @ stride 2K B = 16 cache
// lines/load, the round-10 pathology). Bit-exact layout moves (sum order
// changes <=1ulp). Everything else identical to round-17.
// ws: wht[3] 48MB | multi 50MB (x aliases head; WcT parked at +5M floats,
//     written only after multi is dead)
// d_out: mask 2.1MB | src[4]/dst[4] 1MB | WoT 0.4MB  (until final GEMM)

#define ALPHA 0.2f
#define LOG2E 1.44269504088896f

#if __has_builtin(__builtin_amdgcn_exp2f)
#define EXP2F(x) __builtin_amdgcn_exp2f(x)
#else
extern "C" __device__ float __ocml_exp2_f32(float);
#define EXP2F(x) __ocml_exp2_f32(x)
#endif

typedef __attribute__((ext_vector_type(8))) short s16x8;   // 8 bf16 (4 VGPRs)
typedef __attribute__((ext_vector_type(4))) float f32x4;

__device__ __forceinline__ ushort bf16_rne(float f) {
  union { float f; unsigned u; } v; v.f = f;
  unsigned r = v.u + 0x7FFFu + ((v.u >> 16) & 1u);
  return (ushort)(r >> 16);
}
__device__ __forceinline__ float bf16_tof(ushort h) {
  union { unsigned u; float f; } v; v.u = ((unsigned)h) << 16;
  return v.f;
}
__device__ __forceinline__ void split_store4(
    ushort* __restrict__ ph, ushort* __restrict__ pl,
    float v0, float v1, float v2, float v3) {
  ushort h0 = bf16_rne(v0), h1 = bf16_rne(v1), h2 = bf16_rne(v2), h3 = bf16_rne(v3);
  *(ushort4*)ph = make_ushort4(h0, h1, h2, h3);
  *(ushort4*)pl = make_ushort4(bf16_rne(v0 - bf16_tof(h0)), bf16_rne(v1 - bf16_tof(h1)),
                               bf16_rne(v2 - bf16_tof(h2)), bf16_rne(v3 - bf16_tof(h3)));
}

// wht fragment-order offset (K=512): batch*65536 + (col/16)*8192 + (j/32)*512
//   + (col%16)*8 + ((j>>3)&3)*128 + (j&7)   [j = node index = GEMM k]
__device__ __forceinline__ long wht_off(long batch, int c, int j) {
  return batch * 65536 + (long)(c >> 4) * 8192 + (j >> 5) * 512 +
         ((c & 15) << 3) + (((j >> 3) & 3) << 7) + (j & 7);
}

// generic fragment-order offset for a [Kd x Nd] weight (col c, k-index j)
__device__ __forceinline__ long w_frag_off(int c, int j, int Kd) {
  return (long)(c >> 4) * (Kd * 16) + (j >> 5) * 512 +
         ((c & 15) << 3) + (((j >> 3) & 3) << 7) + (j & 7);
}

#define WHT_SLOT 8388608L   // ushorts per layer slot (whtH 4M + whtL 4M)

// ---- standalone wt_prep: W[K,N] fp32 -> fragment-order TH/TL ----
__global__ __launch_bounds__(256) void wt_prep(
    const float* __restrict__ W, ushort* __restrict__ TH, ushort* __restrict__ TL,
    const int Kd, const int Nd)
{
  const int idx = blockIdx.x * 256 + threadIdx.x;
  if (idx >= Kd * Nd) return;
  const int k = idx / Nd, n = idx % Nd;
  const float v = W[idx];
  const ushort h = bf16_rne(v);
  const long o = w_frag_off(n, k, Kd);
  TH[o] = h;
  TL[o] = bf16_rne(v - bf16_tof(h));
}

// ---- K0 (front union): wh_small x3 | maskprep | wt_prep(W_out)
// branch on blockIdx.x. Overlaps the 67MB adj read with the wh compute. ----
__global__ __launch_bounds__(256) void front_union(
    const float* __restrict__ A, const float* __restrict__ Wst,
    const float* __restrict__ ast,
    ushort* __restrict__ whtBase, float* __restrict__ srcB, float* __restrict__ dstB,
    const int* __restrict__ adj, unsigned* __restrict__ mask,
    const float* __restrict__ W_out, ushort* __restrict__ WoT_H, ushort* __restrict__ WoT_L)
{
  __shared__ float AsT[34][36];
  __shared__ float Ws[34][128];
  const int bid = blockIdx.x;
  const int t = threadIdx.x;

  if (bid >= 3072) {
    if (bid < 5120) {
      // ---- maskprep: pack adj>0 into bitmask [32768][16] uint ----
      const int gid = (bid - 3072) * 256 + t;
      const int4* __restrict__ p = (const int4*)(adj + (long)gid * 32);
      unsigned m = 0;
#pragma unroll
      for (int k = 0; k < 8; k++) {
        const int4 v = p[k];
        m |= (v.x > 0 ? 1u : 0u) << (4 * k);
        m |= (v.y > 0 ? 1u : 0u) << (4 * k + 1);
        m |= (v.z > 0 ? 1u : 0u) << (4 * k + 2);
        m |= (v.w > 0 ? 1u : 0u) << (4 * k + 3);
      }
      mask[gid] = m;
    } else {
      // ---- wt_prep(W_out): [384,128] fp32 -> fragment-order WoT ----
      const int idx = (bid - 5120) * 256 + t;   // 192 blocks = 49152 exact
      const int k = idx / 128, n = idx % 128;
      const float v = W_out[idx];
      const ushort h = bf16_rne(v);
      const long o = w_frag_off(n, k, 384);
      WoT_H[o] = h;
      WoT_L[o] = bf16_rne(v - bf16_tof(h));
    }
    return;
  }

  // ---- wh_small: Wh_l = compound @ W_l -> whT_l (fragment order) + src/dst
  const int l = bid >> 10;
  const float* __restrict__ W = Wst + (long)l * 34 * 128;
  const float* __restrict__ avec = ast + (long)l * 256;
  ushort* __restrict__ whtH = whtBase + (long)l * WHT_SLOT;
  ushort* __restrict__ whtL = whtH + 4194304;
  float* __restrict__ src = srcB + (long)l * 32768;
  float* __restrict__ dst = dstB + (long)l * 32768;
  const long row0 = (long)(bid & 1023) * 32;
  const int cg = t & 31, rg = t >> 5;
  {
    const int r = t >> 3, l8 = t & 7;
#pragma unroll
    for (int q = 0; q < 5; q++) {
      int k = l8 + q * 8;
      if (k < 34) AsT[k][r] = A[(row0 + r) * 34 + k];
    }
  }
  {
    int idx = t;
#pragma unroll
    for (int i = 0; i < 17; i++, idx += 256)
      Ws[idx >> 7][idx & 127] = W[idx];
  }
  __syncthreads();

  float acc[4][4];
#pragma unroll
  for (int r = 0; r < 4; r++)
#pragma unroll
    for (int c = 0; c < 4; c++) acc[r][c] = 0.f;
#pragma unroll 2
  for (int k = 0; k < 34; k++) {
    const float4 wv = *(const float4*)&Ws[k][cg * 4];
    const float4 av = *(const float4*)&AsT[k][rg * 4];
#define GFMA(r, a) \
    acc[r][0] += (a) * wv.x; acc[r][1] += (a) * wv.y; \
    acc[r][2] += (a) * wv.z; acc[r][3] += (a) * wv.w;
    GFMA(0, av.x) GFMA(1, av.y) GFMA(2, av.z) GFMA(3, av.w)
#undef GFMA
  }

  {
    const long batch = row0 >> 9;
    const int j = (int)(row0 & 511) + rg * 4;       // j%4 == 0 -> contiguous 4
#pragma unroll
    for (int cc = 0; cc < 4; cc++) {
      const long o = wht_off(batch, cg * 4 + cc, j);
      split_store4(&whtH[o], &whtL[o], acc[0][cc], acc[1][cc], acc[2][cc], acc[3][cc]);
    }
  }

  const float4 a1 = *(const float4*)&avec[cg * 4];
  const float4 a2 = *(const float4*)&avec[128 + cg * 4];
#pragma unroll
  for (int r = 0; r < 4; r++) {
    float s = acc[r][0]*a1.x + acc[r][1]*a1.y + acc[r][2]*a1.z + acc[r][3]*a1.w;
    float d = acc[r][0]*a2.x + acc[r][1]*a2.y + acc[r][2]*a2.z + acc[r][3]*a2.w;
#pragma unroll
    for (int w = 1; w < 32; w <<= 1) {
      s += __shfl_xor(s, w, 64);
      d += __shfl_xor(d, w, 64);
    }
    if (cg == 0) {
      src[row0 + rg * 4 + r] = s * LOG2E;   // log2-domain at producer
      dst[row0 + rg * 4 + r] = d * LOG2E;
    }
  }
}

// ---- K2 (fused, multi-layer): single-pass masked softmax -> LDS As
// (unnormalized bf16 p), then out = elu((P @ WhT^T) * 1/rowsum).
// blockIdx.z = layer. Softmax threads own contiguous 64-j windows (2 mask
// words each); dstS padded +4/64; As cols XOR-swizzled by (j>>6)<<3. ----
__global__ __launch_bounds__(256, 4) void fused_attn(
    const unsigned* __restrict__ mask,
    const float* __restrict__ srcB, const float* __restrict__ dstB,
    const ushort* __restrict__ whtBase,
    float* __restrict__ out, const int ostride)
{
  __shared__ ushort As[32][520];
  __shared__ float dstS[544];          // phys = j + (j>>6)*4
  __shared__ float invS[32];
  __shared__ float wredM[4];
  const int t = threadIdx.x;
  const int l = blockIdx.z;
  const float* __restrict__ src = srcB + (long)l * 32768;
  const float* __restrict__ dstv = dstB + (long)l * 32768;
  const ushort* __restrict__ whtH = whtBase + (long)l * WHT_SLOT;
  const ushort* __restrict__ whtL = whtH + 4194304;
  const int ocoff = l * 128;
  // XCD swizzle: per layer 1024 blocks = 8 XCDs x 128; each XCD gets 8 whole
  // batches so a batch's 512KB wht slice is HBM-fetched once, reused via L2.
  const int flat = blockIdx.y * 16 + blockIdx.x;
  const int swz = (flat & 7) * 128 + (flat >> 3);
  const long base = (long)(swz >> 4) * 512;   // batch * 512
  const int i0 = (swz & 15) * 32;             // row tile within batch

  // MFMA geometry + entry prefetch of k-blocks 0 and 1 (independent of
  // softmax; L2 latency hides under the VALU phase). Named registers only.
  const int wv = t >> 6, lane = t & 63;
  const int m16 = lane & 15, q = lane >> 4;
  const int n0 = wv * 32;
  const ushort* __restrict__ bH = whtH + base * 128 + wv * 16384 + lane * 8;
  const ushort* __restrict__ bL = whtL + base * 128 + wv * 16384 + lane * 8;
  s16x8 pa0H = *(const s16x8*)&bH[0];
  s16x8 pa0L = *(const s16x8*)&bL[0];
  s16x8 pa1H = *(const s16x8*)&bH[8192];
  s16x8 pa1L = *(const s16x8*)&bL[8192];
  s16x8 pb0H = *(const s16x8*)&bH[512];
  s16x8 pb0L = *(const s16x8*)&bL[512];
  s16x8 pb1H = *(const s16x8*)&bH[8192 + 512];
  s16x8 pb1L = *(const s16x8*)&bL[8192 + 512];

  // stage dstS (already log2 domain, padded layout) + block-wide max md
  {
    const float d0 = dstv[base + t];
    const float d1 = dstv[base + t + 256];
    dstS[t + (t >> 6) * 4] = d0;
    const int t2 = t + 256;
    dstS[t2 + (t2 >> 6) * 4] = d1;
    float mx = fmaxf(d0, d1);
#pragma unroll
    for (int w = 1; w < 64; w <<= 1) mx = fmaxf(mx, __shfl_xor(mx, w, 64));
    if ((t & 63) == 0) wredM[t >> 6] = mx;
  }
  __syncthreads();
  const float md = fmaxf(fmaxf(wredM[0], wredM[1]), fmaxf(wredM[2], wredM[3]));

  // ---- phase 1: single-pass masked softmax -> As bf16, invS = 1/rowsum.
  // 8 threads per row, thread l8 owns contiguous j in [l8*64, l8*64+64).
  {
    const int r = t >> 3, l8 = t & 7;
    const long i = base + i0 + r;
    const float si = src[i];
    const uint2 mw2 = *(const uint2*)(mask + i * 16 + 2 * l8);
    const float em = si + md;
    const float m = fmaxf(em, ALPHA * em);   // >= masked max of leaky(si+dv)
    const float* __restrict__ dp = &dstS[l8 * 68];
    const int jb = l8 * 64;
    const int xs = l8 << 3;                  // As column XOR swizzle
    float sum = 0.f;
#pragma unroll
    for (int g = 0; g < 16; g++) {
      const float4 dv = *(const float4*)&dp[g * 4];
      const unsigned w = ((g & 8) ? mw2.y : mw2.x) >> ((g & 7) * 4);
      float e0 = si + dv.x, e1 = si + dv.y, e2 = si + dv.z, e3 = si + dv.w;
      e0 = fmaxf(e0, ALPHA * e0) - m; e1 = fmaxf(e1, ALPHA * e1) - m;
      e2 = fmaxf(e2, ALPHA * e2) - m; e3 = fmaxf(e3, ALPHA * e3) - m;
      float p0 = EXP2F(e0), p1 = EXP2F(e1), p2 = EXP2F(e2), p3 = EXP2F(e3);
      p0 = (w & 1u) ? p0 : 0.f;
      p1 = (w & 2u) ? p1 : 0.f;
      p2 = (w & 4u) ? p2 : 0.f;
      p3 = (w & 8u) ? p3 : 0.f;
      sum += (p0 + p1) + (p2 + p3);
      union { __hip_bfloat162 b; unsigned u; } u01, u23;
      u01.b = __float22bfloat162_rn(make_float2(p0, p1));
      u23.b = __float22bfloat162_rn(make_float2(p2, p3));
      *(uint2*)&As[r][(jb + g * 4) ^ xs] = make_uint2(u01.u, u23.u);
    }
#pragma unroll
    for (int w = 1; w < 8; w <<= 1) sum += __shfl_xor(sum, w, 64);
    if (l8 == 0) invS[r] = 1.f / sum;
  }
  __syncthreads();

  // ---- phase 2: MFMA aggregation, explicit even/odd depth-2 ping-pong.
  // As reads apply the same column XOR: ((kb>>1)&7)<<3, compile-time. ----
  f32x4 acc00 = {0.f,0.f,0.f,0.f}, acc01 = {0.f,0.f,0.f,0.f};
  f32x4 acc10 = {0.f,0.f,0.f,0.f}, acc11 = {0.f,0.f,0.f,0.f};
#pragma unroll
  for (int kp = 0; kp < 8; kp++) {
    {   // even kb = 2*kp  (set A)
      const int k0 = ((2 * kp) * 32 + q * 8) ^ (kp << 3);
      const s16x8 a0 = *(const s16x8*)&As[m16][k0];
      const s16x8 a1 = *(const s16x8*)&As[16 + m16][k0];
      acc00 = __builtin_amdgcn_mfma_f32_16x16x32_bf16(a0, pa0H, acc00, 0, 0, 0);
      acc01 = __builtin_amdgcn_mfma_f32_16x16x32_bf16(a0, pa1H, acc01, 0, 0, 0);
      acc10 = __builtin_amdgcn_mfma_f32_16x16x32_bf16(a1, pa0H, acc10, 0, 0, 0);
      acc11 = __builtin_amdgcn_mfma_f32_16x16x32_bf16(a1, pa1H, acc11, 0, 0, 0);
      acc00 = __builtin_amdgcn_mfma_f32_16x16x32_bf16(a0, pa0L, acc00, 0, 0, 0);
      acc01 = __builtin_amdgcn_mfma_f32_16x16x32_bf16(a0, pa1L, acc01, 0, 0, 0);
      acc10 = __builtin_amdgcn_mfma_f32_16x16x32_bf16(a1, pa0L, acc10, 0, 0, 0);
      acc11 = __builtin_amdgcn_mfma_f32_16x16x32_bf16(a1, pa1L, acc11, 0, 0, 0);
      if (kp < 7) {
        const int bo = (2 * kp + 2) * 512;
        pa0H = *(const s16x8*)&bH[bo];
        pa0L = *(const s16x8*)&bL[bo];
        pa1H = *(const s16x8*)&bH[8192 + bo];
        pa1L = *(const s16x8*)&bL[8192 + bo];
      }
    }
    {   // odd kb = 2*kp+1  (set B)
      const int k0 = ((2 * kp + 1) * 32 + q * 8) ^ (kp << 3);
      const s16x8 a0 = *(const s16x8*)&As[m16][k0];
      const s16x8 a1 = *(const s16x8*)&As[16 + m16][k0];
      acc00 = __builtin_amdgcn_mfma_f32_16x16x32_bf16(a0, pb0H, acc00, 0, 0, 0);
      acc01 = __builtin_amdgcn_mfma_f32_16x16x32_bf16(a0, pb1H, acc01, 0, 0, 0);
      acc10 = __builtin_amdgcn_mfma_f32_16x16x32_bf16(a1, pb0H, acc10, 0, 0, 0);
      acc11 = __builtin_amdgcn_mfma_f32_16x16x32_bf16(a1, pb1H, acc11, 0, 0, 0);
      acc00 = __builtin_amdgcn_mfma_f32_16x16x32_bf16(a0, pb0L, acc00, 0, 0, 0);
      acc01 = __builtin_amdgcn_mfma_f32_16x16x32_bf16(a0, pb1L, acc01, 0, 0, 0);
      acc10 = __builtin_amdgcn_mfma_f32_16x16x32_bf16(a1, pb0L, acc10, 0, 0, 0);
      acc11 = __builtin_amdgcn_mfma_f32_16x16x32_bf16(a1, pb1L, acc11, 0, 0, 0);
      if (kp < 7) {
        const int bo = (2 * kp + 3) * 512;
        pb0H = *(const s16x8*)&bH[bo];
        pb0L = *(const s16x8*)&bL[bo];
        pb1H = *(const s16x8*)&bH[8192 + bo];
        pb1L = *(const s16x8*)&bL[8192 + bo];
      }
    }
  }
#pragma unroll
  for (int reg = 0; reg < 4; reg++) {
    const int row = q * 4 + reg;
    const float li0 = invS[row], li1 = invS[16 + row];
    float v00 = acc00[reg] * li0, v01 = acc01[reg] * li0;
    float v10 = acc10[reg] * li1, v11 = acc11[reg] * li1;
    v00 = v00 > 0.f ? v00 : __expf(v00) - 1.f;
    v01 = v01 > 0.f ? v01 : __expf(v01) - 1.f;
    v10 = v10 > 0.f ? v10 : __expf(v10) - 1.f;
    v11 = v11 > 0.f ? v11 : __expf(v11) - 1.f;
    float* o0 = out + (base + i0 + row) * (long)ostride + ocoff + n0 + m16;
    float* o1 = out + (base + i0 + 16 + row) * (long)ostride + ocoff + n0 + m16;
    o0[0] = v00; o0[16] = v01;
    o1[0] = v10; o1[16] = v11;
  }
}

// ---- K3/K4: MFMA GEMM, C = A[32768,K] @ BT^T, 32 rows x 128 cols/block.
// A fp32 -> bf16 hi/lo during LDS staging; B pre-split in FRAGMENT ORDER
// (w_frag_off) -> each B load is one coalesced 1KB wave transaction.
// MODE 0: emit whT hi/lo (fragment order) + src/dst (log2-scaled).
// MODE 1: +bias +leaky fp32 store. ----
template<int K, int KC, int MODE>
__global__ __launch_bounds__(256) void mfma_gemm(
    const float* __restrict__ A,
    const ushort* __restrict__ BTH, const ushort* __restrict__ BTL,
    const float* __restrict__ bias, float* __restrict__ outF,
    ushort* __restrict__ whtH, ushort* __restrict__ whtL,
    const float* __restrict__ avec, float* __restrict__ src, float* __restrict__ dst,
    const int ostride)
{
  constexpr int KP = KC + 8;
  __shared__ ushort AsH[32][KP];
  __shared__ ushort AsL[32][KP];
  __shared__ float sredS[4][32], sredD[4][32];
  const int t = threadIdx.x;
  const long row0 = (long)blockIdx.x * 32;
  const int ncoff = (MODE == 1) ? blockIdx.y * 128 : 0;

  const int wv = t >> 6, lane = t & 63;
  const int m16 = lane & 15, q = lane >> 4;
  const int n0 = wv * 32;
  // fragment-order B: tile (ncoff+n0)/16, lane*8; next 16-col tile at +K*16
  const ushort* __restrict__ bh0 = BTH + (long)((ncoff + n0) >> 4) * (K * 16) + lane * 8;
  const ushort* __restrict__ bl0 = BTL + (long)((ncoff + n0) >> 4) * (K * 16) + lane * 8;

  f32x4 acc[2][2];
#pragma unroll
  for (int m = 0; m < 2; m++)
#pragma unroll
    for (int n = 0; n < 2; n++) acc[m][n] = (f32x4){0.f, 0.f, 0.f, 0.f};

  for (int kc = 0; kc < K; kc += KC) {
    constexpr int NIT = (32 * KC / 4) / 256;
#pragma unroll
    for (int it = 0; it < NIT; it++) {
      const int idx = t + it * 256;
      const int r = idx / (KC / 4), k4 = idx % (KC / 4);
      const float4 v = *(const float4*)&A[(row0 + r) * (long)K + kc + k4 * 4];
      split_store4(&AsH[r][k4 * 4], &AsL[r][k4 * 4], v.x, v.y, v.z, v.w);
    }
    __syncthreads();
#pragma unroll
    for (int ks = 0; ks < KC / 32; ks++) {
      const int k0 = ks * 32 + q * 8;
      const s16x8 a0H = *(const s16x8*)&AsH[m16][k0];
      const s16x8 a0L = *(const s16x8*)&AsL[m16][k0];
      const s16x8 a1H = *(const s16x8*)&AsH[16 + m16][k0];
      const s16x8 a1L = *(const s16x8*)&AsL[16 + m16][k0];
      const int bo = ((kc >> 5) + ks) * 512;
      const s16x8 b0H = *(const s16x8*)&bh0[bo];
      const s16x8 b0L = *(const s16x8*)&bl0[bo];
      const s16x8 b1H = *(const s16x8*)&bh0[K * 16 + bo];
      const s16x8 b1L = *(const s16x8*)&bl0[K * 16 + bo];
      acc[0][0] = __builtin_amdgcn_mfma_f32_16x16x32_bf16(a0H, b0H, acc[0][0], 0, 0, 0);
      acc[0][1] = __builtin_amdgcn_mfma_f32_16x16x32_bf16(a0H, b1H, acc[0][1], 0, 0, 0);
      acc[1][0] = __builtin_amdgcn_mfma_f32_16x16x32_bf16(a1H, b0H, acc[1][0], 0, 0, 0);
      acc[1][1] = __builtin_amdgcn_mfma_f32_16x16x32_bf16(a1H, b1H, acc[1][1], 0, 0, 0);
      acc[0][0] = __builtin_amdgcn_mfma_f32_16x16x32_bf16(a0L, b0H, acc[0][0], 0, 0, 0);
      acc[0][1] = __builtin_amdgcn_mfma_f32_16x16x32_bf16(a0L, b1H, acc[0][1], 0, 0, 0);
      acc[1][0] = __builtin_amdgcn_mfma_f32_16x16x32_bf16(a1L, b0H, acc[1][0], 0, 0, 0);
      acc[1][1] = __builtin_amdgcn_mfma_f32_16x16x32_bf16(a1L, b1H, acc[1][1], 0, 0, 0);
      acc[0][0] = __builtin_amdgcn_mfma_f32_16x16x32_bf16(a0H, b0L, acc[0][0], 0, 0, 0);
      acc[0][1] = __builtin_amdgcn_mfma_f32_16x16x32_bf16(a0H, b1L, acc[0][1], 0, 0, 0);
      acc[1][0] = __builtin_amdgcn_mfma_f32_16x16x32_bf16(a1H, b0L, acc[1][0], 0, 0, 0);
      acc[1][1] = __builtin_amdgcn_mfma_f32_16x16x32_bf16(a1H, b1L, acc[1][1], 0, 0, 0);
    }
    __syncthreads();
  }

  if (MODE == 0) {
    // whT hi/lo store in fragment order
    const long batch = row0 >> 9;
    const int iloc = (int)(row0 & 511);
#pragma unroll
    for (int m = 0; m < 2; m++)
#pragma unroll
      for (int n = 0; n < 2; n++) {
        const int c = n0 + n * 16 + m16;
        const int j = iloc + m * 16 + q * 4;        // j%4 == 0 -> contiguous 4
        const long o = wht_off(batch, c, j);
        const f32x4 v = acc[m][n];
        split_store4(&whtH[o], &whtL[o], v[0], v[1], v[2], v[3]);
      }
    // fused src/dst: reduce over cols (16 lanes x 2 n-tiles per wave, 4 waves)
    const float a10 = avec[n0 + m16], a11 = avec[n0 + 16 + m16];
    const float a20 = avec[128 + n0 + m16], a21 = avec[128 + n0 + 16 + m16];
#pragma unroll
    for (int m = 0; m < 2; m++) {
#pragma unroll
      for (int reg = 0; reg < 4; reg++) {
        float s = acc[m][0][reg] * a10 + acc[m][1][reg] * a11;
        float d = acc[m][0][reg] * a20 + acc[m][1][reg] * a21;
#pragma unroll
        for (int w = 1; w < 16; w <<= 1) {
          s += __shfl_xor(s, w, 64);
          d += __shfl_xor(d, w, 64);
        }
        if (m16 == 0) {
          const int row = m * 16 + q * 4 + reg;
          sredS[wv][row] = s;
          sredD[wv][row] = d;
        }
      }
    }
    __syncthreads();
    if (t < 32) {
      const float s = sredS[0][t] + sredS[1][t] + sredS[2][t] + sredS[3][t];
      const float d = sredD[0][t] + sredD[1][t] + sredD[2][t] + sredD[3][t];
      src[row0 + t] = s * LOG2E;   // log2-domain at producer
      dst[row0 + t] = d * LOG2E;
    }
  } else {
#pragma unroll
    for (int m = 0; m < 2; m++)
#pragma unroll
      for (int n = 0; n < 2; n++) {
        const int c = ncoff + n0 + n * 16 + m16;
        const float bv = bias[c];
#pragma unroll
        for (int reg = 0; reg < 4; reg++) {
          float v = acc[m][n][reg] + bv;
          v = fmaxf(v, ALPHA * v);
          outF[(row0 + m * 16 + q * 4 + reg) * (long)ostride + c] = v;
        }
      }
  }
}

extern "C" void kernel_launch(void* const* d_in, const int* in_sizes, int n_in,
                              void* d_out, int out_size, void* d_ws, size_t ws_size,
                              hipStream_t stream) {
  const float* compound = (const float*)d_in[0];
  const int*   adj      = (const int*)d_in[1];
  const float* W_stack  = (const float*)d_in[2];
  const float* a_stack  = (const float*)d_in[3];
  const float* W_out    = (const float*)d_in[4];
  const float* a_out    = (const float*)d_in[5];
  const float* Wc       = (const float*)d_in[6];
  const float* bc       = (const float*)d_in[7];
  float* out = (float*)d_out;

  // workspace: wht slots for 3 layers (48MB), then multi (50MB).
  // x aliases multi head; WcT parked in dead multi tail (written only after
  // multi's last reader, gemm384, has run).
  ushort* wht_all = (ushort*)d_ws;                    // 3 x 16MB slots
  float* f     = (float*)d_ws;
  float* multi = f + 12582912;                        // 12,582,912 floats
  float* x     = multi;                               // aliases multi head
  ushort* WcT_H = (ushort*)(multi + 5000000);         // beyond x's 4.19M floats
  ushort* WcT_L = WcT_H + 32768;

  // d_out parking (dead until final GEMM overwrites):
  // mask 524288 uints | src[4] | dst[4] | WoT_H/L
  unsigned* mask = (unsigned*)d_out;
  float* doutF = (float*)d_out;
  float* srcB = doutF + 524288;                       // 4 x 32768
  float* dstB = srcB + 4 * 32768;                     // 4 x 32768
  ushort* WoT_H = (ushort*)(dstB + 4 * 32768);        // 98304 ushorts
  ushort* WoT_L = WoT_H + 98304;
  float* src3 = srcB + 3 * 32768;
  float* dst3 = dstB + 3 * 32768;

  // front: wh_small x3 + maskprep + wt_prep(W_out) in ONE dispatch
  front_union<<<5312, 256, 0, stream>>>(
      compound, W_stack, a_stack, wht_all, srcB, dstB,
      adj, mask, W_out, WoT_H, WoT_L);
  // 3 GAT heads
  fused_attn<<<dim3(16, 64, 3), 256, 0, stream>>>(
      mask, srcB, dstB, wht_all, multi, 384);
  // layer 4: Wh = multi @ W_out  (MFMA, emits whT slot-0 + src/dst slot-3)
  mfma_gemm<384, 192, 0><<<1024, 256, 0, stream>>>(
      multi, WoT_H, WoT_L, nullptr, nullptr, wht_all, wht_all + 4194304,
      a_out, src3, dst3, 0);
  fused_attn<<<dim3(16, 64, 1), 256, 0, stream>>>(
      mask, src3, dst3, wht_all, x, 128);
  // Wc prep AFTER multi is dead (only x's 4.19M floats live) — round-13 slot
  wt_prep<<<128, 256, 0, stream>>>(Wc, WcT_H, WcT_L, 128, 256);
  // final: out = leaky(x @ Wc + bc)  (MFMA)
  mfma_gemm<128, 128, 1><<<dim3(1024, 2), 256, 0, stream>>>(
      x, WcT_H, WcT_L, bc, out, nullptr, nullptr, nullptr, nullptr, nullptr, 256);
}

// Round 12
// 230.904 us; speedup vs baseline: 1.7431x; 1.0459x over previous
//
#include <hip/hip_runtime.h>
#include <hip/hip_bf16.h>
#include <math.h>

// GAT predictor: B=64, N=512, ATOM=34, GAT=128, HID=256, 3 layers + out.
// Round-19: (a) front_union block-type INTERLEAVE — round-18 counters showed
// the union ran its sections serially (dur == sum of parts; blocks dispatch
// in bid order, so wh retired before mask started). 5312 = 64x83 and the
// sections are exactly 48 wh + 32 mask + 3 wt per 83 -> remap bid via
// (g,r)=(bid/83,bid%83) so every resident window carries the global mix and
// mask's HBM stream overlaps wh's VALU. (b) fused_attn B-prefetch depth
// 2 -> 4 (16 named s16x8, +32 VGPR ~100 < 128 cap): depth-2 gave ~80cy of
// MFMA cover vs ~250cy L2 latency (MfmaUtil stuck at 21%). Spill tripwire:
// WRITE_SIZE must stay 49152. Everything else identical to round-18.
// ws: wht[3] 48MB | multi 50MB (x aliases head; WcT parked at +5M floats,
//     written only after multi is dead)
// d_out: mask 2.1MB | src[4]/dst[4] 1MB | WoT 0.4MB  (until final GEMM)

#define ALPHA 0.2f
#define LOG2E 1.44269504088896f

#if __has_builtin(__builtin_amdgcn_exp2f)
#define EXP2F(x) __builtin_amdgcn_exp2f(x)
#else
extern "C" __device__ float __ocml_exp2_f32(float);
#define EXP2F(x) __ocml_exp2_f32(x)
#endif

typedef __attribute__((ext_vector_type(8))) short s16x8;   // 8 bf16 (4 VGPRs)
typedef __attribute__((ext_vector_type(4))) float f32x4;

__device__ __forceinline__ ushort bf16_rne(float f) {
  union { float f; unsigned u; } v; v.f = f;
  unsigned r = v.u + 0x7FFFu + ((v.u >> 16) & 1u);
  return (ushort)(r >> 16);
}
__device__ __forceinline__ float bf16_tof(ushort h) {
  union { unsigned u; float f; } v; v.u = ((unsigned)h) << 16;
  return v.f;
}
__device__ __forceinline__ void split_store4(
    ushort* __restrict__ ph, ushort* __restrict__ pl,
    float v0, float v1, float v2, float v3) {
  ushort h0 = bf16_rne(v0), h1 = bf16_rne(v1), h2 = bf16_rne(v2), h3 = bf16_rne(v3);
  *(ushort4*)ph = make_ushort4(h0, h1, h2, h3);
  *(ushort4*)pl = make_ushort4(bf16_rne(v0 - bf16_tof(h0)), bf16_rne(v1 - bf16_tof(h1)),
                               bf16_rne(v2 - bf16_tof(h2)), bf16_rne(v3 - bf16_tof(h3)));
}

// wht fragment-order offset (K=512): batch*65536 + (col/16)*8192 + (j/32)*512
//   + (col%16)*8 + ((j>>3)&3)*128 + (j&7)   [j = node index = GEMM k]
__device__ __forceinline__ long wht_off(long batch, int c, int j) {
  return batch * 65536 + (long)(c >> 4) * 8192 + (j >> 5) * 512 +
         ((c & 15) << 3) + (((j >> 3) & 3) << 7) + (j & 7);
}

// generic fragment-order offset for a [Kd x Nd] weight (col c, k-index j)
__device__ __forceinline__ long w_frag_off(int c, int j, int Kd) {
  return (long)(c >> 4) * (Kd * 16) + (j >> 5) * 512 +
         ((c & 15) << 3) + (((j >> 3) & 3) << 7) + (j & 7);
}

#define WHT_SLOT 8388608L   // ushorts per layer slot (whtH 4M + whtL 4M)

// ---- standalone wt_prep: W[K,N] fp32 -> fragment-order TH/TL ----
__global__ __launch_bounds__(256) void wt_prep(
    const float* __restrict__ W, ushort* __restrict__ TH, ushort* __restrict__ TL,
    const int Kd, const int Nd)
{
  const int idx = blockIdx.x * 256 + threadIdx.x;
  if (idx >= Kd * Nd) return;
  const int k = idx / Nd, n = idx % Nd;
  const float v = W[idx];
  const ushort h = bf16_rne(v);
  const long o = w_frag_off(n, k, Kd);
  TH[o] = h;
  TL[o] = bf16_rne(v - bf16_tof(h));
}

// ---- K0 (front union, INTERLEAVED): per 83-block group: 48 wh | 32 mask |
// 3 wt(W_out). Resident windows carry the global mix -> mask's HBM stream
// overlaps wh's compute. ----
__global__ __launch_bounds__(256) void front_union(
    const float* __restrict__ A, const float* __restrict__ Wst,
    const float* __restrict__ ast,
    ushort* __restrict__ whtBase, float* __restrict__ srcB, float* __restrict__ dstB,
    const int* __restrict__ adj, unsigned* __restrict__ mask,
    const float* __restrict__ W_out, ushort* __restrict__ WoT_H, ushort* __restrict__ WoT_L)
{
  __shared__ float AsT[34][36];
  __shared__ float Ws[34][128];
  const int t = threadIdx.x;
  const int g = blockIdx.x / 83, r83 = blockIdx.x - g * 83;

  if (r83 >= 48) {
    if (r83 < 80) {
      // ---- maskprep: pack adj>0 into bitmask [32768][16] uint ----
      const int mb = g * 32 + (r83 - 48);           // [0,2048)
      const int gid = mb * 256 + t;
      const int4* __restrict__ p = (const int4*)(adj + (long)gid * 32);
      unsigned m = 0;
#pragma unroll
      for (int k = 0; k < 8; k++) {
        const int4 v = p[k];
        m |= (v.x > 0 ? 1u : 0u) << (4 * k);
        m |= (v.y > 0 ? 1u : 0u) << (4 * k + 1);
        m |= (v.z > 0 ? 1u : 0u) << (4 * k + 2);
        m |= (v.w > 0 ? 1u : 0u) << (4 * k + 3);
      }
      mask[gid] = m;
    } else {
      // ---- wt_prep(W_out): [384,128] fp32 -> fragment-order WoT ----
      const int wb = g * 3 + (r83 - 80);            // [0,192)
      const int idx = wb * 256 + t;                 // 49152 exact
      const int k = idx / 128, n = idx % 128;
      const float v = W_out[idx];
      const ushort h = bf16_rne(v);
      const long o = w_frag_off(n, k, 384);
      WoT_H[o] = h;
      WoT_L[o] = bf16_rne(v - bf16_tof(h));
    }
    return;
  }

  // ---- wh_small: Wh_l = compound @ W_l -> whT_l (fragment order) + src/dst
  const int bid = g * 48 + r83;                     // [0,3072)
  const int l = bid >> 10;
  const float* __restrict__ W = Wst + (long)l * 34 * 128;
  const float* __restrict__ avec = ast + (long)l * 256;
  ushort* __restrict__ whtH = whtBase + (long)l * WHT_SLOT;
  ushort* __restrict__ whtL = whtH + 4194304;
  float* __restrict__ src = srcB + (long)l * 32768;
  float* __restrict__ dst = dstB + (long)l * 32768;
  const long row0 = (long)(bid & 1023) * 32;
  const int cg = t & 31, rg = t >> 5;
  {
    const int r = t >> 3, l8 = t & 7;
#pragma unroll
    for (int q = 0; q < 5; q++) {
      int k = l8 + q * 8;
      if (k < 34) AsT[k][r] = A[(row0 + r) * 34 + k];
    }
  }
  {
    int idx = t;
#pragma unroll
    for (int i = 0; i < 17; i++, idx += 256)
      Ws[idx >> 7][idx & 127] = W[idx];
  }
  __syncthreads();

  float acc[4][4];
#pragma unroll
  for (int r = 0; r < 4; r++)
#pragma unroll
    for (int c = 0; c < 4; c++) acc[r][c] = 0.f;
#pragma unroll 2
  for (int k = 0; k < 34; k++) {
    const float4 wv = *(const float4*)&Ws[k][cg * 4];
    const float4 av = *(const float4*)&AsT[k][rg * 4];
#define GFMA(r, a) \
    acc[r][0] += (a) * wv.x; acc[r][1] += (a) * wv.y; \
    acc[r][2] += (a) * wv.z; acc[r][3] += (a) * wv.w;
    GFMA(0, av.x) GFMA(1, av.y) GFMA(2, av.z) GFMA(3, av.w)
#undef GFMA
  }

  {
    const long batch = row0 >> 9;
    const int j = (int)(row0 & 511) + rg * 4;       // j%4 == 0 -> contiguous 4
#pragma unroll
    for (int cc = 0; cc < 4; cc++) {
      const long o = wht_off(batch, cg * 4 + cc, j);
      split_store4(&whtH[o], &whtL[o], acc[0][cc], acc[1][cc], acc[2][cc], acc[3][cc]);
    }
  }

  const float4 a1 = *(const float4*)&avec[cg * 4];
  const float4 a2 = *(const float4*)&avec[128 + cg * 4];
#pragma unroll
  for (int r = 0; r < 4; r++) {
    float s = acc[r][0]*a1.x + acc[r][1]*a1.y + acc[r][2]*a1.z + acc[r][3]*a1.w;
    float d = acc[r][0]*a2.x + acc[r][1]*a2.y + acc[r][2]*a2.z + acc[r][3]*a2.w;
#pragma unroll
    for (int w = 1; w < 32; w <<= 1) {
      s += __shfl_xor(s, w, 64);
      d += __shfl_xor(d, w, 64);
    }
    if (cg == 0) {
      src[row0 + rg * 4 + r] = s * LOG2E;   // log2-domain at producer
      dst[row0 + rg * 4 + r] = d * LOG2E;
    }
  }
}

// ---- K2 (fused, multi-layer): single-pass masked softmax -> LDS As
// (unnormalized bf16 p), then out = elu((P @ WhT^T) * 1/rowsum).
// blockIdx.z = layer. B prefetch: depth-4 named-register ping-pong. ----

#define LD_SET(S, KB) \
  S##0H = *(const s16x8*)&bH[(KB) * 512]; \
  S##0L = *(const s16x8*)&bL[(KB) * 512]; \
  S##1H = *(const s16x8*)&bH[8192 + (KB) * 512]; \
  S##1L = *(const s16x8*)&bL[8192 + (KB) * 512];

#define MF(a, b, c) c = __builtin_amdgcn_mfma_f32_16x16x32_bf16(a, b, c, 0, 0, 0)

#define STEP(S, KB) { \
  const int k0_ = ((KB) * 32 + q * 8) ^ ((((KB) >> 1) & 7) << 3); \
  const s16x8 a0_ = *(const s16x8*)&As[m16][k0_]; \
  const s16x8 a1_ = *(const s16x8*)&As[16 + m16][k0_]; \
  MF(a0_, S##0H, acc00); MF(a0_, S##1H, acc01); \
  MF(a1_, S##0H, acc10); MF(a1_, S##1H, acc11); \
  MF(a0_, S##0L, acc00); MF(a0_, S##1L, acc01); \
  MF(a1_, S##0L, acc10); MF(a1_, S##1L, acc11); \
  if ((KB) + 4 < 16) { LD_SET(S, (KB) + 4) } }

__global__ __launch_bounds__(256, 4) void fused_attn(
    const unsigned* __restrict__ mask,
    const float* __restrict__ srcB, const float* __restrict__ dstB,
    const ushort* __restrict__ whtBase,
    float* __restrict__ out, const int ostride)
{
  __shared__ ushort As[32][520];
  __shared__ float dstS[544];          // phys = j + (j>>6)*4
  __shared__ float invS[32];
  __shared__ float wredM[4];
  const int t = threadIdx.x;
  const int l = blockIdx.z;
  const float* __restrict__ src = srcB + (long)l * 32768;
  const float* __restrict__ dstv = dstB + (long)l * 32768;
  const ushort* __restrict__ whtH = whtBase + (long)l * WHT_SLOT;
  const ushort* __restrict__ whtL = whtH + 4194304;
  const int ocoff = l * 128;
  // XCD swizzle: per layer 1024 blocks = 8 XCDs x 128; each XCD gets 8 whole
  // batches so a batch's 512KB wht slice is HBM-fetched once, reused via L2.
  const int flat = blockIdx.y * 16 + blockIdx.x;
  const int swz = (flat & 7) * 128 + (flat >> 3);
  const long base = (long)(swz >> 4) * 512;   // batch * 512
  const int i0 = (swz & 15) * 32;             // row tile within batch

  // MFMA geometry + entry prefetch of k-blocks 0..3 (independent of softmax;
  // L2 latency hides under the VALU phase). Named registers only.
  const int wv = t >> 6, lane = t & 63;
  const int m16 = lane & 15, q = lane >> 4;
  const int n0 = wv * 32;
  const ushort* __restrict__ bH = whtH + base * 128 + wv * 16384 + lane * 8;
  const ushort* __restrict__ bL = whtL + base * 128 + wv * 16384 + lane * 8;
  s16x8 sA0H, sA0L, sA1H, sA1L, sB0H, sB0L, sB1H, sB1L;
  s16x8 sC0H, sC0L, sC1H, sC1L, sD0H, sD0L, sD1H, sD1L;
  LD_SET(sA, 0)
  LD_SET(sB, 1)
  LD_SET(sC, 2)
  LD_SET(sD, 3)

  // stage dstS (already log2 domain, padded layout) + block-wide max md
  {
    const float d0 = dstv[base + t];
    const float d1 = dstv[base + t + 256];
    dstS[t + (t >> 6) * 4] = d0;
    const int t2 = t + 256;
    dstS[t2 + (t2 >> 6) * 4] = d1;
    float mx = fmaxf(d0, d1);
#pragma unroll
    for (int w = 1; w < 64; w <<= 1) mx = fmaxf(mx, __shfl_xor(mx, w, 64));
    if ((t & 63) == 0) wredM[t >> 6] = mx;
  }
  __syncthreads();
  const float md = fmaxf(fmaxf(wredM[0], wredM[1]), fmaxf(wredM[2], wredM[3]));

  // ---- phase 1: single-pass masked softmax -> As bf16, invS = 1/rowsum.
  // 8 threads per row, thread l8 owns contiguous j in [l8*64, l8*64+64).
  {
    const int r = t >> 3, l8 = t & 7;
    const long i = base + i0 + r;
    const float si = src[i];
    const uint2 mw2 = *(const uint2*)(mask + i * 16 + 2 * l8);
    const float em = si + md;
    const float m = fmaxf(em, ALPHA * em);   // >= masked max of leaky(si+dv)
    const float* __restrict__ dp = &dstS[l8 * 68];
    const int jb = l8 * 64;
    const int xs = l8 << 3;                  // As column XOR swizzle
    float sum = 0.f;
#pragma unroll
    for (int g = 0; g < 16; g++) {
      const float4 dv = *(const float4*)&dp[g * 4];
      const unsigned w = ((g & 8) ? mw2.y : mw2.x) >> ((g & 7) * 4);
      float e0 = si + dv.x, e1 = si + dv.y, e2 = si + dv.z, e3 = si + dv.w;
      e0 = fmaxf(e0, ALPHA * e0) - m; e1 = fmaxf(e1, ALPHA * e1) - m;
      e2 = fmaxf(e2, ALPHA * e2) - m; e3 = fmaxf(e3, ALPHA * e3) - m;
      float p0 = EXP2F(e0), p1 = EXP2F(e1), p2 = EXP2F(e2), p3 = EXP2F(e3);
      p0 = (w & 1u) ? p0 : 0.f;
      p1 = (w & 2u) ? p1 : 0.f;
      p2 = (w & 4u) ? p2 : 0.f;
      p3 = (w & 8u) ? p3 : 0.f;
      sum += (p0 + p1) + (p2 + p3);
      union { __hip_bfloat162 b; unsigned u; } u01, u23;
      u01.b = __float22bfloat162_rn(make_float2(p0, p1));
      u23.b = __float22bfloat162_rn(make_float2(p2, p3));
      *(uint2*)&As[r][(jb + g * 4) ^ xs] = make_uint2(u01.u, u23.u);
    }
#pragma unroll
    for (int w = 1; w < 8; w <<= 1) sum += __shfl_xor(sum, w, 64);
    if (l8 == 0) invS[r] = 1.f / sum;
  }
  __syncthreads();

  // ---- phase 2: MFMA aggregation, depth-4 named-register ping-pong.
  // As reads apply the same column XOR: ((kb>>1)&7)<<3, compile-time. ----
  f32x4 acc00 = {0.f,0.f,0.f,0.f}, acc01 = {0.f,0.f,0.f,0.f};
  f32x4 acc10 = {0.f,0.f,0.f,0.f}, acc11 = {0.f,0.f,0.f,0.f};
#pragma unroll
  for (int kp = 0; kp < 4; kp++) {
    STEP(sA, 4 * kp)
    STEP(sB, 4 * kp + 1)
    STEP(sC, 4 * kp + 2)
    STEP(sD, 4 * kp + 3)
  }
#pragma unroll
  for (int reg = 0; reg < 4; reg++) {
    const int row = q * 4 + reg;
    const float li0 = invS[row], li1 = invS[16 + row];
    float v00 = acc00[reg] * li0, v01 = acc01[reg] * li0;
    float v10 = acc10[reg] * li1, v11 = acc11[reg] * li1;
    v00 = v00 > 0.f ? v00 : __expf(v00) - 1.f;
    v01 = v01 > 0.f ? v01 : __expf(v01) - 1.f;
    v10 = v10 > 0.f ? v10 : __expf(v10) - 1.f;
    v11 = v11 > 0.f ? v11 : __expf(v11) - 1.f;
    float* o0 = out + (base + i0 + row) * (long)ostride + ocoff + n0 + m16;
    float* o1 = out + (base + i0 + 16 + row) * (long)ostride + ocoff + n0 + m16;
    o0[0] = v00; o0[16] = v01;
    o1[0] = v10; o1[16] = v11;
  }
}

// ---- K3/K4: MFMA GEMM, C = A[32768,K] @ BT^T, 32 rows x 128 cols/block.
// A fp32 -> bf16 hi/lo during LDS staging; B pre-split in FRAGMENT ORDER
// (w_frag_off) -> each B load is one coalesced 1KB wave transaction.
// MODE 0: emit whT hi/lo (fragment order) + src/dst (log2-scaled).
// MODE 1: +bias +leaky fp32 store. ----
template<int K, int KC, int MODE>
__global__ __launch_bounds__(256) void mfma_gemm(
    const float* __restrict__ A,
    const ushort* __restrict__ BTH, const ushort* __restrict__ BTL,
    const float* __restrict__ bias, float* __restrict__ outF,
    ushort* __restrict__ whtH, ushort* __restrict__ whtL,
    const float* __restrict__ avec, float* __restrict__ src, float* __restrict__ dst,
    const int ostride)
{
  constexpr int KP = KC + 8;
  __shared__ ushort AsH[32][KP];
  __shared__ ushort AsL[32][KP];
  __shared__ float sredS[4][32], sredD[4][32];
  const int t = threadIdx.x;
  const long row0 = (long)blockIdx.x * 32;
  const int ncoff = (MODE == 1) ? blockIdx.y * 128 : 0;

  const int wv = t >> 6, lane = t & 63;
  const int m16 = lane & 15, q = lane >> 4;
  const int n0 = wv * 32;
  // fragment-order B: tile (ncoff+n0)/16, lane*8; next 16-col tile at +K*16
  const ushort* __restrict__ bh0 = BTH + (long)((ncoff + n0) >> 4) * (K * 16) + lane * 8;
  const ushort* __restrict__ bl0 = BTL + (long)((ncoff + n0) >> 4) * (K * 16) + lane * 8;

  f32x4 acc[2][2];
#pragma unroll
  for (int m = 0; m < 2; m++)
#pragma unroll
    for (int n = 0; n < 2; n++) acc[m][n] = (f32x4){0.f, 0.f, 0.f, 0.f};

  for (int kc = 0; kc < K; kc += KC) {
    constexpr int NIT = (32 * KC / 4) / 256;
#pragma unroll
    for (int it = 0; it < NIT; it++) {
      const int idx = t + it * 256;
      const int r = idx / (KC / 4), k4 = idx % (KC / 4);
      const float4 v = *(const float4*)&A[(row0 + r) * (long)K + kc + k4 * 4];
      split_store4(&AsH[r][k4 * 4], &AsL[r][k4 * 4], v.x, v.y, v.z, v.w);
    }
    __syncthreads();
#pragma unroll
    for (int ks = 0; ks < KC / 32; ks++) {
      const int k0 = ks * 32 + q * 8;
      const s16x8 a0H = *(const s16x8*)&AsH[m16][k0];
      const s16x8 a0L = *(const s16x8*)&AsL[m16][k0];
      const s16x8 a1H = *(const s16x8*)&AsH[16 + m16][k0];
      const s16x8 a1L = *(const s16x8*)&AsL[16 + m16][k0];
      const int bo = ((kc >> 5) + ks) * 512;
      const s16x8 b0H = *(const s16x8*)&bh0[bo];
      const s16x8 b0L = *(const s16x8*)&bl0[bo];
      const s16x8 b1H = *(const s16x8*)&bh0[K * 16 + bo];
      const s16x8 b1L = *(const s16x8*)&bl0[K * 16 + bo];
      acc[0][0] = __builtin_amdgcn_mfma_f32_16x16x32_bf16(a0H, b0H, acc[0][0], 0, 0, 0);
      acc[0][1] = __builtin_amdgcn_mfma_f32_16x16x32_bf16(a0H, b1H, acc[0][1], 0, 0, 0);
      acc[1][0] = __builtin_amdgcn_mfma_f32_16x16x32_bf16(a1H, b0H, acc[1][0], 0, 0, 0);
      acc[1][1] = __builtin_amdgcn_mfma_f32_16x16x32_bf16(a1H, b1H, acc[1][1], 0, 0, 0);
      acc[0][0] = __builtin_amdgcn_mfma_f32_16x16x32_bf16(a0L, b0H, acc[0][0], 0, 0, 0);
      acc[0][1] = __builtin_amdgcn_mfma_f32_16x16x32_bf16(a0L, b1H, acc[0][1], 0, 0, 0);
      acc[1][0] = __builtin_amdgcn_mfma_f32_16x16x32_bf16(a1L, b0H, acc[1][0], 0, 0, 0);
      acc[1][1] = __builtin_amdgcn_mfma_f32_16x16x32_bf16(a1L, b1H, acc[1][1], 0, 0, 0);
      acc[0][0] = __builtin_amdgcn_mfma_f32_16x16x32_bf16(a0H, b0L, acc[0][0], 0, 0, 0);
      acc[0][1] = __builtin_amdgcn_mfma_f32_16x16x32_bf16(a0H, b1L, acc[0][1], 0, 0, 0);
      acc[1][0] = __builtin_amdgcn_mfma_f32_16x16x32_bf16(a1H, b0L, acc[1][0], 0, 0, 0);
      acc[1][1] = __builtin_amdgcn_mfma_f32_16x16x32_bf16(a1H, b1L, acc[1][1], 0, 0, 0);
    }
    __syncthreads();
  }

  if (MODE == 0) {
    // whT hi/lo store in fragment order
    const long batch = row0 >> 9;
    const int iloc = (int)(row0 & 511);
#pragma unroll
    for (int m = 0; m < 2; m++)
#pragma unroll
      for (int n = 0; n < 2; n++) {
        const int c = n0 + n * 16 + m16;
        const int j = iloc + m * 16 + q * 4;        // j%4 == 0 -> contiguous 4
        const long o = wht_off(batch, c, j);
        const f32x4 v = acc[m][n];
        split_store4(&whtH[o], &whtL[o], v[0], v[1], v[2], v[3]);
      }
    // fused src/dst: reduce over cols (16 lanes x 2 n-tiles per wave, 4 waves)
    const float a10 = avec[n0 + m16], a11 = avec[n0 + 16 + m16];
    const float a20 = avec[128 + n0 + m16], a21 = avec[128 + n0 + 16 + m16];
#pragma unroll
    for (int m = 0; m < 2; m++) {
#pragma unroll
      for (int reg = 0; reg < 4; reg++) {
        float s = acc[m][0][reg] * a10 + acc[m][1][reg] * a11;
        float d = acc[m][0][reg] * a20 + acc[m][1][reg] * a21;
#pragma unroll
        for (int w = 1; w < 16; w <<= 1) {
          s += __shfl_xor(s, w, 64);
          d += __shfl_xor(d, w, 64);
        }
        if (m16 == 0) {
          const int row = m * 16 + q * 4 + reg;
          sredS[wv][row] = s;
          sredD[wv][row] = d;
        }
      }
    }
    __syncthreads();
    if (t < 32) {
      const float s = sredS[0][t] + sredS[1][t] + sredS[2][t] + sredS[3][t];
      const float d = sredD[0][t] + sredD[1][t] + sredD[2][t] + sredD[3][t];
      src[row0 + t] = s * LOG2E;   // log2-domain at producer
      dst[row0 + t] = d * LOG2E;
    }
  } else {
#pragma unroll
    for (int m = 0; m < 2; m++)
#pragma unroll
      for (int n = 0; n < 2; n++) {
        const int c = ncoff + n0 + n * 16 + m16;
        const float bv = bias[c];
#pragma unroll
        for (int reg = 0; reg < 4; reg++) {
          float v = acc[m][n][reg] + bv;
          v = fmaxf(v, ALPHA * v);
          outF[(row0 + m * 16 + q * 4 + reg) * (long)ostride + c] = v;
        }
      }
  }
}

extern "C" void kernel_launch(void* const* d_in, const int* in_sizes, int n_in,
                              void* d_out, int out_size, void* d_ws, size_t ws_size,
                              hipStream_t stream) {
  const float* compound = (const float*)d_in[0];
  const int*   adj      = (const int*)d_in[1];
  const float* W_stack  = (const float*)d_in[2];
  const float* a_stack  = (const float*)d_in[3];
  const float* W_out    = (const float*)d_in[4];
  const float* a_out    = (const float*)d_in[5];
  const float* Wc       = (const float*)d_in[6];
  const float* bc       = (const float*)d_in[7];
  float* out = (float*)d_out;

  // workspace: wht slots for 3 layers (48MB), then multi (50MB).
  // x aliases multi head; WcT parked in dead multi tail (written only after
  // multi's last reader, gemm384, has run).
  ushort* wht_all = (ushort*)d_ws;                    // 3 x 16MB slots
  float* f     = (float*)d_ws;
  float* multi = f + 12582912;                        // 12,582,912 floats
  float* x     = multi;                               // aliases multi head
  ushort* WcT_H = (ushort*)(multi + 5000000);         // beyond x's 4.19M floats
  ushort* WcT_L = WcT_H + 32768;

  // d_out parking (dead until final GEMM overwrites):
  // mask 524288 uints | src[4] | dst[4] | WoT_H/L
  unsigned* mask = (unsigned*)d_out;
  float* doutF = (float*)d_out;
  float* srcB = doutF + 524288;                       // 4 x 32768
  float* dstB = srcB + 4 * 32768;                     // 4 x 32768
  ushort* WoT_H = (ushort*)(dstB + 4 * 32768);        // 98304 ushorts
  ushort* WoT_L = WoT_H + 98304;
  float* src3 = srcB + 3 * 32768;
  float* dst3 = dstB + 3 * 32768;

  // front: wh_small x3 + maskprep + wt_prep(W_out), INTERLEAVED, one dispatch
  front_union<<<5312, 256, 0, stream>>>(
      compound, W_stack, a_stack, wht_all, srcB, dstB,
      adj, mask, W_out, WoT_H, WoT_L);
  // 3 GAT heads
  fused_attn<<<dim3(16, 64, 3), 256, 0, stream>>>(
      mask, srcB, dstB, wht_all, multi, 384);
  // layer 4: Wh = multi @ W_out  (MFMA, emits whT slot-0 + src/dst slot-3)
  mfma_gemm<384, 192, 0><<<1024, 256, 0, stream>>>(
      multi, WoT_H, WoT_L, nullptr, nullptr, wht_all, wht_all + 4194304,
      a_out, src3, dst3, 0);
  fused_attn<<<dim3(16, 64, 1), 256, 0, stream>>>(
      mask, src3, dst3, wht_all, x, 128);
  // Wc prep AFTER multi is dead (only x's 4.19M floats live) — round-13 slot
  wt_prep<<<128, 256, 0, stream>>>(Wc, WcT_H, WcT_L, 128, 256);
  // final: out = leaky(x @ Wc + bc)  (MFMA)
  mfma_gemm<128, 128, 1><<<dim3(1024, 2), 256, 0, stream>>>(
      x, WcT_H, WcT_L, bc, out, nullptr, nullptr, nullptr, nullptr, nullptr, 256);
}